// Round 7
// baseline (369.419 us; speedup 1.0000x reference)
//
#include <hip/hip_runtime.h>
#include <cstddef>

#define NNODES 40000
#define NEDGES 640000
#define NETOT  (NNODES + NEDGES)
#define ELLW   96          // fixed edge slots per node; overflow -> spill list
#define NCAST  30720       // float4 groups across the 6 weight tensors
#define NBUCK  313         // dst>>7 buckets (128 nodes each)
#define SEGCAP 8192        // pairs per bucket segment (expected ~2300, +129 sigma)
#define ABLOCKS 84         // ceil(NETOT / 8192) edge-bucketing blocks
#define CBLOCKS 30         // NCAST / 1024 weight-cast blocks
#define ACB (ABLOCKS + CBLOCKS)

typedef unsigned short u16;
typedef unsigned int   u32;
using v2f = __attribute__((ext_vector_type(2))) float;

// ---------------- helpers ----------------
__device__ inline float wave_sum(float v) {
#pragma unroll
    for (int o = 32; o > 0; o >>= 1) v += __shfl_xor(v, o);
    return v;
}
__device__ inline u16 f2bf(float f) {   // round-to-nearest-even f32 -> bf16
    u32 u = __float_as_uint(f);
    return (u16)((u + 0x7fffu + ((u >> 16) & 1u)) >> 16);
}

// ---------------- build phase A: bucket edges by dst range + weight cast + prep_v + M2/cv ----
__global__ void build_a_kernel(const int* __restrict__ ei, u32* __restrict__ bcnt,
                               u32* __restrict__ seg,
                               const float* __restrict__ W1, const float* __restrict__ as1,
                               const float* __restrict__ ad1, float* __restrict__ vbuf,
                               const float* __restrict__ pw3, const float* __restrict__ pb3,
                               const float* __restrict__ fw, const float* __restrict__ fb,
                               u16* __restrict__ m2c, float* __restrict__ cvb,
                               const float* s0, u16* d0, int n0, const float* s1, u16* d1, int n1,
                               const float* s2, u16* d2, int n2, const float* s3, u16* d3, int n3,
                               const float* s4, u16* d4, int n4, const float* s5, u16* d5, int n5) {
    int tid = threadIdx.x;
    int blk = blockIdx.x;
    if (blk >= ABLOCKS) {
        if (blk < ACB) {                          // ---- weight cast ----
            int i = (blk - ABLOCKS) * 1024 + tid;
            const float* s; u16* d;
            if      (i < n0) { s = s0; d = d0; }
            else if ((i -= n0) < n1) { s = s1; d = d1; }
            else if ((i -= n1) < n2) { s = s2; d = d2; }
            else if ((i -= n2) < n3) { s = s3; d = d3; }
            else if ((i -= n3) < n4) { s = s4; d = d4; }
            else if ((i -= n4) < n5) { s = s5; d = d5; }
            else return;
            float4 v = ((const float4*)s)[i];
            ushort4 o; o.x = f2bf(v.x); o.y = f2bf(v.y); o.z = f2bf(v.z); o.w = f2bf(v.w);
            ((ushort4*)d)[i] = o;
        } else if (blk == ACB) {                  // ---- prep_v: v_s[h]=W_h^T a_s[h], v_d ----
            if (tid < 256) {
                int h = tid >> 6, k = tid & 63;
                float ss = 0.f, dd = 0.f;
                for (int c = 0; c < 64; c++) {
                    float w = W1[(h * 64 + c) * 64 + k];
                    ss += as1[h * 64 + c] * w;
                    dd += ad1[h * 64 + c] * w;
                }
                vbuf[tid] = ss;
                vbuf[256 + tid] = dd;
            }
        } else if (blk < ACB + 17) {              // ---- M2 = fw[:,128:] @ pw3 (bf16 out) ----
            int entry = (blk - (ACB + 1)) * 1024 + tid;   // 16 blocks x 1024 = 16384 entries
            int o = entry >> 7, k = entry & 127;
            float s = 0.f;
            for (int j = 0; j < 128; j++)
                s += fw[o * 256 + 128 + j] * pw3[j * 128 + k];
            m2c[o * 128 + k] = f2bf(s);
        } else {                                  // ---- cv = fw[:,128:] @ pb3 + fb ----
            if (tid < 128) {
                float s = fb[tid];
                for (int j = 0; j < 128; j++)
                    s += fw[tid * 256 + 128 + j] * pb3[j];
                cvb[tid] = s;
            }
        }
        return;
    }
    __shared__ u32 hist[NBUCK], hbase[NBUCK];
    for (int i = tid; i < NBUCK; i += 1024) hist[i] = 0;
    __syncthreads();
    u32 pk[8], loc[8]; int bj[8];
    int g0 = blk * 8192;
#pragma unroll
    for (int j = 0; j < 8; j++) {
        int g = g0 + j * 1024 + tid;
        bj[j] = -1;
        if (g < NETOT) {
            int src, dst;
            if (g < NEDGES) { src = ei[g]; dst = ei[NEDGES + g]; }
            else            { src = g - NEDGES; dst = src; }
            int b = dst >> 7;
            pk[j] = ((u32)dst << 16) | (u32)src;
            bj[j] = b;
            loc[j] = atomicAdd(&hist[b], 1u);
        }
    }
    __syncthreads();
    for (int i = tid; i < NBUCK; i += 1024) {
        u32 c = hist[i];
        hbase[i] = c ? atomicAdd(&bcnt[i], c) : 0u;
    }
    __syncthreads();
#pragma unroll
    for (int j = 0; j < 8; j++) {
        if (bj[j] >= 0) {
            u32 pos = hbase[bj[j]] + loc[j];
            if (pos < SEGCAP) seg[(size_t)bj[j] * SEGCAP + pos] = pk[j];
        }
    }
}

// ---------------- build phase B: per-bucket ELL fill (LDS slot counters, XCD-local writes) ----
__global__ void build_b_kernel(const u32* __restrict__ seg, const u32* __restrict__ bcnt,
                               int* __restrict__ cnt, u16* __restrict__ srcs16,
                               int2* __restrict__ ovbuf) {
    __shared__ u32 lcnt[128];
    int tid = threadIdx.x;
    int b = blockIdx.x;
    int base = b << 7;
    if (tid < 128) lcnt[tid] = 0;
    __syncthreads();
    u32 m = bcnt[b]; if (m > SEGCAP) m = SEGCAP;
    const u32* sp = seg + (size_t)b * SEGCAP;
    for (u32 e = tid; e < m; e += 256) {
        u32 pkv = sp[e];
        u32 dst = pkv >> 16, src = pkv & 0xffffu;
        u32 p = atomicAdd(&lcnt[dst - (u32)base], 1u);
        if (p < ELLW) srcs16[dst * ELLW + p] = (u16)src;
        else {
            int q = atomicAdd(&cnt[NNODES], 1);   // rare spill
            ovbuf[q] = make_int2((int)dst, (int)src);
        }
    }
    __syncthreads();
    if (tid < 128 && base + tid < NNODES) cnt[base + tid] = (int)lcnt[tid];
}

// ---------------- layer-1 scores es/ed = x·v  +  cast x -> bf16 table xc ----------------
__global__ void esed1_kernel(const float* __restrict__ x, const float* __restrict__ vbuf,
                             float* __restrict__ es, float* __restrict__ ed,
                             u16* __restrict__ xc) {
    __shared__ float vl[512];
    int tid = threadIdx.x;
    vl[tid] = vbuf[tid];
    vl[tid + 256] = vbuf[tid + 256];
    __syncthreads();
    int lane = tid & 63, wave = tid >> 6;
    int i = lane >> 2, q = lane & 3;
    int node = blockIdx.x * 64 + wave * 16 + i;
    const float* xp = x + (size_t)node * 64 + q * 16;
    float xr[16];
    *(float4*)&xr[0]  = ((const float4*)xp)[0];
    *(float4*)&xr[4]  = ((const float4*)xp)[1];
    *(float4*)&xr[8]  = ((const float4*)xp)[2];
    *(float4*)&xr[12] = ((const float4*)xp)[3];
    float p[8];
#pragma unroll
    for (int h = 0; h < 8; h++) {
        float s = 0.f;
#pragma unroll
        for (int j = 0; j < 16; j++) s += xr[j] * vl[h * 64 + q * 16 + j];
        p[h] = s;
    }
#pragma unroll
    for (int h = 0; h < 8; h++) {
        p[h] += __shfl_xor(p[h], 1);
        p[h] += __shfl_xor(p[h], 2);
    }
    es[node * 4 + q] = p[q];
    ed[node * 4 + q] = p[4 + q];
    u16* cp = xc + (size_t)node * 64 + q * 16;
#pragma unroll
    for (int j = 0; j < 16; j += 4) {
        ushort4 o; o.x = f2bf(xr[j]); o.y = f2bf(xr[j + 1]);
        o.z = f2bf(xr[j + 2]); o.w = f2bf(xr[j + 3]);
        *(ushort4*)(cp + j) = o;
    }
}

// ---------------- layer-1 aggregation over x (64-dim rows, 128B) ----------------
__global__ void gat_agg_kernel(const u16* __restrict__ xc,
                               const float* __restrict__ es, const float* __restrict__ ed,
                               const int* __restrict__ cnt, const u16* __restrict__ srcs16,
                               const int2* __restrict__ ovbuf,
                               u16* __restrict__ agg, int n) {
    __shared__ float wbuf[4][4][100];
    __shared__ u32   sbuf[4][ELLW];
    int wave = threadIdx.x >> 6;
    int wid = (blockIdx.x * blockDim.x + threadIdx.x) >> 6;
    int lane = threadIdx.x & 63;
    if (wid >= n) return;

    int degt = cnt[wid];
    int mainc = degt < ELLW ? degt : ELLW;
    int padt = (mainc + 7) & ~7;
    const u16* sp = srcs16 + (size_t)wid * ELLW;

    const int h = lane & 3;
    const int esub = lane >> 2;
    float edh = ed[(size_t)wid * 4 + h];

    // ---- phase 1 ----
    float den = 0.f;
    for (int i0 = 0; i0 < padt; i0 += 16) {
        int e = i0 + esub;
        if (e < padt) {
            float w = 0.f; u32 off = 0;
            if (e < mainc) {
                int s = sp[e];
                off = (u32)s << 7;
                float v = es[(size_t)s * 4 + h] + edh;
                v = v > 0.f ? v : 0.2f * v;
                w = __expf(v);
            }
            wbuf[wave][h][e] = w;
            if (h == 0) sbuf[wave][e] = off;
            den += w;
        }
    }
    int ovn = 0;
    if (degt > ELLW) {
        ovn = cnt[n];
        for (int j = esub; j < ovn; j += 16) {
            int2 t = ovbuf[j];
            if (t.x == wid) {
                float v = es[(size_t)t.y * 4 + h] + edh;
                v = v > 0.f ? v : 0.2f * v;
                den += __expf(v);
            }
        }
    }
#pragma unroll
    for (int o = 4; o < 64; o <<= 1) den += __shfl_xor(den, o);
    float inv = 1.f / (den + 1e-16f);

    // ---- phase 2: gather 128B rows, accumulate all 4 heads ----
    const int e2 = lane >> 5, f16 = lane & 31;
    const char* hp = (const char*)xc + f16 * 4;
    v2f a0 = {0.f, 0.f}, a1 = {0.f, 0.f}, a2 = {0.f, 0.f}, a3 = {0.f, 0.f};
    for (int eb = 0; eb < padt; eb += 8) {
        u32 of[4]; u32 g[4];
        float w0[4], w1[4], w2[4], w3[4];
#pragma unroll
        for (int k = 0; k < 4; k++) of[k] = sbuf[wave][eb + 2 * k + e2];
#pragma unroll
        for (int k = 0; k < 4; k++) g[k] = *(const u32*)(hp + of[k]);
#pragma unroll
        for (int k = 0; k < 4; k++) {
            int e = eb + 2 * k + e2;
            w0[k] = wbuf[wave][0][e]; w1[k] = wbuf[wave][1][e];
            w2[k] = wbuf[wave][2][e]; w3[k] = wbuf[wave][3][e];
        }
#pragma unroll
        for (int k = 0; k < 4; k++) {
            v2f hx;
            hx.x = __uint_as_float(g[k] << 16);
            hx.y = __uint_as_float(g[k] & 0xffff0000u);
            a0 += v2f{w0[k], w0[k]} * hx;
            a1 += v2f{w1[k], w1[k]} * hx;
            a2 += v2f{w2[k], w2[k]} * hx;
            a3 += v2f{w3[k], w3[k]} * hx;
        }
    }
    if (degt > ELLW) {
        for (int j = 0; j < ovn; j++) {
            int2 t = ovbuf[j];
            if (t.x != wid) continue;
            float wh[4];
#pragma unroll
            for (int hh = 0; hh < 4; hh++) {
                float v = es[(size_t)t.y * 4 + hh] + __shfl(edh, hh);
                v = v > 0.f ? v : 0.2f * v;
                wh[hh] = __expf(v);
            }
            if (lane < 32) {
                u32 g = *(const u32*)(hp + ((u32)t.y << 7));
                v2f hx;
                hx.x = __uint_as_float(g << 16);
                hx.y = __uint_as_float(g & 0xffff0000u);
                a0 += v2f{wh[0], wh[0]} * hx;
                a1 += v2f{wh[1], wh[1]} * hx;
                a2 += v2f{wh[2], wh[2]} * hx;
                a3 += v2f{wh[3], wh[3]} * hx;
            }
        }
    }
    a0.x += __shfl_xor(a0.x, 32); a0.y += __shfl_xor(a0.y, 32);
    a1.x += __shfl_xor(a1.x, 32); a1.y += __shfl_xor(a1.y, 32);
    a2.x += __shfl_xor(a2.x, 32); a2.y += __shfl_xor(a2.y, 32);
    a3.x += __shfl_xor(a3.x, 32); a3.y += __shfl_xor(a3.y, 32);
    float iv[4];
#pragma unroll
    for (int hh = 0; hh < 4; hh++) iv[hh] = __shfl(inv, hh);
    if (lane < 32) {
        u32* op = (u32*)agg + (size_t)wid * 128 + f16;
        op[0]  = ((u32)f2bf(a0.y * iv[0]) << 16) | f2bf(a0.x * iv[0]);
        op[32] = ((u32)f2bf(a1.y * iv[1]) << 16) | f2bf(a1.x * iv[1]);
        op[64] = ((u32)f2bf(a2.y * iv[2]) << 16) | f2bf(a2.x * iv[2]);
        op[96] = ((u32)f2bf(a3.y * iv[3]) << 16) | f2bf(a3.x * iv[3]);
    }
}

// ---------------- layer-1 post-GEMM (block-diagonal per head) + bias + LN + ReLU -> xb bf16 ----------------
__global__ void w1ln_kernel(const u16* __restrict__ agg, const u16* __restrict__ B,
                            const float* __restrict__ bias,
                            const float* __restrict__ lng, const float* __restrict__ lnb,
                            u16* __restrict__ xb, int M) {
    using bfrag = __attribute__((ext_vector_type(8))) short;
    using ffrag = __attribute__((ext_vector_type(4))) float;
    int wave = threadIdx.x >> 6, lane = threadIdx.x & 63;
    int lm = lane & 15, kg = (lane >> 4) * 8;
    int rowblk = blockIdx.x * 64 + wave * 16;
    ffrag acc[16] = {};
#pragma unroll
    for (int hh = 0; hh < 4; hh++) {
#pragma unroll
        for (int k0 = 0; k0 < 64; k0 += 32) {
            bfrag af = *(const bfrag*)(agg + (size_t)(rowblk + lm) * 256 + hh * 64 + kg + k0);
#pragma unroll
            for (int tt = 0; tt < 4; tt++) {
                int t = hh * 4 + tt;
                bfrag bf = *(const bfrag*)(B + (size_t)(hh * 64 + tt * 16 + lm) * 64 + kg + k0);
                acc[t] = __builtin_amdgcn_mfma_f32_16x16x32_bf16(af, bf, acc[t], 0, 0, 0);
            }
        }
    }
    int orow = rowblk + (lane >> 4) * 4;
    float bi[16], gg[16], bb[16];
#pragma unroll
    for (int t = 0; t < 16; t++) {
        int col = t * 16 + lm;
        bi[t] = bias[col]; gg[t] = lng[col]; bb[t] = lnb[col];
    }
#pragma unroll
    for (int r = 0; r < 4; r++) {
        float pv[16];
        float s1 = 0.f, s2 = 0.f;
#pragma unroll
        for (int t = 0; t < 16; t++) {
            float v = acc[t][r] + bi[t];
            pv[t] = v; s1 += v; s2 += v * v;
        }
#pragma unroll
        for (int o = 1; o < 16; o <<= 1) { s1 += __shfl_xor(s1, o); s2 += __shfl_xor(s2, o); }
        float mu = s1 / 256.f;
        float var = s2 / 256.f - mu * mu;
        float rstd = rsqrtf(var + 1e-5f);
#pragma unroll
        for (int t = 0; t < 16; t++) {
            float v = (pv[t] - mu) * rstd * gg[t] + bb[t];
            v = v > 0.f ? v : 0.f;
            xb[(size_t)(orow + r) * 256 + t * 16 + lm] = f2bf(v);
        }
    }
}

// ---------------- GEMM (128-wide N tile) + fused attention scores (layers 2,3) ----------------
template <int H, int C, bool AF32>
__global__ void gemm_scores_kernel(const void* __restrict__ Aptr, const u16* __restrict__ B,
                                   u16* __restrict__ Cout,
                                   const float* __restrict__ as, const float* __restrict__ ad,
                                   float* __restrict__ es, float* __restrict__ ed,
                                   int M, int Nn, int K) {
    constexpr int HT = 128 / C;
    using bfrag = __attribute__((ext_vector_type(8))) short;
    using ffrag = __attribute__((ext_vector_type(4))) float;
    int wave = threadIdx.x >> 6, lane = threadIdx.x & 63;
    int lm = lane & 15, kg = (lane >> 4) * 8;
    int rowblk = blockIdx.x * 64 + wave * 16;
    int n0 = blockIdx.y * 128;
    const u16* Bp = B + (size_t)(n0 + lm) * K + kg;
    ffrag acc[8] = {};
    for (int k0 = 0; k0 < K; k0 += 32) {
        bfrag af;
        if constexpr (AF32) {
            const float* ap = (const float*)Aptr + (size_t)(rowblk + lm) * K + kg + k0;
            float4 a0 = *(const float4*)ap;
            float4 a1 = *(const float4*)(ap + 4);
            af[0] = (short)f2bf(a0.x); af[1] = (short)f2bf(a0.y);
            af[2] = (short)f2bf(a0.z); af[3] = (short)f2bf(a0.w);
            af[4] = (short)f2bf(a1.x); af[5] = (short)f2bf(a1.y);
            af[6] = (short)f2bf(a1.z); af[7] = (short)f2bf(a1.w);
        } else {
            af = *(const bfrag*)((const u16*)Aptr + (size_t)(rowblk + lm) * K + kg + k0);
        }
#pragma unroll
        for (int t = 0; t < 8; t++) {
            bfrag bf = *(const bfrag*)(Bp + (size_t)t * 16 * K + k0);
            acc[t] = __builtin_amdgcn_mfma_f32_16x16x32_bf16(af, bf, acc[t], 0, 0, 0);
        }
    }
    int orow = rowblk + (lane >> 4) * 4;   // C/D: col = lane&15, row = (lane>>4)*4 + reg
    float asv[8], adv[8];
#pragma unroll
    for (int t = 0; t < 8; t++) {
        int fcol = n0 + t * 16 + lm;
        asv[t] = as[fcol]; adv[t] = ad[fcol];
    }
    float ps[4][HT] = {}, pd[4][HT] = {};
#pragma unroll
    for (int t = 0; t < 8; t++) {
        const int hh = t / (C / 16);
#pragma unroll
        for (int r = 0; r < 4; r++) {
            float v = acc[t][r];
            ps[r][hh] += v * asv[t];
            pd[r][hh] += v * adv[t];
            Cout[(size_t)(orow + r) * Nn + n0 + t * 16 + lm] = f2bf(v);
        }
    }
    int hb = blockIdx.y * HT;
#pragma unroll
    for (int r = 0; r < 4; r++)
#pragma unroll
        for (int hh = 0; hh < HT; hh++) {
            float s = ps[r][hh], d = pd[r][hh];
#pragma unroll
            for (int o = 1; o < 16; o <<= 1) { s += __shfl_xor(s, o); d += __shfl_xor(d, o); }
            if (lm == 0) {
                es[(size_t)(orow + r) * H + hb + hh] = s;
                ed[(size_t)(orow + r) * H + hb + hh] = d;
            }
        }
}

// ---------------- fused GAT softmax + aggregation (R1 chassis), layers 2,3 ----------------
template <int H, int C, bool LNRELU>
__global__ void gat_fused_kernel(const u16* __restrict__ hmat,
                                 const float* __restrict__ es, const float* __restrict__ ed,
                                 const int* __restrict__ cnt, const u16* __restrict__ srcs16,
                                 const int2* __restrict__ ovbuf,
                                 const float* __restrict__ bias,
                                 const float* __restrict__ lng, const float* __restrict__ lnb,
                                 void* __restrict__ out, int n) {
    constexpr int HC = H * C;
    constexpr int VPT = HC / 64;
    constexpr int SH = (HC == 256) ? 9 : 8;      // byte-offset shift for h rows
    constexpr int EPW = 64 / H;                  // edges per phase-1 pass
    constexpr int HSH = (H == 4) ? 2 : ((H == 2) ? 1 : 0);
    __shared__ float wbuf[4][H][100];
    __shared__ int   sbuf[4][ELLW];
    int wave = threadIdx.x >> 6;
    int wid = (blockIdx.x * blockDim.x + threadIdx.x) >> 6;
    int lane = threadIdx.x & 63;
    if (wid >= n) return;

    int degt = cnt[wid];
    int mainc = degt < ELLW ? degt : ELLW;
    int pad = (mainc + 7) & ~7;
    const u16* sp = srcs16 + (size_t)wid * ELLW;

    const int h = lane & (H - 1);
    const int esub = lane >> HSH;
    float edh = ed[(size_t)wid * H + h];

    // ---- phase 1 ----
    float den = 0.f;
    for (int i0 = 0; i0 < pad; i0 += EPW) {
        int e = i0 + esub;
        if (e < pad) {
            float w = 0.f;
            int soff = 0;
            if (e < mainc) {
                int s = sp[e];
                soff = s << SH;
                float v = es[(size_t)s * H + h] + edh;
                v = v > 0.f ? v : 0.2f * v;
                w = __expf(v);
            }
            wbuf[wave][h][e] = w;
            if (h == 0) sbuf[wave][e] = soff;
            den += w;
        }
    }
    int ovn = 0;
    if (degt > ELLW) {
        ovn = cnt[n];
        for (int j = esub; j < ovn; j += EPW) {
            int2 t = ovbuf[j];
            if (t.x == wid) {
                float v = es[(size_t)t.y * H + h] + edh;
                v = v > 0.f ? v : 0.2f * v;
                den += __expf(v);
            }
        }
    }
#pragma unroll
    for (int o = H; o < 64; o <<= 1) den += __shfl_xor(den, o);
    float inv = 1.f / (den + 1e-16f);

    // ---- phase 2: 8-deep batches ----
    const int myhead = (lane * VPT) / C;
    const float invh = __shfl(inv, myhead);
    const int loff = lane * (VPT * 2);
    v2f a01 = {0.f, 0.f}, a23 = {0.f, 0.f};

    for (int e = 0; e < pad; e += 8) {
        int4   o0 = *(const int4*)&sbuf[wave][e];
        int4   o1 = *(const int4*)&sbuf[wave][e + 4];
        float4 w0 = *(const float4*)&wbuf[wave][myhead][e];
        float4 w1 = *(const float4*)&wbuf[wave][myhead][e + 4];
        int   oo[8] = {o0.x, o0.y, o0.z, o0.w, o1.x, o1.y, o1.z, o1.w};
        float ww[8] = {w0.x, w0.y, w0.z, w0.w, w1.x, w1.y, w1.z, w1.w};
        if constexpr (VPT == 4) {
            uint2 gg[8];
#pragma unroll
            for (int u = 0; u < 8; u++)
                gg[u] = *(const uint2*)((const char*)hmat + (size_t)(u32)oo[u] + loff);
#pragma unroll
            for (int u = 0; u < 8; u++) {
                v2f wv = {ww[u], ww[u]};
                v2f h01, h23;
                h01.x = __uint_as_float(gg[u].x << 16);
                h01.y = __uint_as_float(gg[u].x & 0xffff0000u);
                h23.x = __uint_as_float(gg[u].y << 16);
                h23.y = __uint_as_float(gg[u].y & 0xffff0000u);
                a01 += wv * h01;
                a23 += wv * h23;
            }
        } else {
            u32 gg[8];
#pragma unroll
            for (int u = 0; u < 8; u++)
                gg[u] = *(const u32*)((const char*)hmat + (size_t)(u32)oo[u] + loff);
#pragma unroll
            for (int u = 0; u < 8; u++) {
                v2f wv = {ww[u], ww[u]};
                v2f h01;
                h01.x = __uint_as_float(gg[u] << 16);
                h01.y = __uint_as_float(gg[u] & 0xffff0000u);
                a01 += wv * h01;
            }
        }
    }
    if (degt > ELLW) {
        const float edm = __shfl(edh, myhead);
        for (int j = 0; j < ovn; j++) {
            int2 t = ovbuf[j];
            if (t.x != wid) continue;
            float v = es[(size_t)t.y * H + myhead] + edm;
            v = v > 0.f ? v : 0.2f * v;
            float w = __expf(v);
            v2f wv = {w, w};
            if constexpr (VPT == 4) {
                uint2 g = *(const uint2*)((const char*)hmat + ((size_t)t.y << SH) + loff);
                v2f h01, h23;
                h01.x = __uint_as_float(g.x << 16);
                h01.y = __uint_as_float(g.x & 0xffff0000u);
                h23.x = __uint_as_float(g.y << 16);
                h23.y = __uint_as_float(g.y & 0xffff0000u);
                a01 += wv * h01;
                a23 += wv * h23;
            } else {
                u32 g = *(const u32*)((const char*)hmat + ((size_t)t.y << SH) + loff);
                v2f h01;
                h01.x = __uint_as_float(g << 16);
                h01.y = __uint_as_float(g & 0xffff0000u);
                a01 += wv * h01;
            }
        }
    }
    {
        v2f iv = {invh, invh};
        a01 *= iv;
        a23 *= iv;
    }

    int fbase = lane * VPT;
    float y[VPT];
    y[0] = a01.x + bias[fbase + 0];
    y[1] = a01.y + bias[fbase + 1];
    if constexpr (VPT == 4) {
        y[2] = a23.x + bias[fbase + 2];
        y[3] = a23.y + bias[fbase + 3];
    }

    if constexpr (LNRELU) {
        float s1 = 0.f, s2 = 0.f;
#pragma unroll
        for (int j = 0; j < VPT; j++) { s1 += y[j]; s2 += y[j] * y[j]; }
        s1 = wave_sum(s1);
        s2 = wave_sum(s2);
        float mu = s1 / (float)HC;
        float var = s2 / (float)HC - mu * mu;
        float rstd = rsqrtf(var + 1e-5f);
#pragma unroll
        for (int j = 0; j < VPT; j++) {
            float v = (y[j] - mu) * rstd * lng[fbase + j] + lnb[fbase + j];
            y[j] = v > 0.f ? v : 0.f;
        }
        u16* op = (u16*)out + (size_t)wid * HC + fbase;
        if constexpr (VPT == 4) {
            ushort4 o; o.x = f2bf(y[0]); o.y = f2bf(y[1]); o.z = f2bf(y[2]); o.w = f2bf(y[3]);
            *(ushort4*)op = o;
        } else {
            ushort2 o; o.x = f2bf(y[0]); o.y = f2bf(y[1]);
            *(ushort2*)op = o;
        }
    } else {
        float* op = (float*)out + (size_t)wid * HC + fbase;
        if constexpr (VPT == 4) *(float4*)op = make_float4(y[0], y[1], y[2], y[3]);
        else                    *(float2*)op = make_float2(y[0], y[1]);
    }
}

// ---------------- PointNet layers 1+2 fused ----------------
__global__ void gemm_pn12_kernel(const float* __restrict__ pos,
                                 const float* __restrict__ pw1, const float* __restrict__ pb1,
                                 const float* __restrict__ bn1g, const float* __restrict__ bn1b,
                                 const u16* __restrict__ B, u16* __restrict__ Cout,
                                 const float* __restrict__ pb2,
                                 const float* __restrict__ bn2g, const float* __restrict__ bn2b,
                                 int M) {
    const int Nn = 128, K = 64;
    using bfrag = __attribute__((ext_vector_type(8))) short;
    using ffrag = __attribute__((ext_vector_type(4))) float;
    int wave = threadIdx.x >> 6, lane = threadIdx.x & 63;
    int lm = lane & 15, kg = (lane >> 4) * 8;
    int rowblk = blockIdx.x * 64 + wave * 16;
    int row = rowblk + lm;
    float p0 = pos[row * 3 + 0], p1 = pos[row * 3 + 1], p2 = pos[row * 3 + 2];
    const u16* Bp = B + (size_t)lm * K + kg;
    const float bnscale = rsqrtf(1.0f + 1e-5f);
    ffrag acc[8] = {};
#pragma unroll
    for (int k0 = 0; k0 < K; k0 += 32) {
        bfrag af;
#pragma unroll
        for (int j = 0; j < 8; j++) {
            int k = kg + k0 + j;
            float v = p0 * pw1[k * 3 + 0] + p1 * pw1[k * 3 + 1] + p2 * pw1[k * 3 + 2] + pb1[k];
            v = v * (bn1g[k] * bnscale) + bn1b[k];
            v = v > 0.f ? v : 0.f;
            af[j] = (short)f2bf(v);
        }
#pragma unroll
        for (int t = 0; t < 8; t++) {
            bfrag bf = *(const bfrag*)(Bp + (size_t)t * 16 * K + k0);
            acc[t] = __builtin_amdgcn_mfma_f32_16x16x32_bf16(af, bf, acc[t], 0, 0, 0);
        }
    }
    int orow = rowblk + (lane >> 4) * 4;
#pragma unroll
    for (int t = 0; t < 8; t++) {
        int col = t * 16 + lm;
        float bi = pb2[col], g = bn2g[col] * bnscale, bb = bn2b[col];
#pragma unroll
        for (int r = 0; r < 4; r++) {
            float v = (acc[t][r] + bi) * g + bb;
            v = v > 0.f ? v : 0.f;
            Cout[(size_t)(orow + r) * Nn + col] = f2bf(v);
        }
    }
}

// ---------------- final: interleaved blocks — even: out = cvt(x3)@fw1^T + p2@M2^T + cv
//                                              odd:  pf = p2@pw3^T + pb3
// No LDS, no barrier; pf and out are independent (M2 = fw2@pw3 precomputed).
__global__ void gemm_final_kernel(const u16* __restrict__ p2, const u16* __restrict__ pw3c,
                                  const float* __restrict__ pb3, float* __restrict__ pf,
                                  const float* __restrict__ x3, const u16* __restrict__ fwc,
                                  const u16* __restrict__ m2c, const float* __restrict__ cvb,
                                  float* __restrict__ outp, int M) {
    using bfrag = __attribute__((ext_vector_type(8))) short;
    using ffrag = __attribute__((ext_vector_type(4))) float;
    int wave = threadIdx.x >> 6, lane = threadIdx.x & 63;
    int lm = lane & 15, kg = (lane >> 4) * 8;
    int task = blockIdx.x & 1;
    int rowblk = (blockIdx.x >> 1) * 64 + wave * 16;
    ffrag acc[8] = {};
    if (task) {
        // ---- pf tile (K=128) ----
        const u16* Ap = p2 + (size_t)(rowblk + lm) * 128 + kg;
        const u16* Bp = pw3c + (size_t)lm * 128 + kg;
#pragma unroll
        for (int k0 = 0; k0 < 128; k0 += 32) {
            bfrag af = *(const bfrag*)(Ap + k0);
#pragma unroll
            for (int t = 0; t < 8; t++) {
                bfrag bf = *(const bfrag*)(Bp + (size_t)t * 16 * 128 + k0);
                acc[t] = __builtin_amdgcn_mfma_f32_16x16x32_bf16(af, bf, acc[t], 0, 0, 0);
            }
        }
        int orow = rowblk + (lane >> 4) * 4;
#pragma unroll
        for (int t = 0; t < 8; t++) {
            int col = t * 16 + lm;
            float bi = pb3[col];
#pragma unroll
            for (int r = 0; r < 4; r++)
                pf[(size_t)(orow + r) * 128 + col] = acc[t][r] + bi;
        }
    } else {
        // ---- out tile: x3 half (f32->bf16) then p2 half (bf16) ----
        int row = rowblk + lm;
        const u16* Bp1 = fwc + (size_t)lm * 256 + kg;
#pragma unroll
        for (int k0 = 0; k0 < 128; k0 += 32) {
            const float* ap = x3 + (size_t)row * 128 + kg + k0;
            float4 a0 = *(const float4*)ap;
            float4 a1 = *(const float4*)(ap + 4);
            bfrag af;
            af[0] = (short)f2bf(a0.x); af[1] = (short)f2bf(a0.y);
            af[2] = (short)f2bf(a0.z); af[3] = (short)f2bf(a0.w);
            af[4] = (short)f2bf(a1.x); af[5] = (short)f2bf(a1.y);
            af[6] = (short)f2bf(a1.z); af[7] = (short)f2bf(a1.w);
#pragma unroll
            for (int t = 0; t < 8; t++) {
                bfrag bf = *(const bfrag*)(Bp1 + (size_t)t * 16 * 256 + k0);
                acc[t] = __builtin_amdgcn_mfma_f32_16x16x32_bf16(af, bf, acc[t], 0, 0, 0);
            }
        }
        const u16* Ap2 = p2 + (size_t)row * 128 + kg;
        const u16* Bp2 = m2c + (size_t)lm * 128 + kg;
#pragma unroll
        for (int k0 = 0; k0 < 128; k0 += 32) {
            bfrag af = *(const bfrag*)(Ap2 + k0);
#pragma unroll
            for (int t = 0; t < 8; t++) {
                bfrag bf = *(const bfrag*)(Bp2 + (size_t)t * 16 * 128 + k0);
                acc[t] = __builtin_amdgcn_mfma_f32_16x16x32_bf16(af, bf, acc[t], 0, 0, 0);
            }
        }
        int orow = rowblk + (lane >> 4) * 4;
#pragma unroll
        for (int t = 0; t < 8; t++) {
            int col = t * 16 + lm;
            float bi = cvb[col];
#pragma unroll
            for (int r = 0; r < 4; r++)
                outp[(size_t)(orow + r) * 128 + col] = acc[t][r] + bi;
        }
    }
}

extern "C" void kernel_launch(void* const* d_in, const int* in_sizes, int n_in,
                              void* d_out, int out_size, void* d_ws, size_t ws_size,
                              hipStream_t stream) {
    const float* x    = (const float*)d_in[0];
    const int*   ei   = (const int*)d_in[1];
    const float* pos  = (const float*)d_in[2];
    const float* W1   = (const float*)d_in[3];
    const float* as1  = (const float*)d_in[4];
    const float* ad1  = (const float*)d_in[5];
    const float* bg1  = (const float*)d_in[6];
    const float* ln1g = (const float*)d_in[7];
    const float* ln1b = (const float*)d_in[8];
    const float* W2   = (const float*)d_in[9];
    const float* as2  = (const float*)d_in[10];
    const float* ad2  = (const float*)d_in[11];
    const float* bg2  = (const float*)d_in[12];
    const float* ln2g = (const float*)d_in[13];
    const float* ln2b = (const float*)d_in[14];
    const float* W3   = (const float*)d_in[15];
    const float* as3  = (const float*)d_in[16];
    const float* ad3  = (const float*)d_in[17];
    const float* bg3  = (const float*)d_in[18];
    const float* pw1  = (const float*)d_in[19];
    const float* pb1  = (const float*)d_in[20];
    const float* bn1g = (const float*)d_in[21];
    const float* bn1b = (const float*)d_in[22];
    const float* pw2  = (const float*)d_in[23];
    const float* pb2  = (const float*)d_in[24];
    const float* bn2g = (const float*)d_in[25];
    const float* bn2b = (const float*)d_in[26];
    const float* pw3  = (const float*)d_in[27];
    const float* pb3  = (const float*)d_in[28];
    const float* fw   = (const float*)d_in[29];
    const float* fb   = (const float*)d_in[30];

    const int N = NNODES;
    float* out = (float*)d_out;                    // [N,128]
    float* x3  = out + (size_t)N * 128;            // [N,128]
    float* pf  = out + (size_t)2 * N * 128;        // [N,128]

    char* ws = (char*)d_ws;
    size_t off = 0;
    auto alloc = [&](size_t bytes) -> void* {
        void* p = ws + off;
        off += (bytes + 255) / 256 * 256;
        return p;
    };
    int*   cnt    = (int*)alloc((size_t)(N + 1 + NBUCK) * 4);  // degrees + spill count + bucket cursors
    u32*   bcnt   = (u32*)(cnt + N + 1);
    u32*   seg    = (u32*)alloc((size_t)NBUCK * SEGCAP * 4);   // bucketed packed (dst<<16|src)
    u16*   srcs16 = (u16*)alloc((size_t)N * ELLW * 2);
    int2*  ovbuf  = (int2*)alloc((size_t)NETOT * 8);
    float* esb    = (float*)alloc((size_t)N * 4 * 4);
    float* edb    = (float*)alloc((size_t)N * 4 * 4);
    u16*   w1c    = (u16*)alloc(16384 * 2);
    u16*   w2c    = (u16*)alloc(32768 * 2);
    u16*   w3c    = (u16*)alloc(16384 * 2);
    u16*   pw2c   = (u16*)alloc(8192 * 2);
    u16*   pw3c   = (u16*)alloc(16384 * 2);
    u16*   fwc    = (u16*)alloc(32768 * 2);
    u16*   m2c    = (u16*)alloc(16384 * 2);             // M2 = fw2 @ pw3 (bf16)
    float* cvb    = (float*)alloc(128 * 4);             // cv = fw2 @ pb3 + fb
    u16*   hbufb  = (u16*)alloc((size_t)N * 128 * 2);   // layers 2,3 h tables
    u16*   xb     = (u16*)alloc((size_t)N * 256 * 2);
    u16*   p2b    = (u16*)alloc((size_t)N * 128 * 2);
    u16*   xc     = (u16*)alloc((size_t)N * 64 * 2);    // layer-1 bf16 x table
    float* vbuf   = (float*)alloc(512 * 4);             // v_s/v_d [8][64]
    u16*   aggb   = (u16*)alloc((size_t)N * 256 * 2);   // layer-1 aggregate (bf16)

    // ---- graph build (2 phases) + weight cast + prep_v + M2/cv ----
    hipMemsetAsync(cnt, 0, (size_t)(N + 1 + NBUCK) * 4, stream);
    build_a_kernel<<<ACB + 18, 1024, 0, stream>>>(
        ei, bcnt, seg, W1, as1, ad1, vbuf, pw3, pb3, fw, fb, m2c, cvb,
        W1, w1c, 4096, W2, w2c, 8192, W3, w3c, 4096,
        pw2, pw2c, 2048, pw3, pw3c, 4096, fw, fwc, 8192);
    build_b_kernel<<<NBUCK, 256, 0, stream>>>(seg, bcnt, cnt, srcs16, ovbuf);

    const int NW = N / 4;   // one-wave-per-node kernels
    const int GB = N / 64;  // 625 GEMM row-blocks

    // ---- PointNet layers 1+2 ----
    gemm_pn12_kernel<<<GB, 256, 0, stream>>>(
        pos, pw1, pb1, bn1g, bn1b, pw2c, p2b, pb2, bn2g, bn2b, N);

    // ---- GAT layer 1 (aggregate-then-transform) ----
    esed1_kernel<<<GB, 256, 0, stream>>>(x, vbuf, esb, edb, xc);
    gat_agg_kernel<<<NW, 256, 0, stream>>>(xc, esb, edb, cnt, srcs16, ovbuf, aggb, N);
    w1ln_kernel<<<GB, 256, 0, stream>>>(aggb, w1c, bg1, ln1g, ln1b, xb, N);

    // ---- GAT layer 2 ----
    gemm_scores_kernel<2, 64, false><<<dim3(GB, 1), 256, 0, stream>>>(
        xb, w2c, hbufb, as2, ad2, esb, edb, N, 128, 256);
    gat_fused_kernel<2, 64, true><<<NW, 256, 0, stream>>>(
        hbufb, esb, edb, cnt, srcs16, ovbuf, bg2, ln2g, ln2b, xb, N);

    // ---- GAT layer 3 (out f32 -> x3) ----
    gemm_scores_kernel<1, 128, false><<<dim3(GB, 1), 256, 0, stream>>>(
        xb, w3c, hbufb, as3, ad3, esb, edb, N, 128, 128);
    gat_fused_kernel<1, 128, false><<<NW, 256, 0, stream>>>(
        hbufb, esb, edb, cnt, srcs16, ovbuf, bg3, nullptr, nullptr, x3, N);

    // ---- final: out + pf (independent, interleaved blocks, no LDS) ----
    gemm_final_kernel<<<2 * GB, 256, 0, stream>>>(
        p2b, pw3c, pb3, pf, x3, fwc, m2c, cvb, out, N);
}

// Round 8
// 359.475 us; speedup vs baseline: 1.0277x; 1.0277x over previous
//
#include <hip/hip_runtime.h>
#include <cstddef>

#define NNODES 40000
#define NEDGES 640000
#define NETOT  (NNODES + NEDGES)
#define ELLW   96          // fixed edge slots per node; overflow -> spill list
#define NCAST  30720       // float4 groups across the 6 weight tensors
#define NBUCK  313         // dst>>7 buckets (128 nodes each)
#define SEGCAP 8192        // pairs per bucket segment (expected ~2300, +129 sigma)
#define ABLOCKS 84         // ceil(NETOT / 8192) edge-bucketing blocks
#define CBLOCKS 30         // NCAST / 1024 weight-cast blocks

typedef unsigned short u16;
typedef unsigned int   u32;
using v2f = __attribute__((ext_vector_type(2))) float;

// ---------------- helpers ----------------
__device__ inline float wave_sum(float v) {
#pragma unroll
    for (int o = 32; o > 0; o >>= 1) v += __shfl_xor(v, o);
    return v;
}
__device__ inline u16 f2bf(float f) {   // round-to-nearest-even f32 -> bf16
    u32 u = __float_as_uint(f);
    return (u16)((u + 0x7fffu + ((u >> 16) & 1u)) >> 16);
}

// ---------------- build phase A: bucket edges by dst range + weight cast + prep_v ----
__global__ void build_a_kernel(const int* __restrict__ ei, u32* __restrict__ bcnt,
                               u32* __restrict__ seg,
                               const float* __restrict__ W1, const float* __restrict__ as1,
                               const float* __restrict__ ad1, float* __restrict__ vbuf,
                               const float* s0, u16* d0, int n0, const float* s1, u16* d1, int n1,
                               const float* s2, u16* d2, int n2, const float* s3, u16* d3, int n3,
                               const float* s4, u16* d4, int n4, const float* s5, u16* d5, int n5) {
    int tid = threadIdx.x;
    int blk = blockIdx.x;
    if (blk >= ABLOCKS) {
        if (blk < ABLOCKS + CBLOCKS) {            // ---- weight cast ----
            int i = (blk - ABLOCKS) * 1024 + tid;
            const float* s; u16* d;
            if      (i < n0) { s = s0; d = d0; }
            else if ((i -= n0) < n1) { s = s1; d = d1; }
            else if ((i -= n1) < n2) { s = s2; d = d2; }
            else if ((i -= n2) < n3) { s = s3; d = d3; }
            else if ((i -= n3) < n4) { s = s4; d = d4; }
            else if ((i -= n4) < n5) { s = s5; d = d5; }
            else return;
            float4 v = ((const float4*)s)[i];
            ushort4 o; o.x = f2bf(v.x); o.y = f2bf(v.y); o.z = f2bf(v.z); o.w = f2bf(v.w);
            ((ushort4*)d)[i] = o;
        } else if (tid < 256) {                   // ---- prep_v: v_s[h]=W_h^T a_s[h], v_d ----
            int h = tid >> 6, k = tid & 63;
            float ss = 0.f, dd = 0.f;
            for (int c = 0; c < 64; c++) {
                float w = W1[(h * 64 + c) * 64 + k];
                ss += as1[h * 64 + c] * w;
                dd += ad1[h * 64 + c] * w;
            }
            vbuf[tid] = ss;
            vbuf[256 + tid] = dd;
        }
        return;
    }
    __shared__ u32 hist[NBUCK], hbase[NBUCK];
    for (int i = tid; i < NBUCK; i += 1024) hist[i] = 0;
    __syncthreads();
    u32 pk[8], loc[8]; int bj[8];
    int g0 = blk * 8192;
#pragma unroll
    for (int j = 0; j < 8; j++) {
        int g = g0 + j * 1024 + tid;
        bj[j] = -1;
        if (g < NETOT) {
            int src, dst;
            if (g < NEDGES) { src = ei[g]; dst = ei[NEDGES + g]; }
            else            { src = g - NEDGES; dst = src; }
            int b = dst >> 7;
            pk[j] = ((u32)dst << 16) | (u32)src;
            bj[j] = b;
            loc[j] = atomicAdd(&hist[b], 1u);
        }
    }
    __syncthreads();
    for (int i = tid; i < NBUCK; i += 1024) {
        u32 c = hist[i];
        hbase[i] = c ? atomicAdd(&bcnt[i], c) : 0u;
    }
    __syncthreads();
#pragma unroll
    for (int j = 0; j < 8; j++) {
        if (bj[j] >= 0) {
            u32 pos = hbase[bj[j]] + loc[j];
            if (pos < SEGCAP) seg[(size_t)bj[j] * SEGCAP + pos] = pk[j];
        }
    }
}

// ---------------- build phase B: per-bucket ELL fill (LDS slot counters, XCD-local writes) ----
__global__ void build_b_kernel(const u32* __restrict__ seg, const u32* __restrict__ bcnt,
                               int* __restrict__ cnt, u16* __restrict__ srcs16,
                               int2* __restrict__ ovbuf) {
    __shared__ u32 lcnt[128];
    int tid = threadIdx.x;
    int b = blockIdx.x;
    int base = b << 7;
    if (tid < 128) lcnt[tid] = 0;
    __syncthreads();
    u32 m = bcnt[b]; if (m > SEGCAP) m = SEGCAP;
    const u32* sp = seg + (size_t)b * SEGCAP;
    for (u32 e = tid; e < m; e += 256) {
        u32 pkv = sp[e];
        u32 dst = pkv >> 16, src = pkv & 0xffffu;
        u32 p = atomicAdd(&lcnt[dst - (u32)base], 1u);
        if (p < ELLW) srcs16[dst * ELLW + p] = (u16)src;
        else {
            int q = atomicAdd(&cnt[NNODES], 1);   // rare spill
            ovbuf[q] = make_int2((int)dst, (int)src);
        }
    }
    __syncthreads();
    if (tid < 128 && base + tid < NNODES) cnt[base + tid] = (int)lcnt[tid];
}

// ---------------- layer-1 scores es/ed = x·v  +  cast x -> bf16 table xc ----------------
__global__ void esed1_kernel(const float* __restrict__ x, const float* __restrict__ vbuf,
                             float* __restrict__ es, float* __restrict__ ed,
                             u16* __restrict__ xc) {
    __shared__ float vl[512];
    int tid = threadIdx.x;
    vl[tid] = vbuf[tid];
    vl[tid + 256] = vbuf[tid + 256];
    __syncthreads();
    int lane = tid & 63, wave = tid >> 6;
    int i = lane >> 2, q = lane & 3;
    int node = blockIdx.x * 64 + wave * 16 + i;
    const float* xp = x + (size_t)node * 64 + q * 16;
    float xr[16];
    *(float4*)&xr[0]  = ((const float4*)xp)[0];
    *(float4*)&xr[4]  = ((const float4*)xp)[1];
    *(float4*)&xr[8]  = ((const float4*)xp)[2];
    *(float4*)&xr[12] = ((const float4*)xp)[3];
    float p[8];
#pragma unroll
    for (int h = 0; h < 8; h++) {
        float s = 0.f;
#pragma unroll
        for (int j = 0; j < 16; j++) s += xr[j] * vl[h * 64 + q * 16 + j];
        p[h] = s;
    }
#pragma unroll
    for (int h = 0; h < 8; h++) {
        p[h] += __shfl_xor(p[h], 1);
        p[h] += __shfl_xor(p[h], 2);
    }
    es[node * 4 + q] = p[q];
    ed[node * 4 + q] = p[4 + q];
    u16* cp = xc + (size_t)node * 64 + q * 16;
#pragma unroll
    for (int j = 0; j < 16; j += 4) {
        ushort4 o; o.x = f2bf(xr[j]); o.y = f2bf(xr[j + 1]);
        o.z = f2bf(xr[j + 2]); o.w = f2bf(xr[j + 3]);
        *(ushort4*)(cp + j) = o;
    }
}

// ---------------- layer-1 aggregation over x (64-dim rows, 128B) ----------------
__global__ void gat_agg_kernel(const u16* __restrict__ xc,
                               const float* __restrict__ es, const float* __restrict__ ed,
                               const int* __restrict__ cnt, const u16* __restrict__ srcs16,
                               const int2* __restrict__ ovbuf,
                               u16* __restrict__ agg, int n) {
    __shared__ float wbuf[4][4][100];
    __shared__ u32   sbuf[4][ELLW];
    int wave = threadIdx.x >> 6;
    int wid = (blockIdx.x * blockDim.x + threadIdx.x) >> 6;
    int lane = threadIdx.x & 63;
    if (wid >= n) return;

    int degt = cnt[wid];
    int mainc = degt < ELLW ? degt : ELLW;
    int padt = (mainc + 7) & ~7;
    const u16* sp = srcs16 + (size_t)wid * ELLW;

    const int h = lane & 3;
    const int esub = lane >> 2;
    float edh = ed[(size_t)wid * 4 + h];

    // ---- phase 1 ----
    float den = 0.f;
    for (int i0 = 0; i0 < padt; i0 += 16) {
        int e = i0 + esub;
        if (e < padt) {
            float w = 0.f; u32 off = 0;
            if (e < mainc) {
                int s = sp[e];
                off = (u32)s << 7;
                float v = es[(size_t)s * 4 + h] + edh;
                v = v > 0.f ? v : 0.2f * v;
                w = __expf(v);
            }
            wbuf[wave][h][e] = w;
            if (h == 0) sbuf[wave][e] = off;
            den += w;
        }
    }
    int ovn = 0;
    if (degt > ELLW) {
        ovn = cnt[n];
        for (int j = esub; j < ovn; j += 16) {
            int2 t = ovbuf[j];
            if (t.x == wid) {
                float v = es[(size_t)t.y * 4 + h] + edh;
                v = v > 0.f ? v : 0.2f * v;
                den += __expf(v);
            }
        }
    }
#pragma unroll
    for (int o = 4; o < 64; o <<= 1) den += __shfl_xor(den, o);
    float inv = 1.f / (den + 1e-16f);

    // ---- phase 2: gather 128B rows, accumulate all 4 heads ----
    const int e2 = lane >> 5, f16 = lane & 31;
    const char* hp = (const char*)xc + f16 * 4;
    v2f a0 = {0.f, 0.f}, a1 = {0.f, 0.f}, a2 = {0.f, 0.f}, a3 = {0.f, 0.f};
    for (int eb = 0; eb < padt; eb += 8) {
        u32 of[4]; u32 g[4];
        float w0[4], w1[4], w2[4], w3[4];
#pragma unroll
        for (int k = 0; k < 4; k++) of[k] = sbuf[wave][eb + 2 * k + e2];
#pragma unroll
        for (int k = 0; k < 4; k++) g[k] = *(const u32*)(hp + of[k]);
#pragma unroll
        for (int k = 0; k < 4; k++) {
            int e = eb + 2 * k + e2;
            w0[k] = wbuf[wave][0][e]; w1[k] = wbuf[wave][1][e];
            w2[k] = wbuf[wave][2][e]; w3[k] = wbuf[wave][3][e];
        }
#pragma unroll
        for (int k = 0; k < 4; k++) {
            v2f hx;
            hx.x = __uint_as_float(g[k] << 16);
            hx.y = __uint_as_float(g[k] & 0xffff0000u);
            a0 += v2f{w0[k], w0[k]} * hx;
            a1 += v2f{w1[k], w1[k]} * hx;
            a2 += v2f{w2[k], w2[k]} * hx;
            a3 += v2f{w3[k], w3[k]} * hx;
        }
    }
    if (degt > ELLW) {
        for (int j = 0; j < ovn; j++) {
            int2 t = ovbuf[j];
            if (t.x != wid) continue;
            float wh[4];
#pragma unroll
            for (int hh = 0; hh < 4; hh++) {
                float v = es[(size_t)t.y * 4 + hh] + __shfl(edh, hh);
                v = v > 0.f ? v : 0.2f * v;
                wh[hh] = __expf(v);
            }
            if (lane < 32) {
                u32 g = *(const u32*)(hp + ((u32)t.y << 7));
                v2f hx;
                hx.x = __uint_as_float(g << 16);
                hx.y = __uint_as_float(g & 0xffff0000u);
                a0 += v2f{wh[0], wh[0]} * hx;
                a1 += v2f{wh[1], wh[1]} * hx;
                a2 += v2f{wh[2], wh[2]} * hx;
                a3 += v2f{wh[3], wh[3]} * hx;
            }
        }
    }
    a0.x += __shfl_xor(a0.x, 32); a0.y += __shfl_xor(a0.y, 32);
    a1.x += __shfl_xor(a1.x, 32); a1.y += __shfl_xor(a1.y, 32);
    a2.x += __shfl_xor(a2.x, 32); a2.y += __shfl_xor(a2.y, 32);
    a3.x += __shfl_xor(a3.x, 32); a3.y += __shfl_xor(a3.y, 32);
    float iv[4];
#pragma unroll
    for (int hh = 0; hh < 4; hh++) iv[hh] = __shfl(inv, hh);
    if (lane < 32) {
        u32* op = (u32*)agg + (size_t)wid * 128 + f16;
        op[0]  = ((u32)f2bf(a0.y * iv[0]) << 16) | f2bf(a0.x * iv[0]);
        op[32] = ((u32)f2bf(a1.y * iv[1]) << 16) | f2bf(a1.x * iv[1]);
        op[64] = ((u32)f2bf(a2.y * iv[2]) << 16) | f2bf(a2.x * iv[2]);
        op[96] = ((u32)f2bf(a3.y * iv[3]) << 16) | f2bf(a3.x * iv[3]);
    }
}

// ---------------- layer-1 post-GEMM (block-diagonal per head) + bias + LN + ReLU -> xb bf16 ----------------
__global__ void w1ln_kernel(const u16* __restrict__ agg, const u16* __restrict__ B,
                            const float* __restrict__ bias,
                            const float* __restrict__ lng, const float* __restrict__ lnb,
                            u16* __restrict__ xb, int M) {
    using bfrag = __attribute__((ext_vector_type(8))) short;
    using ffrag = __attribute__((ext_vector_type(4))) float;
    int wave = threadIdx.x >> 6, lane = threadIdx.x & 63;
    int lm = lane & 15, kg = (lane >> 4) * 8;
    int rowblk = blockIdx.x * 64 + wave * 16;
    ffrag acc[16] = {};
#pragma unroll
    for (int hh = 0; hh < 4; hh++) {
#pragma unroll
        for (int k0 = 0; k0 < 64; k0 += 32) {
            bfrag af = *(const bfrag*)(agg + (size_t)(rowblk + lm) * 256 + hh * 64 + kg + k0);
#pragma unroll
            for (int tt = 0; tt < 4; tt++) {
                int t = hh * 4 + tt;
                bfrag bf = *(const bfrag*)(B + (size_t)(hh * 64 + tt * 16 + lm) * 64 + kg + k0);
                acc[t] = __builtin_amdgcn_mfma_f32_16x16x32_bf16(af, bf, acc[t], 0, 0, 0);
            }
        }
    }
    int orow = rowblk + (lane >> 4) * 4;
    float bi[16], gg[16], bb[16];
#pragma unroll
    for (int t = 0; t < 16; t++) {
        int col = t * 16 + lm;
        bi[t] = bias[col]; gg[t] = lng[col]; bb[t] = lnb[col];
    }
#pragma unroll
    for (int r = 0; r < 4; r++) {
        float pv[16];
        float s1 = 0.f, s2 = 0.f;
#pragma unroll
        for (int t = 0; t < 16; t++) {
            float v = acc[t][r] + bi[t];
            pv[t] = v; s1 += v; s2 += v * v;
        }
#pragma unroll
        for (int o = 1; o < 16; o <<= 1) { s1 += __shfl_xor(s1, o); s2 += __shfl_xor(s2, o); }
        float mu = s1 / 256.f;
        float var = s2 / 256.f - mu * mu;
        float rstd = rsqrtf(var + 1e-5f);
#pragma unroll
        for (int t = 0; t < 16; t++) {
            float v = (pv[t] - mu) * rstd * gg[t] + bb[t];
            v = v > 0.f ? v : 0.f;
            xb[(size_t)(orow + r) * 256 + t * 16 + lm] = f2bf(v);
        }
    }
}

// ---------------- GEMM (128-wide N tile) + fused attention scores (layers 2,3) ----------------
template <int H, int C, bool AF32>
__global__ void gemm_scores_kernel(const void* __restrict__ Aptr, const u16* __restrict__ B,
                                   u16* __restrict__ Cout,
                                   const float* __restrict__ as, const float* __restrict__ ad,
                                   float* __restrict__ es, float* __restrict__ ed,
                                   int M, int Nn, int K) {
    constexpr int HT = 128 / C;
    using bfrag = __attribute__((ext_vector_type(8))) short;
    using ffrag = __attribute__((ext_vector_type(4))) float;
    int wave = threadIdx.x >> 6, lane = threadIdx.x & 63;
    int lm = lane & 15, kg = (lane >> 4) * 8;
    int rowblk = blockIdx.x * 64 + wave * 16;
    int n0 = blockIdx.y * 128;
    const u16* Bp = B + (size_t)(n0 + lm) * K + kg;
    ffrag acc[8] = {};
    for (int k0 = 0; k0 < K; k0 += 32) {
        bfrag af;
        if constexpr (AF32) {
            const float* ap = (const float*)Aptr + (size_t)(rowblk + lm) * K + kg + k0;
            float4 a0 = *(const float4*)ap;
            float4 a1 = *(const float4*)(ap + 4);
            af[0] = (short)f2bf(a0.x); af[1] = (short)f2bf(a0.y);
            af[2] = (short)f2bf(a0.z); af[3] = (short)f2bf(a0.w);
            af[4] = (short)f2bf(a1.x); af[5] = (short)f2bf(a1.y);
            af[6] = (short)f2bf(a1.z); af[7] = (short)f2bf(a1.w);
        } else {
            af = *(const bfrag*)((const u16*)Aptr + (size_t)(rowblk + lm) * K + kg + k0);
        }
#pragma unroll
        for (int t = 0; t < 8; t++) {
            bfrag bf = *(const bfrag*)(Bp + (size_t)t * 16 * K + k0);
            acc[t] = __builtin_amdgcn_mfma_f32_16x16x32_bf16(af, bf, acc[t], 0, 0, 0);
        }
    }
    int orow = rowblk + (lane >> 4) * 4;   // C/D: col = lane&15, row = (lane>>4)*4 + reg
    float asv[8], adv[8];
#pragma unroll
    for (int t = 0; t < 8; t++) {
        int fcol = n0 + t * 16 + lm;
        asv[t] = as[fcol]; adv[t] = ad[fcol];
    }
    float ps[4][HT] = {}, pd[4][HT] = {};
#pragma unroll
    for (int t = 0; t < 8; t++) {
        const int hh = t / (C / 16);
#pragma unroll
        for (int r = 0; r < 4; r++) {
            float v = acc[t][r];
            ps[r][hh] += v * asv[t];
            pd[r][hh] += v * adv[t];
            Cout[(size_t)(orow + r) * Nn + n0 + t * 16 + lm] = f2bf(v);
        }
    }
    int hb = blockIdx.y * HT;
#pragma unroll
    for (int r = 0; r < 4; r++)
#pragma unroll
        for (int hh = 0; hh < HT; hh++) {
            float s = ps[r][hh], d = pd[r][hh];
#pragma unroll
            for (int o = 1; o < 16; o <<= 1) { s += __shfl_xor(s, o); d += __shfl_xor(d, o); }
            if (lm == 0) {
                es[(size_t)(orow + r) * H + hb + hh] = s;
                ed[(size_t)(orow + r) * H + hb + hh] = d;
            }
        }
}

// ---------------- fused GAT softmax + aggregation (R1 chassis), layers 2,3 ----------------
template <int H, int C, bool LNRELU>
__global__ void gat_fused_kernel(const u16* __restrict__ hmat,
                                 const float* __restrict__ es, const float* __restrict__ ed,
                                 const int* __restrict__ cnt, const u16* __restrict__ srcs16,
                                 const int2* __restrict__ ovbuf,
                                 const float* __restrict__ bias,
                                 const float* __restrict__ lng, const float* __restrict__ lnb,
                                 void* __restrict__ out, int n) {
    constexpr int HC = H * C;
    constexpr int VPT = HC / 64;
    constexpr int SH = (HC == 256) ? 9 : 8;      // byte-offset shift for h rows
    constexpr int EPW = 64 / H;                  // edges per phase-1 pass
    constexpr int HSH = (H == 4) ? 2 : ((H == 2) ? 1 : 0);
    __shared__ float wbuf[4][H][100];
    __shared__ int   sbuf[4][ELLW];
    int wave = threadIdx.x >> 6;
    int wid = (blockIdx.x * blockDim.x + threadIdx.x) >> 6;
    int lane = threadIdx.x & 63;
    if (wid >= n) return;

    int degt = cnt[wid];
    int mainc = degt < ELLW ? degt : ELLW;
    int pad = (mainc + 7) & ~7;
    const u16* sp = srcs16 + (size_t)wid * ELLW;

    const int h = lane & (H - 1);
    const int esub = lane >> HSH;
    float edh = ed[(size_t)wid * H + h];

    // ---- phase 1 ----
    float den = 0.f;
    for (int i0 = 0; i0 < pad; i0 += EPW) {
        int e = i0 + esub;
        if (e < pad) {
            float w = 0.f;
            int soff = 0;
            if (e < mainc) {
                int s = sp[e];
                soff = s << SH;
                float v = es[(size_t)s * H + h] + edh;
                v = v > 0.f ? v : 0.2f * v;
                w = __expf(v);
            }
            wbuf[wave][h][e] = w;
            if (h == 0) sbuf[wave][e] = soff;
            den += w;
        }
    }
    int ovn = 0;
    if (degt > ELLW) {
        ovn = cnt[n];
        for (int j = esub; j < ovn; j += EPW) {
            int2 t = ovbuf[j];
            if (t.x == wid) {
                float v = es[(size_t)t.y * H + h] + edh;
                v = v > 0.f ? v : 0.2f * v;
                den += __expf(v);
            }
        }
    }
#pragma unroll
    for (int o = H; o < 64; o <<= 1) den += __shfl_xor(den, o);
    float inv = 1.f / (den + 1e-16f);

    // ---- phase 2: 8-deep batches ----
    const int myhead = (lane * VPT) / C;
    const float invh = __shfl(inv, myhead);
    const int loff = lane * (VPT * 2);
    v2f a01 = {0.f, 0.f}, a23 = {0.f, 0.f};

    for (int e = 0; e < pad; e += 8) {
        int4   o0 = *(const int4*)&sbuf[wave][e];
        int4   o1 = *(const int4*)&sbuf[wave][e + 4];
        float4 w0 = *(const float4*)&wbuf[wave][myhead][e];
        float4 w1 = *(const float4*)&wbuf[wave][myhead][e + 4];
        int   oo[8] = {o0.x, o0.y, o0.z, o0.w, o1.x, o1.y, o1.z, o1.w};
        float ww[8] = {w0.x, w0.y, w0.z, w0.w, w1.x, w1.y, w1.z, w1.w};
        if constexpr (VPT == 4) {
            uint2 gg[8];
#pragma unroll
            for (int u = 0; u < 8; u++)
                gg[u] = *(const uint2*)((const char*)hmat + (size_t)(u32)oo[u] + loff);
#pragma unroll
            for (int u = 0; u < 8; u++) {
                v2f wv = {ww[u], ww[u]};
                v2f h01, h23;
                h01.x = __uint_as_float(gg[u].x << 16);
                h01.y = __uint_as_float(gg[u].x & 0xffff0000u);
                h23.x = __uint_as_float(gg[u].y << 16);
                h23.y = __uint_as_float(gg[u].y & 0xffff0000u);
                a01 += wv * h01;
                a23 += wv * h23;
            }
        } else {
            u32 gg[8];
#pragma unroll
            for (int u = 0; u < 8; u++)
                gg[u] = *(const u32*)((const char*)hmat + (size_t)(u32)oo[u] + loff);
#pragma unroll
            for (int u = 0; u < 8; u++) {
                v2f wv = {ww[u], ww[u]};
                v2f h01;
                h01.x = __uint_as_float(gg[u] << 16);
                h01.y = __uint_as_float(gg[u] & 0xffff0000u);
                a01 += wv * h01;
            }
        }
    }
    if (degt > ELLW) {
        const float edm = __shfl(edh, myhead);
        for (int j = 0; j < ovn; j++) {
            int2 t = ovbuf[j];
            if (t.x != wid) continue;
            float v = es[(size_t)t.y * H + myhead] + edm;
            v = v > 0.f ? v : 0.2f * v;
            float w = __expf(v);
            v2f wv = {w, w};
            if constexpr (VPT == 4) {
                uint2 g = *(const uint2*)((const char*)hmat + ((size_t)t.y << SH) + loff);
                v2f h01, h23;
                h01.x = __uint_as_float(g.x << 16);
                h01.y = __uint_as_float(g.x & 0xffff0000u);
                h23.x = __uint_as_float(g.y << 16);
                h23.y = __uint_as_float(g.y & 0xffff0000u);
                a01 += wv * h01;
                a23 += wv * h23;
            } else {
                u32 g = *(const u32*)((const char*)hmat + ((size_t)t.y << SH) + loff);
                v2f h01;
                h01.x = __uint_as_float(g << 16);
                h01.y = __uint_as_float(g & 0xffff0000u);
                a01 += wv * h01;
            }
        }
    }
    {
        v2f iv = {invh, invh};
        a01 *= iv;
        a23 *= iv;
    }

    int fbase = lane * VPT;
    float y[VPT];
    y[0] = a01.x + bias[fbase + 0];
    y[1] = a01.y + bias[fbase + 1];
    if constexpr (VPT == 4) {
        y[2] = a23.x + bias[fbase + 2];
        y[3] = a23.y + bias[fbase + 3];
    }

    if constexpr (LNRELU) {
        float s1 = 0.f, s2 = 0.f;
#pragma unroll
        for (int j = 0; j < VPT; j++) { s1 += y[j]; s2 += y[j] * y[j]; }
        s1 = wave_sum(s1);
        s2 = wave_sum(s2);
        float mu = s1 / (float)HC;
        float var = s2 / (float)HC - mu * mu;
        float rstd = rsqrtf(var + 1e-5f);
#pragma unroll
        for (int j = 0; j < VPT; j++) {
            float v = (y[j] - mu) * rstd * lng[fbase + j] + lnb[fbase + j];
            y[j] = v > 0.f ? v : 0.f;
        }
        u16* op = (u16*)out + (size_t)wid * HC + fbase;
        if constexpr (VPT == 4) {
            ushort4 o; o.x = f2bf(y[0]); o.y = f2bf(y[1]); o.z = f2bf(y[2]); o.w = f2bf(y[3]);
            *(ushort4*)op = o;
        } else {
            ushort2 o; o.x = f2bf(y[0]); o.y = f2bf(y[1]);
            *(ushort2*)op = o;
        }
    } else {
        float* op = (float*)out + (size_t)wid * HC + fbase;
        if constexpr (VPT == 4) *(float4*)op = make_float4(y[0], y[1], y[2], y[3]);
        else                    *(float2*)op = make_float2(y[0], y[1]);
    }
}

// ---------------- PointNet layers 1+2 fused ----------------
__global__ void gemm_pn12_kernel(const float* __restrict__ pos,
                                 const float* __restrict__ pw1, const float* __restrict__ pb1,
                                 const float* __restrict__ bn1g, const float* __restrict__ bn1b,
                                 const u16* __restrict__ B, u16* __restrict__ Cout,
                                 const float* __restrict__ pb2,
                                 const float* __restrict__ bn2g, const float* __restrict__ bn2b,
                                 int M) {
    const int Nn = 128, K = 64;
    using bfrag = __attribute__((ext_vector_type(8))) short;
    using ffrag = __attribute__((ext_vector_type(4))) float;
    int wave = threadIdx.x >> 6, lane = threadIdx.x & 63;
    int lm = lane & 15, kg = (lane >> 4) * 8;
    int rowblk = blockIdx.x * 64 + wave * 16;
    int row = rowblk + lm;
    float p0 = pos[row * 3 + 0], p1 = pos[row * 3 + 1], p2 = pos[row * 3 + 2];
    const u16* Bp = B + (size_t)lm * K + kg;
    const float bnscale = rsqrtf(1.0f + 1e-5f);
    ffrag acc[8] = {};
#pragma unroll
    for (int k0 = 0; k0 < K; k0 += 32) {
        bfrag af;
#pragma unroll
        for (int j = 0; j < 8; j++) {
            int k = kg + k0 + j;
            float v = p0 * pw1[k * 3 + 0] + p1 * pw1[k * 3 + 1] + p2 * pw1[k * 3 + 2] + pb1[k];
            v = v * (bn1g[k] * bnscale) + bn1b[k];
            v = v > 0.f ? v : 0.f;
            af[j] = (short)f2bf(v);
        }
#pragma unroll
        for (int t = 0; t < 8; t++) {
            bfrag bf = *(const bfrag*)(Bp + (size_t)t * 16 * K + k0);
            acc[t] = __builtin_amdgcn_mfma_f32_16x16x32_bf16(af, bf, acc[t], 0, 0, 0);
        }
    }
    int orow = rowblk + (lane >> 4) * 4;
#pragma unroll
    for (int t = 0; t < 8; t++) {
        int col = t * 16 + lm;
        float bi = pb2[col], g = bn2g[col] * bnscale, bb = bn2b[col];
#pragma unroll
        for (int r = 0; r < 4; r++) {
            float v = (acc[t][r] + bi) * g + bb;
            v = v > 0.f ? v : 0.f;
            Cout[(size_t)(orow + r) * Nn + col] = f2bf(v);
        }
    }
}

// ---------------- fused: pf = p2@pw3^T + pb3; out = [x3|pf]@fw^T + fb ----------------
// Both output tiles are staged in LDS (pft) then written COALESCED (float4, 512B rows).
__global__ void gemm_pw3cat_kernel(const u16* __restrict__ p2, const u16* __restrict__ Bpw3,
                                   const float* __restrict__ pb3, float* __restrict__ pf,
                                   const float* __restrict__ x3, const u16* __restrict__ Bfw,
                                   const float* __restrict__ fb, float* __restrict__ outp,
                                   int M) {
    using bfrag = __attribute__((ext_vector_type(8))) short;
    using ffrag = __attribute__((ext_vector_type(4))) float;
    __shared__ float pft[64][132];   // stride 132: bank offset 4/row, 16B-aligned rows
    int wave = threadIdx.x >> 6, lane = threadIdx.x & 63;
    int lm = lane & 15, kg = (lane >> 4) * 8;
    int rowblk = blockIdx.x * 64 + wave * 16;
    int rowbase = blockIdx.x * 64;

    // ---- stage 1: pf tile (K=128, Nn=128) -> pft only ----
    {
        const u16* Ap = p2 + (size_t)(rowblk + lm) * 128 + kg;
        const u16* Bp = Bpw3 + (size_t)lm * 128 + kg;
        ffrag acc[8] = {};
#pragma unroll
        for (int k0 = 0; k0 < 128; k0 += 32) {
            bfrag af = *(const bfrag*)(Ap + k0);
#pragma unroll
            for (int t = 0; t < 8; t++) {
                bfrag bf = *(const bfrag*)(Bp + (size_t)t * 16 * 128 + k0);
                acc[t] = __builtin_amdgcn_mfma_f32_16x16x32_bf16(af, bf, acc[t], 0, 0, 0);
            }
        }
        int lrow = wave * 16 + (lane >> 4) * 4;
#pragma unroll
        for (int t = 0; t < 8; t++) {
            int col = t * 16 + lm;
            float bi = pb3[col];
#pragma unroll
            for (int r = 0; r < 4; r++)
                pft[lrow + r][col] = acc[t][r] + bi;
        }
    }
    __syncthreads();

    // ---- coalesced pf write from pft (read-only vs stage-2 reads: no hazard) ----
    for (int i = threadIdx.x; i < 2048; i += 256) {
        int row = i >> 5, c4 = (i & 31) << 2;
        float4 v = *(const float4*)&pft[row][c4];
        *(float4*)&pf[(size_t)(rowbase + row) * 128 + c4] = v;
    }

    // ---- stage 2: out = [x3|pf]@fw^T + fb (K=256, Nn=128) ----
    {
        const u16* Bp = Bfw + (size_t)lm * 256 + kg;
        ffrag acc[8] = {};
        int row = rowblk + lm, lrow = wave * 16 + lm;
#pragma unroll
        for (int k0 = 0; k0 < 256; k0 += 32) {
            bfrag af;
            if (k0 < 128) {
                const float* ap = x3 + (size_t)row * 128 + kg + k0;
                float4 a0 = *(const float4*)ap;
                float4 a1 = *(const float4*)(ap + 4);
                af[0] = (short)f2bf(a0.x); af[1] = (short)f2bf(a0.y);
                af[2] = (short)f2bf(a0.z); af[3] = (short)f2bf(a0.w);
                af[4] = (short)f2bf(a1.x); af[5] = (short)f2bf(a1.y);
                af[6] = (short)f2bf(a1.z); af[7] = (short)f2bf(a1.w);
            } else {
                const float* ap = &pft[lrow][kg + k0 - 128];
                float4 a0 = *(const float4*)ap;
                float4 a1 = *(const float4*)(ap + 4);
                af[0] = (short)f2bf(a0.x); af[1] = (short)f2bf(a0.y);
                af[2] = (short)f2bf(a0.z); af[3] = (short)f2bf(a0.w);
                af[4] = (short)f2bf(a1.x); af[5] = (short)f2bf(a1.y);
                af[6] = (short)f2bf(a1.z); af[7] = (short)f2bf(a1.w);
            }
#pragma unroll
            for (int t = 0; t < 8; t++) {
                bfrag bf = *(const bfrag*)(Bp + (size_t)t * 16 * 256 + k0);
                acc[t] = __builtin_amdgcn_mfma_f32_16x16x32_bf16(af, bf, acc[t], 0, 0, 0);
            }
        }
        __syncthreads();   // all pft reads (stage-2 A-frags + pf copy) done before reuse
        int lrow2 = wave * 16 + (lane >> 4) * 4;
#pragma unroll
        for (int t = 0; t < 8; t++) {
            int col = t * 16 + lm;
            float bi = fb[col];
#pragma unroll
            for (int r = 0; r < 4; r++)
                pft[lrow2 + r][col] = acc[t][r] + bi;
        }
        __syncthreads();
        // ---- coalesced out write from pft ----
        for (int i = threadIdx.x; i < 2048; i += 256) {
            int rw = i >> 5, c4 = (i & 31) << 2;
            float4 v = *(const float4*)&pft[rw][c4];
            *(float4*)&outp[(size_t)(rowbase + rw) * 128 + c4] = v;
        }
    }
}

extern "C" void kernel_launch(void* const* d_in, const int* in_sizes, int n_in,
                              void* d_out, int out_size, void* d_ws, size_t ws_size,
                              hipStream_t stream) {
    const float* x    = (const float*)d_in[0];
    const int*   ei   = (const int*)d_in[1];
    const float* pos  = (const float*)d_in[2];
    const float* W1   = (const float*)d_in[3];
    const float* as1  = (const float*)d_in[4];
    const float* ad1  = (const float*)d_in[5];
    const float* bg1  = (const float*)d_in[6];
    const float* ln1g = (const float*)d_in[7];
    const float* ln1b = (const float*)d_in[8];
    const float* W2   = (const float*)d_in[9];
    const float* as2  = (const float*)d_in[10];
    const float* ad2  = (const float*)d_in[11];
    const float* bg2  = (const float*)d_in[12];
    const float* ln2g = (const float*)d_in[13];
    const float* ln2b = (const float*)d_in[14];
    const float* W3   = (const float*)d_in[15];
    const float* as3  = (const float*)d_in[16];
    const float* ad3  = (const float*)d_in[17];
    const float* bg3  = (const float*)d_in[18];
    const float* pw1  = (const float*)d_in[19];
    const float* pb1  = (const float*)d_in[20];
    const float* bn1g = (const float*)d_in[21];
    const float* bn1b = (const float*)d_in[22];
    const float* pw2  = (const float*)d_in[23];
    const float* pb2  = (const float*)d_in[24];
    const float* bn2g = (const float*)d_in[25];
    const float* bn2b = (const float*)d_in[26];
    const float* pw3  = (const float*)d_in[27];
    const float* pb3  = (const float*)d_in[28];
    const float* fw   = (const float*)d_in[29];
    const float* fb   = (const float*)d_in[30];

    const int N = NNODES;
    float* out = (float*)d_out;                    // [N,128]
    float* x3  = out + (size_t)N * 128;            // [N,128]
    float* pf  = out + (size_t)2 * N * 128;        // [N,128]

    char* ws = (char*)d_ws;
    size_t off = 0;
    auto alloc = [&](size_t bytes) -> void* {
        void* p = ws + off;
        off += (bytes + 255) / 256 * 256;
        return p;
    };
    int*   cnt    = (int*)alloc((size_t)(N + 1 + NBUCK) * 4);  // degrees + spill count + bucket cursors
    u32*   bcnt   = (u32*)(cnt + N + 1);
    u32*   seg    = (u32*)alloc((size_t)NBUCK * SEGCAP * 4);   // bucketed packed (dst<<16|src)
    u16*   srcs16 = (u16*)alloc((size_t)N * ELLW * 2);
    int2*  ovbuf  = (int2*)alloc((size_t)NETOT * 8);
    float* esb    = (float*)alloc((size_t)N * 4 * 4);
    float* edb    = (float*)alloc((size_t)N * 4 * 4);
    u16*   w1c    = (u16*)alloc(16384 * 2);
    u16*   w2c    = (u16*)alloc(32768 * 2);
    u16*   w3c    = (u16*)alloc(16384 * 2);
    u16*   pw2c   = (u16*)alloc(8192 * 2);
    u16*   pw3c   = (u16*)alloc(16384 * 2);
    u16*   fwc    = (u16*)alloc(32768 * 2);
    u16*   hbufb  = (u16*)alloc((size_t)N * 128 * 2);   // layers 2,3 h tables
    u16*   xb     = (u16*)alloc((size_t)N * 256 * 2);
    u16*   p2b    = (u16*)alloc((size_t)N * 128 * 2);
    u16*   xc     = (u16*)alloc((size_t)N * 64 * 2);    // layer-1 bf16 x table
    float* vbuf   = (float*)alloc(512 * 4);             // v_s/v_d [8][64]
    u16*   aggb   = (u16*)alloc((size_t)N * 256 * 2);   // layer-1 aggregate (bf16)

    // ---- graph build (2 phases) + weight cast + prep_v ----
    hipMemsetAsync(cnt, 0, (size_t)(N + 1 + NBUCK) * 4, stream);
    build_a_kernel<<<ABLOCKS + CBLOCKS + 1, 1024, 0, stream>>>(
        ei, bcnt, seg, W1, as1, ad1, vbuf,
        W1, w1c, 4096, W2, w2c, 8192, W3, w3c, 4096,
        pw2, pw2c, 2048, pw3, pw3c, 4096, fw, fwc, 8192);
    build_b_kernel<<<NBUCK, 256, 0, stream>>>(seg, bcnt, cnt, srcs16, ovbuf);

    const int NW = N / 4;   // one-wave-per-node kernels
    const int GB = N / 64;  // 625 GEMM row-blocks

    // ---- PointNet layers 1+2 ----
    gemm_pn12_kernel<<<GB, 256, 0, stream>>>(
        pos, pw1, pb1, bn1g, bn1b, pw2c, p2b, pb2, bn2g, bn2b, N);

    // ---- GAT layer 1 (aggregate-then-transform) ----
    esed1_kernel<<<GB, 256, 0, stream>>>(x, vbuf, esb, edb, xc);
    gat_agg_kernel<<<NW, 256, 0, stream>>>(xc, esb, edb, cnt, srcs16, ovbuf, aggb, N);
    w1ln_kernel<<<GB, 256, 0, stream>>>(aggb, w1c, bg1, ln1g, ln1b, xb, N);

    // ---- GAT layer 2 ----
    gemm_scores_kernel<2, 64, false><<<dim3(GB, 1), 256, 0, stream>>>(
        xb, w2c, hbufb, as2, ad2, esb, edb, N, 128, 256);
    gat_fused_kernel<2, 64, true><<<NW, 256, 0, stream>>>(
        hbufb, esb, edb, cnt, srcs16, ovbuf, bg2, ln2g, ln2b, xb, N);

    // ---- GAT layer 3 (out f32 -> x3) ----
    gemm_scores_kernel<1, 128, false><<<dim3(GB, 1), 256, 0, stream>>>(
        xb, w3c, hbufb, as3, ad3, esb, edb, N, 128, 128);
    gat_fused_kernel<1, 128, false><<<NW, 256, 0, stream>>>(
        hbufb, esb, edb, cnt, srcs16, ovbuf, bg3, nullptr, nullptr, x3, N);

    // ---- pw3 GEMM + fusion GEMM (fused; coalesced f32 epilogues) ----
    gemm_pw3cat_kernel<<<GB, 256, 0, stream>>>(p2b, pw3c, pb3, pf, x3, fwc, fb, out, N);
}

// Round 9
// 354.141 us; speedup vs baseline: 1.0431x; 1.0151x over previous
//
#include <hip/hip_runtime.h>
#include <cstddef>

#define NNODES 40000
#define NEDGES 640000
#define NETOT  (NNODES + NEDGES)
#define ELLW   96          // fixed edge slots per node; overflow -> spill list
#define NCAST  30720       // float4 groups across the 6 weight tensors
#define NBUCK  313         // dst>>7 buckets (128 nodes each)
#define SEGCAP 8192        // pairs per bucket segment (expected ~2300, +129 sigma)
#define ABLOCKS 84         // ceil(NETOT / 8192) edge-bucketing blocks
#define CBLOCKS 30         // NCAST / 1024 weight-cast blocks
#define GBLK   625         // NNODES / 64 row-blocks

typedef unsigned short u16;
typedef unsigned int   u32;
using v2f = __attribute__((ext_vector_type(2))) float;

// ---------------- helpers ----------------
__device__ inline float wave_sum(float v) {
#pragma unroll
    for (int o = 32; o > 0; o >>= 1) v += __shfl_xor(v, o);
    return v;
}
__device__ inline u16 f2bf(float f) {   // round-to-nearest-even f32 -> bf16
    u32 u = __float_as_uint(f);
    return (u16)((u + 0x7fffu + ((u >> 16) & 1u)) >> 16);
}

// ---------------- build phase A: bucket edges by dst range + weight cast + prep_v ----
__global__ void build_a_kernel(const int* __restrict__ ei, u32* __restrict__ bcnt,
                               u32* __restrict__ seg,
                               const float* __restrict__ W1, const float* __restrict__ as1,
                               const float* __restrict__ ad1, float* __restrict__ vbuf,
                               const float* s0, u16* d0, int n0, const float* s1, u16* d1, int n1,
                               const float* s2, u16* d2, int n2, const float* s3, u16* d3, int n3,
                               const float* s4, u16* d4, int n4, const float* s5, u16* d5, int n5) {
    int tid = threadIdx.x;
    int blk = blockIdx.x;
    if (blk >= ABLOCKS) {
        if (blk < ABLOCKS + CBLOCKS) {            // ---- weight cast ----
            int i = (blk - ABLOCKS) * 1024 + tid;
            const float* s; u16* d;
            if      (i < n0) { s = s0; d = d0; }
            else if ((i -= n0) < n1) { s = s1; d = d1; }
            else if ((i -= n1) < n2) { s = s2; d = d2; }
            else if ((i -= n2) < n3) { s = s3; d = d3; }
            else if ((i -= n3) < n4) { s = s4; d = d4; }
            else if ((i -= n4) < n5) { s = s5; d = d5; }
            else return;
            float4 v = ((const float4*)s)[i];
            ushort4 o; o.x = f2bf(v.x); o.y = f2bf(v.y); o.z = f2bf(v.z); o.w = f2bf(v.w);
            ((ushort4*)d)[i] = o;
        } else if (tid < 256) {                   // ---- prep_v: v_s[h]=W_h^T a_s[h], v_d ----
            int h = tid >> 6, k = tid & 63;
            float ss = 0.f, dd = 0.f;
            for (int c = 0; c < 64; c++) {
                float w = W1[(h * 64 + c) * 64 + k];
                ss += as1[h * 64 + c] * w;
                dd += ad1[h * 64 + c] * w;
            }
            vbuf[tid] = ss;
            vbuf[256 + tid] = dd;
        }
        return;
    }
    __shared__ u32 hist[NBUCK], hbase[NBUCK];
    for (int i = tid; i < NBUCK; i += 1024) hist[i] = 0;
    __syncthreads();
    u32 pk[8], loc[8]; int bj[8];
    int g0 = blk * 8192;
#pragma unroll
    for (int j = 0; j < 8; j++) {
        int g = g0 + j * 1024 + tid;
        bj[j] = -1;
        if (g < NETOT) {
            int src, dst;
            if (g < NEDGES) { src = ei[g]; dst = ei[NEDGES + g]; }
            else            { src = g - NEDGES; dst = src; }
            int b = dst >> 7;
            pk[j] = ((u32)dst << 16) | (u32)src;
            bj[j] = b;
            loc[j] = atomicAdd(&hist[b], 1u);
        }
    }
    __syncthreads();
    for (int i = tid; i < NBUCK; i += 1024) {
        u32 c = hist[i];
        hbase[i] = c ? atomicAdd(&bcnt[i], c) : 0u;
    }
    __syncthreads();
#pragma unroll
    for (int j = 0; j < 8; j++) {
        if (bj[j] >= 0) {
            u32 pos = hbase[bj[j]] + loc[j];
            if (pos < SEGCAP) seg[(size_t)bj[j] * SEGCAP + pos] = pk[j];
        }
    }
}

// ---------------- mid kernel: build_b (ELL fill) + esed1 (layer-1 scores/cast) + pn12 ----------------
// Block ranges: [0,NBUCK)=build_b, [NBUCK,NBUCK+GBLK)=esed1, [NBUCK+GBLK,NBUCK+2*GBLK)=pn12.
// All three are independent; inputs come from build_a only.
__global__ void mid_kernel(const u32* __restrict__ seg, const u32* __restrict__ bcnt,
                           int* __restrict__ cnt, u16* __restrict__ srcs16,
                           int2* __restrict__ ovbuf,
                           const float* __restrict__ x, const float* __restrict__ vbuf,
                           float* __restrict__ es, float* __restrict__ ed, u16* __restrict__ xc,
                           const float* __restrict__ pos,
                           const float* __restrict__ pw1, const float* __restrict__ pb1,
                           const float* __restrict__ bn1g, const float* __restrict__ bn1b,
                           const u16* __restrict__ Bpn, u16* __restrict__ p2out,
                           const float* __restrict__ pb2,
                           const float* __restrict__ bn2g, const float* __restrict__ bn2b) {
    __shared__ u32 lcnt[128];
    __shared__ float vl[512];
    int tid = threadIdx.x;
    int blk = blockIdx.x;

    if (blk < NBUCK) {                            // ---- build_b: per-bucket ELL fill ----
        int base = blk << 7;
        if (tid < 128) lcnt[tid] = 0;
        __syncthreads();
        u32 m = bcnt[blk]; if (m > SEGCAP) m = SEGCAP;
        const u32* sp = seg + (size_t)blk * SEGCAP;
        for (u32 e = tid; e < m; e += 256) {
            u32 pkv = sp[e];
            u32 dst = pkv >> 16, src = pkv & 0xffffu;
            u32 p = atomicAdd(&lcnt[dst - (u32)base], 1u);
            if (p < ELLW) srcs16[dst * ELLW + p] = (u16)src;
            else {
                int q = atomicAdd(&cnt[NNODES], 1);   // rare spill
                ovbuf[q] = make_int2((int)dst, (int)src);
            }
        }
        __syncthreads();
        if (tid < 128 && base + tid < NNODES) cnt[base + tid] = (int)lcnt[tid];
        return;
    }
    blk -= NBUCK;
    if (blk < GBLK) {                             // ---- esed1: es/ed = x.v + cast x->bf16 ----
        vl[tid] = vbuf[tid];
        vl[tid + 256] = vbuf[tid + 256];
        __syncthreads();
        int lane = tid & 63, wave = tid >> 6;
        int i = lane >> 2, q = lane & 3;
        int node = blk * 64 + wave * 16 + i;
        const float* xp = x + (size_t)node * 64 + q * 16;
        float xr[16];
        *(float4*)&xr[0]  = ((const float4*)xp)[0];
        *(float4*)&xr[4]  = ((const float4*)xp)[1];
        *(float4*)&xr[8]  = ((const float4*)xp)[2];
        *(float4*)&xr[12] = ((const float4*)xp)[3];
        float p[8];
#pragma unroll
        for (int h = 0; h < 8; h++) {
            float s = 0.f;
#pragma unroll
            for (int j = 0; j < 16; j++) s += xr[j] * vl[h * 64 + q * 16 + j];
            p[h] = s;
        }
#pragma unroll
        for (int h = 0; h < 8; h++) {
            p[h] += __shfl_xor(p[h], 1);
            p[h] += __shfl_xor(p[h], 2);
        }
        es[node * 4 + q] = p[q];
        ed[node * 4 + q] = p[4 + q];
        u16* cp = xc + (size_t)node * 64 + q * 16;
#pragma unroll
        for (int j = 0; j < 16; j += 4) {
            ushort4 o; o.x = f2bf(xr[j]); o.y = f2bf(xr[j + 1]);
            o.z = f2bf(xr[j + 2]); o.w = f2bf(xr[j + 3]);
            *(ushort4*)(cp + j) = o;
        }
        return;
    }
    blk -= GBLK;                                  // ---- pn12: p2 = relu(bn2(relu(bn1(pos@pw1))@pw2)) ----
    {
        const int Nn = 128, K = 64;
        using bfrag = __attribute__((ext_vector_type(8))) short;
        using ffrag = __attribute__((ext_vector_type(4))) float;
        int wave = tid >> 6, lane = tid & 63;
        int lm = lane & 15, kg = (lane >> 4) * 8;
        int rowblk = blk * 64 + wave * 16;
        int row = rowblk + lm;
        float p0 = pos[row * 3 + 0], p1 = pos[row * 3 + 1], p2 = pos[row * 3 + 2];
        const u16* Bp = Bpn + (size_t)lm * K + kg;
        const float bnscale = rsqrtf(1.0f + 1e-5f);
        ffrag acc[8] = {};
#pragma unroll
        for (int k0 = 0; k0 < K; k0 += 32) {
            bfrag af;
#pragma unroll
            for (int j = 0; j < 8; j++) {
                int k = kg + k0 + j;
                float v = p0 * pw1[k * 3 + 0] + p1 * pw1[k * 3 + 1] + p2 * pw1[k * 3 + 2] + pb1[k];
                v = v * (bn1g[k] * bnscale) + bn1b[k];
                v = v > 0.f ? v : 0.f;
                af[j] = (short)f2bf(v);
            }
#pragma unroll
            for (int t = 0; t < 8; t++) {
                bfrag bf = *(const bfrag*)(Bp + (size_t)t * 16 * K + k0);
                acc[t] = __builtin_amdgcn_mfma_f32_16x16x32_bf16(af, bf, acc[t], 0, 0, 0);
            }
        }
        int orow = rowblk + (lane >> 4) * 4;
#pragma unroll
        for (int t = 0; t < 8; t++) {
            int col = t * 16 + lm;
            float bi = pb2[col], g = bn2g[col] * bnscale, bb = bn2b[col];
#pragma unroll
            for (int r = 0; r < 4; r++) {
                float v = (acc[t][r] + bi) * g + bb;
                v = v > 0.f ? v : 0.f;
                p2out[(size_t)(orow + r) * Nn + col] = f2bf(v);
            }
        }
    }
}

// ---------------- layer-1 aggregation over x (64-dim rows, 128B) ----------------
__global__ void gat_agg_kernel(const u16* __restrict__ xc,
                               const float* __restrict__ es, const float* __restrict__ ed,
                               const int* __restrict__ cnt, const u16* __restrict__ srcs16,
                               const int2* __restrict__ ovbuf,
                               u16* __restrict__ agg, int n) {
    __shared__ float wbuf[4][4][100];
    __shared__ u32   sbuf[4][ELLW];
    int wave = threadIdx.x >> 6;
    int wid = (blockIdx.x * blockDim.x + threadIdx.x) >> 6;
    int lane = threadIdx.x & 63;
    if (wid >= n) return;

    int degt = cnt[wid];
    int mainc = degt < ELLW ? degt : ELLW;
    int padt = (mainc + 7) & ~7;
    const u16* sp = srcs16 + (size_t)wid * ELLW;

    const int h = lane & 3;
    const int esub = lane >> 2;
    float edh = ed[(size_t)wid * 4 + h];

    // ---- phase 1 ----
    float den = 0.f;
    for (int i0 = 0; i0 < padt; i0 += 16) {
        int e = i0 + esub;
        if (e < padt) {
            float w = 0.f; u32 off = 0;
            if (e < mainc) {
                int s = sp[e];
                off = (u32)s << 7;
                float v = es[(size_t)s * 4 + h] + edh;
                v = v > 0.f ? v : 0.2f * v;
                w = __expf(v);
            }
            wbuf[wave][h][e] = w;
            if (h == 0) sbuf[wave][e] = off;
            den += w;
        }
    }
    int ovn = 0;
    if (degt > ELLW) {
        ovn = cnt[n];
        for (int j = esub; j < ovn; j += 16) {
            int2 t = ovbuf[j];
            if (t.x == wid) {
                float v = es[(size_t)t.y * 4 + h] + edh;
                v = v > 0.f ? v : 0.2f * v;
                den += __expf(v);
            }
        }
    }
#pragma unroll
    for (int o = 4; o < 64; o <<= 1) den += __shfl_xor(den, o);
    float inv = 1.f / (den + 1e-16f);

    // ---- phase 2: gather 128B rows, accumulate all 4 heads ----
    const int e2 = lane >> 5, f16 = lane & 31;
    const char* hp = (const char*)xc + f16 * 4;
    v2f a0 = {0.f, 0.f}, a1 = {0.f, 0.f}, a2 = {0.f, 0.f}, a3 = {0.f, 0.f};
    for (int eb = 0; eb < padt; eb += 8) {
        u32 of[4]; u32 g[4];
        float w0[4], w1[4], w2[4], w3[4];
#pragma unroll
        for (int k = 0; k < 4; k++) of[k] = sbuf[wave][eb + 2 * k + e2];
#pragma unroll
        for (int k = 0; k < 4; k++) g[k] = *(const u32*)(hp + of[k]);
#pragma unroll
        for (int k = 0; k < 4; k++) {
            int e = eb + 2 * k + e2;
            w0[k] = wbuf[wave][0][e]; w1[k] = wbuf[wave][1][e];
            w2[k] = wbuf[wave][2][e]; w3[k] = wbuf[wave][3][e];
        }
#pragma unroll
        for (int k = 0; k < 4; k++) {
            v2f hx;
            hx.x = __uint_as_float(g[k] << 16);
            hx.y = __uint_as_float(g[k] & 0xffff0000u);
            a0 += v2f{w0[k], w0[k]} * hx;
            a1 += v2f{w1[k], w1[k]} * hx;
            a2 += v2f{w2[k], w2[k]} * hx;
            a3 += v2f{w3[k], w3[k]} * hx;
        }
    }
    if (degt > ELLW) {
        for (int j = 0; j < ovn; j++) {
            int2 t = ovbuf[j];
            if (t.x != wid) continue;
            float wh[4];
#pragma unroll
            for (int hh = 0; hh < 4; hh++) {
                float v = es[(size_t)t.y * 4 + hh] + __shfl(edh, hh);
                v = v > 0.f ? v : 0.2f * v;
                wh[hh] = __expf(v);
            }
            if (lane < 32) {
                u32 g = *(const u32*)(hp + ((u32)t.y << 7));
                v2f hx;
                hx.x = __uint_as_float(g << 16);
                hx.y = __uint_as_float(g & 0xffff0000u);
                a0 += v2f{wh[0], wh[0]} * hx;
                a1 += v2f{wh[1], wh[1]} * hx;
                a2 += v2f{wh[2], wh[2]} * hx;
                a3 += v2f{wh[3], wh[3]} * hx;
            }
        }
    }
    a0.x += __shfl_xor(a0.x, 32); a0.y += __shfl_xor(a0.y, 32);
    a1.x += __shfl_xor(a1.x, 32); a1.y += __shfl_xor(a1.y, 32);
    a2.x += __shfl_xor(a2.x, 32); a2.y += __shfl_xor(a2.y, 32);
    a3.x += __shfl_xor(a3.x, 32); a3.y += __shfl_xor(a3.y, 32);
    float iv[4];
#pragma unroll
    for (int hh = 0; hh < 4; hh++) iv[hh] = __shfl(inv, hh);
    if (lane < 32) {
        u32* op = (u32*)agg + (size_t)wid * 128 + f16;
        op[0]  = ((u32)f2bf(a0.y * iv[0]) << 16) | f2bf(a0.x * iv[0]);
        op[32] = ((u32)f2bf(a1.y * iv[1]) << 16) | f2bf(a1.x * iv[1]);
        op[64] = ((u32)f2bf(a2.y * iv[2]) << 16) | f2bf(a2.x * iv[2]);
        op[96] = ((u32)f2bf(a3.y * iv[3]) << 16) | f2bf(a3.x * iv[3]);
    }
}

// ---------------- layer-1 post-GEMM (block-diagonal per head) + bias + LN + ReLU -> xb bf16 ----------------
__global__ void w1ln_kernel(const u16* __restrict__ agg, const u16* __restrict__ B,
                            const float* __restrict__ bias,
                            const float* __restrict__ lng, const float* __restrict__ lnb,
                            u16* __restrict__ xb, int M) {
    using bfrag = __attribute__((ext_vector_type(8))) short;
    using ffrag = __attribute__((ext_vector_type(4))) float;
    int wave = threadIdx.x >> 6, lane = threadIdx.x & 63;
    int lm = lane & 15, kg = (lane >> 4) * 8;
    int rowblk = blockIdx.x * 64 + wave * 16;
    ffrag acc[16] = {};
#pragma unroll
    for (int hh = 0; hh < 4; hh++) {
#pragma unroll
        for (int k0 = 0; k0 < 64; k0 += 32) {
            bfrag af = *(const bfrag*)(agg + (size_t)(rowblk + lm) * 256 + hh * 64 + kg + k0);
#pragma unroll
            for (int tt = 0; tt < 4; tt++) {
                int t = hh * 4 + tt;
                bfrag bf = *(const bfrag*)(B + (size_t)(hh * 64 + tt * 16 + lm) * 64 + kg + k0);
                acc[t] = __builtin_amdgcn_mfma_f32_16x16x32_bf16(af, bf, acc[t], 0, 0, 0);
            }
        }
    }
    int orow = rowblk + (lane >> 4) * 4;
    float bi[16], gg[16], bb[16];
#pragma unroll
    for (int t = 0; t < 16; t++) {
        int col = t * 16 + lm;
        bi[t] = bias[col]; gg[t] = lng[col]; bb[t] = lnb[col];
    }
#pragma unroll
    for (int r = 0; r < 4; r++) {
        float pv[16];
        float s1 = 0.f, s2 = 0.f;
#pragma unroll
        for (int t = 0; t < 16; t++) {
            float v = acc[t][r] + bi[t];
            pv[t] = v; s1 += v; s2 += v * v;
        }
#pragma unroll
        for (int o = 1; o < 16; o <<= 1) { s1 += __shfl_xor(s1, o); s2 += __shfl_xor(s2, o); }
        float mu = s1 / 256.f;
        float var = s2 / 256.f - mu * mu;
        float rstd = rsqrtf(var + 1e-5f);
#pragma unroll
        for (int t = 0; t < 16; t++) {
            float v = (pv[t] - mu) * rstd * gg[t] + bb[t];
            v = v > 0.f ? v : 0.f;
            xb[(size_t)(orow + r) * 256 + t * 16 + lm] = f2bf(v);
        }
    }
}

// ---------------- GEMM (128-wide N tile) + fused attention scores (layers 2,3) ----------------
template <int H, int C, bool AF32>
__global__ void gemm_scores_kernel(const void* __restrict__ Aptr, const u16* __restrict__ B,
                                   u16* __restrict__ Cout,
                                   const float* __restrict__ as, const float* __restrict__ ad,
                                   float* __restrict__ es, float* __restrict__ ed,
                                   int M, int Nn, int K) {
    constexpr int HT = 128 / C;
    using bfrag = __attribute__((ext_vector_type(8))) short;
    using ffrag = __attribute__((ext_vector_type(4))) float;
    int wave = threadIdx.x >> 6, lane = threadIdx.x & 63;
    int lm = lane & 15, kg = (lane >> 4) * 8;
    int rowblk = blockIdx.x * 64 + wave * 16;
    int n0 = blockIdx.y * 128;
    const u16* Bp = B + (size_t)(n0 + lm) * K + kg;
    ffrag acc[8] = {};
    for (int k0 = 0; k0 < K; k0 += 32) {
        bfrag af;
        if constexpr (AF32) {
            const float* ap = (const float*)Aptr + (size_t)(rowblk + lm) * K + kg + k0;
            float4 a0 = *(const float4*)ap;
            float4 a1 = *(const float4*)(ap + 4);
            af[0] = (short)f2bf(a0.x); af[1] = (short)f2bf(a0.y);
            af[2] = (short)f2bf(a0.z); af[3] = (short)f2bf(a0.w);
            af[4] = (short)f2bf(a1.x); af[5] = (short)f2bf(a1.y);
            af[6] = (short)f2bf(a1.z); af[7] = (short)f2bf(a1.w);
        } else {
            af = *(const bfrag*)((const u16*)Aptr + (size_t)(rowblk + lm) * K + kg + k0);
        }
#pragma unroll
        for (int t = 0; t < 8; t++) {
            bfrag bf = *(const bfrag*)(Bp + (size_t)t * 16 * K + k0);
            acc[t] = __builtin_amdgcn_mfma_f32_16x16x32_bf16(af, bf, acc[t], 0, 0, 0);
        }
    }
    int orow = rowblk + (lane >> 4) * 4;   // C/D: col = lane&15, row = (lane>>4)*4 + reg
    float asv[8], adv[8];
#pragma unroll
    for (int t = 0; t < 8; t++) {
        int fcol = n0 + t * 16 + lm;
        asv[t] = as[fcol]; adv[t] = ad[fcol];
    }
    float ps[4][HT] = {}, pd[4][HT] = {};
#pragma unroll
    for (int t = 0; t < 8; t++) {
        const int hh = t / (C / 16);
#pragma unroll
        for (int r = 0; r < 4; r++) {
            float v = acc[t][r];
            ps[r][hh] += v * asv[t];
            pd[r][hh] += v * adv[t];
            Cout[(size_t)(orow + r) * Nn + n0 + t * 16 + lm] = f2bf(v);
        }
    }
    int hb = blockIdx.y * HT;
#pragma unroll
    for (int r = 0; r < 4; r++)
#pragma unroll
        for (int hh = 0; hh < HT; hh++) {
            float s = ps[r][hh], d = pd[r][hh];
#pragma unroll
            for (int o = 1; o < 16; o <<= 1) { s += __shfl_xor(s, o); d += __shfl_xor(d, o); }
            if (lm == 0) {
                es[(size_t)(orow + r) * H + hb + hh] = s;
                ed[(size_t)(orow + r) * H + hb + hh] = d;
            }
        }
}

// ---------------- fused GAT softmax + aggregation (R1 chassis), layers 2,3 ----------------
template <int H, int C, bool LNRELU>
__global__ void gat_fused_kernel(const u16* __restrict__ hmat,
                                 const float* __restrict__ es, const float* __restrict__ ed,
                                 const int* __restrict__ cnt, const u16* __restrict__ srcs16,
                                 const int2* __restrict__ ovbuf,
                                 const float* __restrict__ bias,
                                 const float* __restrict__ lng, const float* __restrict__ lnb,
                                 void* __restrict__ out, int n) {
    constexpr int HC = H * C;
    constexpr int VPT = HC / 64;
    constexpr int SH = (HC == 256) ? 9 : 8;      // byte-offset shift for h rows
    constexpr int EPW = 64 / H;                  // edges per phase-1 pass
    constexpr int HSH = (H == 4) ? 2 : ((H == 2) ? 1 : 0);
    __shared__ float wbuf[4][H][100];
    __shared__ int   sbuf[4][ELLW];
    int wave = threadIdx.x >> 6;
    int wid = (blockIdx.x * blockDim.x + threadIdx.x) >> 6;
    int lane = threadIdx.x & 63;
    if (wid >= n) return;

    int degt = cnt[wid];
    int mainc = degt < ELLW ? degt : ELLW;
    int pad = (mainc + 7) & ~7;
    const u16* sp = srcs16 + (size_t)wid * ELLW;

    const int h = lane & (H - 1);
    const int esub = lane >> HSH;
    float edh = ed[(size_t)wid * H + h];

    // ---- phase 1 ----
    float den = 0.f;
    for (int i0 = 0; i0 < pad; i0 += EPW) {
        int e = i0 + esub;
        if (e < pad) {
            float w = 0.f;
            int soff = 0;
            if (e < mainc) {
                int s = sp[e];
                soff = s << SH;
                float v = es[(size_t)s * H + h] + edh;
                v = v > 0.f ? v : 0.2f * v;
                w = __expf(v);
            }
            wbuf[wave][h][e] = w;
            if (h == 0) sbuf[wave][e] = soff;
            den += w;
        }
    }
    int ovn = 0;
    if (degt > ELLW) {
        ovn = cnt[n];
        for (int j = esub; j < ovn; j += EPW) {
            int2 t = ovbuf[j];
            if (t.x == wid) {
                float v = es[(size_t)t.y * H + h] + edh;
                v = v > 0.f ? v : 0.2f * v;
                den += __expf(v);
            }
        }
    }
#pragma unroll
    for (int o = H; o < 64; o <<= 1) den += __shfl_xor(den, o);
    float inv = 1.f / (den + 1e-16f);

    // ---- phase 2: 8-deep batches ----
    const int myhead = (lane * VPT) / C;
    const float invh = __shfl(inv, myhead);
    const int loff = lane * (VPT * 2);
    v2f a01 = {0.f, 0.f}, a23 = {0.f, 0.f};

    for (int e = 0; e < pad; e += 8) {
        int4   o0 = *(const int4*)&sbuf[wave][e];
        int4   o1 = *(const int4*)&sbuf[wave][e + 4];
        float4 w0 = *(const float4*)&wbuf[wave][myhead][e];
        float4 w1 = *(const float4*)&wbuf[wave][myhead][e + 4];
        int   oo[8] = {o0.x, o0.y, o0.z, o0.w, o1.x, o1.y, o1.z, o1.w};
        float ww[8] = {w0.x, w0.y, w0.z, w0.w, w1.x, w1.y, w1.z, w1.w};
        if constexpr (VPT == 4) {
            uint2 gg[8];
#pragma unroll
            for (int u = 0; u < 8; u++)
                gg[u] = *(const uint2*)((const char*)hmat + (size_t)(u32)oo[u] + loff);
#pragma unroll
            for (int u = 0; u < 8; u++) {
                v2f wv = {ww[u], ww[u]};
                v2f h01, h23;
                h01.x = __uint_as_float(gg[u].x << 16);
                h01.y = __uint_as_float(gg[u].x & 0xffff0000u);
                h23.x = __uint_as_float(gg[u].y << 16);
                h23.y = __uint_as_float(gg[u].y & 0xffff0000u);
                a01 += wv * h01;
                a23 += wv * h23;
            }
        } else {
            u32 gg[8];
#pragma unroll
            for (int u = 0; u < 8; u++)
                gg[u] = *(const u32*)((const char*)hmat + (size_t)(u32)oo[u] + loff);
#pragma unroll
            for (int u = 0; u < 8; u++) {
                v2f wv = {ww[u], ww[u]};
                v2f h01;
                h01.x = __uint_as_float(gg[u] << 16);
                h01.y = __uint_as_float(gg[u] & 0xffff0000u);
                a01 += wv * h01;
            }
        }
    }
    if (degt > ELLW) {
        const float edm = __shfl(edh, myhead);
        for (int j = 0; j < ovn; j++) {
            int2 t = ovbuf[j];
            if (t.x != wid) continue;
            float v = es[(size_t)t.y * H + myhead] + edm;
            v = v > 0.f ? v : 0.2f * v;
            float w = __expf(v);
            v2f wv = {w, w};
            if constexpr (VPT == 4) {
                uint2 g = *(const uint2*)((const char*)hmat + ((size_t)t.y << SH) + loff);
                v2f h01, h23;
                h01.x = __uint_as_float(g.x << 16);
                h01.y = __uint_as_float(g.x & 0xffff0000u);
                h23.x = __uint_as_float(g.y << 16);
                h23.y = __uint_as_float(g.y & 0xffff0000u);
                a01 += wv * h01;
                a23 += wv * h23;
            } else {
                u32 g = *(const u32*)((const char*)hmat + ((size_t)t.y << SH) + loff);
                v2f h01;
                h01.x = __uint_as_float(g << 16);
                h01.y = __uint_as_float(g & 0xffff0000u);
                a01 += wv * h01;
            }
        }
    }
    {
        v2f iv = {invh, invh};
        a01 *= iv;
        a23 *= iv;
    }

    int fbase = lane * VPT;
    float y[VPT];
    y[0] = a01.x + bias[fbase + 0];
    y[1] = a01.y + bias[fbase + 1];
    if constexpr (VPT == 4) {
        y[2] = a23.x + bias[fbase + 2];
        y[3] = a23.y + bias[fbase + 3];
    }

    if constexpr (LNRELU) {
        float s1 = 0.f, s2 = 0.f;
#pragma unroll
        for (int j = 0; j < VPT; j++) { s1 += y[j]; s2 += y[j] * y[j]; }
        s1 = wave_sum(s1);
        s2 = wave_sum(s2);
        float mu = s1 / (float)HC;
        float var = s2 / (float)HC - mu * mu;
        float rstd = rsqrtf(var + 1e-5f);
#pragma unroll
        for (int j = 0; j < VPT; j++) {
            float v = (y[j] - mu) * rstd * lng[fbase + j] + lnb[fbase + j];
            y[j] = v > 0.f ? v : 0.f;
        }
        u16* op = (u16*)out + (size_t)wid * HC + fbase;
        if constexpr (VPT == 4) {
            ushort4 o; o.x = f2bf(y[0]); o.y = f2bf(y[1]); o.z = f2bf(y[2]); o.w = f2bf(y[3]);
            *(ushort4*)op = o;
        } else {
            ushort2 o; o.x = f2bf(y[0]); o.y = f2bf(y[1]);
            *(ushort2*)op = o;
        }
    } else {
        float* op = (float*)out + (size_t)wid * HC + fbase;
        if constexpr (VPT == 4) *(float4*)op = make_float4(y[0], y[1], y[2], y[3]);
        else                    *(float2*)op = make_float2(y[0], y[1]);
    }
}

// ---------------- fused: pf = p2@pw3^T + pb3; out = [x3|pf]@fw^T + fb ----------------
// 8 waves (512 thr): wave = (row-group rw, col-half ch). Halved per-wave critical path,
// doubled TLP. LDS-staged coalesced epilogues.
__global__ void gemm_pw3cat_kernel(const u16* __restrict__ p2, const u16* __restrict__ Bpw3,
                                   const float* __restrict__ pb3, float* __restrict__ pf,
                                   const float* __restrict__ x3, const u16* __restrict__ Bfw,
                                   const float* __restrict__ fb, float* __restrict__ outp,
                                   int M) {
    using bfrag = __attribute__((ext_vector_type(8))) short;
    using ffrag = __attribute__((ext_vector_type(4))) float;
    __shared__ float pft[64][132];   // stride 132: bank offset 4/row, 16B-aligned rows
    int wave = threadIdx.x >> 6, lane = threadIdx.x & 63;
    int lm = lane & 15, kg = (lane >> 4) * 8;
    int rw = wave & 3, ch = wave >> 2;
    int rowblk = blockIdx.x * 64 + rw * 16;
    int rowbase = blockIdx.x * 64;
    int colbase = ch * 64;

    // ---- stage 1: pf quarter-tile (16 rows x 64 cols per wave, K=128) -> pft ----
    {
        const u16* Ap = p2 + (size_t)(rowblk + lm) * 128 + kg;
        const u16* Bp = Bpw3 + (size_t)(colbase + lm) * 128 + kg;
        ffrag acc[4] = {};
#pragma unroll
        for (int k0 = 0; k0 < 128; k0 += 32) {
            bfrag af = *(const bfrag*)(Ap + k0);
#pragma unroll
            for (int t = 0; t < 4; t++) {
                bfrag bf = *(const bfrag*)(Bp + (size_t)t * 16 * 128 + k0);
                acc[t] = __builtin_amdgcn_mfma_f32_16x16x32_bf16(af, bf, acc[t], 0, 0, 0);
            }
        }
        int lrow = rw * 16 + (lane >> 4) * 4;
#pragma unroll
        for (int t = 0; t < 4; t++) {
            int col = colbase + t * 16 + lm;
            float bi = pb3[col];
#pragma unroll
            for (int r = 0; r < 4; r++)
                pft[lrow + r][col] = acc[t][r] + bi;
        }
    }
    __syncthreads();

    // ---- coalesced pf write from pft (reads only; no hazard vs stage-2 pft reads) ----
    for (int i = threadIdx.x; i < 2048; i += 512) {
        int row = i >> 5, c4 = (i & 31) << 2;
        float4 v = *(const float4*)&pft[row][c4];
        *(float4*)&pf[(size_t)(rowbase + row) * 128 + c4] = v;
    }

    // ---- stage 2: out = [x3|pf]@fw^T + fb (K=256) ----
    {
        const u16* Bp = Bfw + (size_t)(colbase + lm) * 256 + kg;
        ffrag acc[4] = {};
        int row = rowblk + lm, lrow = rw * 16 + lm;
#pragma unroll
        for (int k0 = 0; k0 < 256; k0 += 32) {
            bfrag af;
            if (k0 < 128) {
                const float* ap = x3 + (size_t)row * 128 + kg + k0;
                float4 a0 = *(const float4*)ap;
                float4 a1 = *(const float4*)(ap + 4);
                af[0] = (short)f2bf(a0.x); af[1] = (short)f2bf(a0.y);
                af[2] = (short)f2bf(a0.z); af[3] = (short)f2bf(a0.w);
                af[4] = (short)f2bf(a1.x); af[5] = (short)f2bf(a1.y);
                af[6] = (short)f2bf(a1.z); af[7] = (short)f2bf(a1.w);
            } else {
                const float* ap = &pft[lrow][kg + k0 - 128];
                float4 a0 = *(const float4*)ap;
                float4 a1 = *(const float4*)(ap + 4);
                af[0] = (short)f2bf(a0.x); af[1] = (short)f2bf(a0.y);
                af[2] = (short)f2bf(a0.z); af[3] = (short)f2bf(a0.w);
                af[4] = (short)f2bf(a1.x); af[5] = (short)f2bf(a1.y);
                af[6] = (short)f2bf(a1.z); af[7] = (short)f2bf(a1.w);
            }
#pragma unroll
            for (int t = 0; t < 4; t++) {
                bfrag bf = *(const bfrag*)(Bp + (size_t)t * 16 * 256 + k0);
                acc[t] = __builtin_amdgcn_mfma_f32_16x16x32_bf16(af, bf, acc[t], 0, 0, 0);
            }
        }
        __syncthreads();   // all pft reads (stage-2 A-frags + pf copy) done before reuse
        int lrow2 = rw * 16 + (lane >> 4) * 4;
#pragma unroll
        for (int t = 0; t < 4; t++) {
            int col = colbase + t * 16 + lm;
            float bi = fb[col];
#pragma unroll
            for (int r = 0; r < 4; r++)
                pft[lrow2 + r][col] = acc[t][r] + bi;
        }
        __syncthreads();
        // ---- coalesced out write from pft ----
        for (int i = threadIdx.x; i < 2048; i += 512) {
            int rw2 = i >> 5, c4 = (i & 31) << 2;
            float4 v = *(const float4*)&pft[rw2][c4];
            *(float4*)&outp[(size_t)(rowbase + rw2) * 128 + c4] = v;
        }
    }
}

extern "C" void kernel_launch(void* const* d_in, const int* in_sizes, int n_in,
                              void* d_out, int out_size, void* d_ws, size_t ws_size,
                              hipStream_t stream) {
    const float* x    = (const float*)d_in[0];
    const int*   ei   = (const int*)d_in[1];
    const float* pos  = (const float*)d_in[2];
    const float* W1   = (const float*)d_in[3];
    const float* as1  = (const float*)d_in[4];
    const float* ad1  = (const float*)d_in[5];
    const float* bg1  = (const float*)d_in[6];
    const float* ln1g = (const float*)d_in[7];
    const float* ln1b = (const float*)d_in[8];
    const float* W2   = (const float*)d_in[9];
    const float* as2  = (const float*)d_in[10];
    const float* ad2  = (const float*)d_in[11];
    const float* bg2  = (const float*)d_in[12];
    const float* ln2g = (const float*)d_in[13];
    const float* ln2b = (const float*)d_in[14];
    const float* W3   = (const float*)d_in[15];
    const float* as3  = (const float*)d_in[16];
    const float* ad3  = (const float*)d_in[17];
    const float* bg3  = (const float*)d_in[18];
    const float* pw1  = (const float*)d_in[19];
    const float* pb1  = (const float*)d_in[20];
    const float* bn1g = (const float*)d_in[21];
    const float* bn1b = (const float*)d_in[22];
    const float* pw2  = (const float*)d_in[23];
    const float* pb2  = (const float*)d_in[24];
    const float* bn2g = (const float*)d_in[25];
    const float* bn2b = (const float*)d_in[26];
    const float* pw3  = (const float*)d_in[27];
    const float* pb3  = (const float*)d_in[28];
    const float* fw   = (const float*)d_in[29];
    const float* fb   = (const float*)d_in[30];

    const int N = NNODES;
    float* out = (float*)d_out;                    // [N,128]
    float* x3  = out + (size_t)N * 128;            // [N,128]
    float* pf  = out + (size_t)2 * N * 128;        // [N,128]

    char* ws = (char*)d_ws;
    size_t off = 0;
    auto alloc = [&](size_t bytes) -> void* {
        void* p = ws + off;
        off += (bytes + 255) / 256 * 256;
        return p;
    };
    int*   cnt    = (int*)alloc((size_t)(N + 1 + NBUCK) * 4);  // degrees + spill count + bucket cursors
    u32*   bcnt   = (u32*)(cnt + N + 1);
    u32*   seg    = (u32*)alloc((size_t)NBUCK * SEGCAP * 4);   // bucketed packed (dst<<16|src)
    u16*   srcs16 = (u16*)alloc((size_t)N * ELLW * 2);
    int2*  ovbuf  = (int2*)alloc((size_t)NETOT * 8);
    float* esb    = (float*)alloc((size_t)N * 4 * 4);
    float* edb    = (float*)alloc((size_t)N * 4 * 4);
    u16*   w1c    = (u16*)alloc(16384 * 2);
    u16*   w2c    = (u16*)alloc(32768 * 2);
    u16*   w3c    = (u16*)alloc(16384 * 2);
    u16*   pw2c   = (u16*)alloc(8192 * 2);
    u16*   pw3c   = (u16*)alloc(16384 * 2);
    u16*   fwc    = (u16*)alloc(32768 * 2);
    u16*   hbufb  = (u16*)alloc((size_t)N * 128 * 2);   // layers 2,3 h tables
    u16*   xb     = (u16*)alloc((size_t)N * 256 * 2);
    u16*   p2b    = (u16*)alloc((size_t)N * 128 * 2);
    u16*   xc     = (u16*)alloc((size_t)N * 64 * 2);    // layer-1 bf16 x table
    float* vbuf   = (float*)alloc(512 * 4);             // v_s/v_d [8][64]
    u16*   aggb   = (u16*)alloc((size_t)N * 256 * 2);   // layer-1 aggregate (bf16)

    // ---- graph build phase A + weight cast + prep_v ----
    hipMemsetAsync(cnt, 0, (size_t)(N + 1 + NBUCK) * 4, stream);
    build_a_kernel<<<ABLOCKS + CBLOCKS + 1, 1024, 0, stream>>>(
        ei, bcnt, seg, W1, as1, ad1, vbuf,
        W1, w1c, 4096, W2, w2c, 8192, W3, w3c, 4096,
        pw2, pw2c, 2048, pw3, pw3c, 4096, fw, fwc, 8192);

    // ---- mid: build_b + esed1 + pn12 (independent, one launch) ----
    mid_kernel<<<NBUCK + 2 * GBLK, 256, 0, stream>>>(
        seg, bcnt, cnt, srcs16, ovbuf,
        x, vbuf, esb, edb, xc,
        pos, pw1, pb1, bn1g, bn1b, pw2c, p2b, pb2, bn2g, bn2b);

    const int NW = N / 4;   // one-wave-per-node kernels
    const int GB = GBLK;    // 625 GEMM row-blocks

    // ---- GAT layer 1 (aggregate-then-transform) ----
    gat_agg_kernel<<<NW, 256, 0, stream>>>(xc, esb, edb, cnt, srcs16, ovbuf, aggb, N);
    w1ln_kernel<<<GB, 256, 0, stream>>>(aggb, w1c, bg1, ln1g, ln1b, xb, N);

    // ---- GAT layer 2 ----
    gemm_scores_kernel<2, 64, false><<<dim3(GB, 1), 256, 0, stream>>>(
        xb, w2c, hbufb, as2, ad2, esb, edb, N, 128, 256);
    gat_fused_kernel<2, 64, true><<<NW, 256, 0, stream>>>(
        hbufb, esb, edb, cnt, srcs16, ovbuf, bg2, ln2g, ln2b, xb, N);

    // ---- GAT layer 3 (out f32 -> x3) ----
    gemm_scores_kernel<1, 128, false><<<dim3(GB, 1), 256, 0, stream>>>(
        xb, w3c, hbufb, as3, ad3, esb, edb, N, 128, 128);
    gat_fused_kernel<1, 128, false><<<NW, 256, 0, stream>>>(
        hbufb, esb, edb, cnt, srcs16, ovbuf, bg3, nullptr, nullptr, x3, N);

    // ---- pw3 GEMM + fusion GEMM (8-wave, LDS-staged coalesced epilogues) ----
    gemm_pw3cat_kernel<<<GB, 512, 0, stream>>>(p2b, pw3c, pb3, pf, x3, fwc, fb, out, N);
}

// Round 10
// 352.180 us; speedup vs baseline: 1.0489x; 1.0056x over previous
//
#include <hip/hip_runtime.h>
#include <cstddef>

#define NNODES 40000
#define NEDGES 640000
#define NETOT  (NNODES + NEDGES)
#define ELLW   96          // fixed edge slots per node; overflow -> spill list
#define NCAST  30720       // float4 groups across the 6 weight tensors
#define NBUCK  313         // dst>>7 buckets (128 nodes each)
#define SEGCAP 8192        // pairs per bucket segment (expected ~2300, +129 sigma)
#define ABLOCKS 84         // ceil(NETOT / 8192) edge-bucketing blocks
#define CBLOCKS 30         // NCAST / 1024 weight-cast blocks
#define GBLK   625         // NNODES / 64 row-blocks

typedef unsigned short u16;
typedef unsigned int   u32;
using v2f = __attribute__((ext_vector_type(2))) float;

// ---------------- helpers ----------------
__device__ inline float wave_sum(float v) {
#pragma unroll
    for (int o = 32; o > 0; o >>= 1) v += __shfl_xor(v, o);
    return v;
}
__device__ inline u16 f2bf(float f) {   // round-to-nearest-even f32 -> bf16
    u32 u = __float_as_uint(f);
    return (u16)((u + 0x7fffu + ((u >> 16) & 1u)) >> 16);
}

// ---------------- build phase A: bucket edges by dst range + weight cast + prep_v ----
__global__ void build_a_kernel(const int* __restrict__ ei, u32* __restrict__ bcnt,
                               u32* __restrict__ seg,
                               const float* __restrict__ W1, const float* __restrict__ as1,
                               const float* __restrict__ ad1, float* __restrict__ vbuf,
                               const float* s0, u16* d0, int n0, const float* s1, u16* d1, int n1,
                               const float* s2, u16* d2, int n2, const float* s3, u16* d3, int n3,
                               const float* s4, u16* d4, int n4, const float* s5, u16* d5, int n5) {
    int tid = threadIdx.x;
    int blk = blockIdx.x;
    if (blk >= ABLOCKS) {
        if (blk < ABLOCKS + CBLOCKS) {            // ---- weight cast ----
            int i = (blk - ABLOCKS) * 1024 + tid;
            const float* s; u16* d;
            if      (i < n0) { s = s0; d = d0; }
            else if ((i -= n0) < n1) { s = s1; d = d1; }
            else if ((i -= n1) < n2) { s = s2; d = d2; }
            else if ((i -= n2) < n3) { s = s3; d = d3; }
            else if ((i -= n3) < n4) { s = s4; d = d4; }
            else if ((i -= n4) < n5) { s = s5; d = d5; }
            else return;
            float4 v = ((const float4*)s)[i];
            ushort4 o; o.x = f2bf(v.x); o.y = f2bf(v.y); o.z = f2bf(v.z); o.w = f2bf(v.w);
            ((ushort4*)d)[i] = o;
        } else if (tid < 256) {                   // ---- prep_v: v_s[h]=W_h^T a_s[h], v_d ----
            int h = tid >> 6, k = tid & 63;
            float ss = 0.f, dd = 0.f;
            for (int c = 0; c < 64; c++) {
                float w = W1[(h * 64 + c) * 64 + k];
                ss += as1[h * 64 + c] * w;
                dd += ad1[h * 64 + c] * w;
            }
            vbuf[tid] = ss;
            vbuf[256 + tid] = dd;
        }
        return;
    }
    __shared__ u32 hist[NBUCK], hbase[NBUCK];
    for (int i = tid; i < NBUCK; i += 1024) hist[i] = 0;
    __syncthreads();
    u32 pk[8], loc[8]; int bj[8];
    int g0 = blk * 8192;
#pragma unroll
    for (int j = 0; j < 8; j++) {
        int g = g0 + j * 1024 + tid;
        bj[j] = -1;
        if (g < NETOT) {
            int src, dst;
            if (g < NEDGES) { src = ei[g]; dst = ei[NEDGES + g]; }
            else            { src = g - NEDGES; dst = src; }
            int b = dst >> 7;
            pk[j] = ((u32)dst << 16) | (u32)src;
            bj[j] = b;
            loc[j] = atomicAdd(&hist[b], 1u);
        }
    }
    __syncthreads();
    for (int i = tid; i < NBUCK; i += 1024) {
        u32 c = hist[i];
        hbase[i] = c ? atomicAdd(&bcnt[i], c) : 0u;
    }
    __syncthreads();
#pragma unroll
    for (int j = 0; j < 8; j++) {
        if (bj[j] >= 0) {
            u32 pos = hbase[bj[j]] + loc[j];
            if (pos < SEGCAP) seg[(size_t)bj[j] * SEGCAP + pos] = pk[j];
        }
    }
}

// ---------------- mid kernel: build_b (ELL fill) + esed1 (layer-1 scores/cast) + pn12 ----------------
__global__ void mid_kernel(const u32* __restrict__ seg, const u32* __restrict__ bcnt,
                           int* __restrict__ cnt, u16* __restrict__ srcs16,
                           int2* __restrict__ ovbuf,
                           const float* __restrict__ x, const float* __restrict__ vbuf,
                           float* __restrict__ es, float* __restrict__ ed, u16* __restrict__ xc,
                           const float* __restrict__ pos,
                           const float* __restrict__ pw1, const float* __restrict__ pb1,
                           const float* __restrict__ bn1g, const float* __restrict__ bn1b,
                           const u16* __restrict__ Bpn, u16* __restrict__ p2out,
                           const float* __restrict__ pb2,
                           const float* __restrict__ bn2g, const float* __restrict__ bn2b) {
    __shared__ u32 lcnt[128];
    __shared__ float vl[512];
    int tid = threadIdx.x;
    int blk = blockIdx.x;

    if (blk < NBUCK) {                            // ---- build_b: per-bucket ELL fill ----
        int base = blk << 7;
        if (tid < 128) lcnt[tid] = 0;
        __syncthreads();
        u32 m = bcnt[blk]; if (m > SEGCAP) m = SEGCAP;
        const u32* sp = seg + (size_t)blk * SEGCAP;
        for (u32 e = tid; e < m; e += 256) {
            u32 pkv = sp[e];
            u32 dst = pkv >> 16, src = pkv & 0xffffu;
            u32 p = atomicAdd(&lcnt[dst - (u32)base], 1u);
            if (p < ELLW) srcs16[dst * ELLW + p] = (u16)src;
            else {
                int q = atomicAdd(&cnt[NNODES], 1);   // rare spill
                ovbuf[q] = make_int2((int)dst, (int)src);
            }
        }
        __syncthreads();
        if (tid < 128 && base + tid < NNODES) cnt[base + tid] = (int)lcnt[tid];
        return;
    }
    blk -= NBUCK;
    if (blk < GBLK) {                             // ---- esed1: es/ed = x.v + cast x->bf16 ----
        vl[tid] = vbuf[tid];
        vl[tid + 256] = vbuf[tid + 256];
        __syncthreads();
        int lane = tid & 63, wave = tid >> 6;
        int i = lane >> 2, q = lane & 3;
        int node = blk * 64 + wave * 16 + i;
        const float* xp = x + (size_t)node * 64 + q * 16;
        float xr[16];
        *(float4*)&xr[0]  = ((const float4*)xp)[0];
        *(float4*)&xr[4]  = ((const float4*)xp)[1];
        *(float4*)&xr[8]  = ((const float4*)xp)[2];
        *(float4*)&xr[12] = ((const float4*)xp)[3];
        float p[8];
#pragma unroll
        for (int h = 0; h < 8; h++) {
            float s = 0.f;
#pragma unroll
            for (int j = 0; j < 16; j++) s += xr[j] * vl[h * 64 + q * 16 + j];
            p[h] = s;
        }
#pragma unroll
        for (int h = 0; h < 8; h++) {
            p[h] += __shfl_xor(p[h], 1);
            p[h] += __shfl_xor(p[h], 2);
        }
        es[node * 4 + q] = p[q];
        ed[node * 4 + q] = p[4 + q];
        u16* cp = xc + (size_t)node * 64 + q * 16;
#pragma unroll
        for (int j = 0; j < 16; j += 4) {
            ushort4 o; o.x = f2bf(xr[j]); o.y = f2bf(xr[j + 1]);
            o.z = f2bf(xr[j + 2]); o.w = f2bf(xr[j + 3]);
            *(ushort4*)(cp + j) = o;
        }
        return;
    }
    blk -= GBLK;                                  // ---- pn12 ----
    {
        const int Nn = 128, K = 64;
        using bfrag = __attribute__((ext_vector_type(8))) short;
        using ffrag = __attribute__((ext_vector_type(4))) float;
        int wave = tid >> 6, lane = tid & 63;
        int lm = lane & 15, kg = (lane >> 4) * 8;
        int rowblk = blk * 64 + wave * 16;
        int row = rowblk + lm;
        float p0 = pos[row * 3 + 0], p1 = pos[row * 3 + 1], p2 = pos[row * 3 + 2];
        const u16* Bp = Bpn + (size_t)lm * K + kg;
        const float bnscale = rsqrtf(1.0f + 1e-5f);
        ffrag acc[8] = {};
#pragma unroll
        for (int k0 = 0; k0 < K; k0 += 32) {
            bfrag af;
#pragma unroll
            for (int j = 0; j < 8; j++) {
                int k = kg + k0 + j;
                float v = p0 * pw1[k * 3 + 0] + p1 * pw1[k * 3 + 1] + p2 * pw1[k * 3 + 2] + pb1[k];
                v = v * (bn1g[k] * bnscale) + bn1b[k];
                v = v > 0.f ? v : 0.f;
                af[j] = (short)f2bf(v);
            }
#pragma unroll
            for (int t = 0; t < 8; t++) {
                bfrag bf = *(const bfrag*)(Bp + (size_t)t * 16 * K + k0);
                acc[t] = __builtin_amdgcn_mfma_f32_16x16x32_bf16(af, bf, acc[t], 0, 0, 0);
            }
        }
        int orow = rowblk + (lane >> 4) * 4;
#pragma unroll
        for (int t = 0; t < 8; t++) {
            int col = t * 16 + lm;
            float bi = pb2[col], g = bn2g[col] * bnscale, bb = bn2b[col];
#pragma unroll
            for (int r = 0; r < 4; r++) {
                float v = (acc[t][r] + bi) * g + bb;
                v = v > 0.f ? v : 0.f;
                p2out[(size_t)(orow + r) * Nn + col] = f2bf(v);
            }
        }
    }
}

// ---------------- layer-1 aggregation over x (64-dim rows, 128B) ----------------
__global__ void gat_agg_kernel(const u16* __restrict__ xc,
                               const float* __restrict__ es, const float* __restrict__ ed,
                               const int* __restrict__ cnt, const u16* __restrict__ srcs16,
                               const int2* __restrict__ ovbuf,
                               u16* __restrict__ agg, int n) {
    __shared__ float wbuf[4][4][100];
    __shared__ u32   sbuf[4][ELLW];
    int wave = threadIdx.x >> 6;
    int wid = (blockIdx.x * blockDim.x + threadIdx.x) >> 6;
    int lane = threadIdx.x & 63;
    if (wid >= n) return;

    int degt = cnt[wid];
    int mainc = degt < ELLW ? degt : ELLW;
    int padt = (mainc + 7) & ~7;
    const u16* sp = srcs16 + (size_t)wid * ELLW;

    const int h = lane & 3;
    const int esub = lane >> 2;
    float edh = ed[(size_t)wid * 4 + h];

    // ---- phase 1 ----
    float den = 0.f;
    for (int i0 = 0; i0 < padt; i0 += 16) {
        int e = i0 + esub;
        if (e < padt) {
            float w = 0.f; u32 off = 0;
            if (e < mainc) {
                int s = sp[e];
                off = (u32)s << 7;
                float v = es[(size_t)s * 4 + h] + edh;
                v = v > 0.f ? v : 0.2f * v;
                w = __expf(v);
            }
            wbuf[wave][h][e] = w;
            if (h == 0) sbuf[wave][e] = off;
            den += w;
        }
    }
    int ovn = 0;
    if (degt > ELLW) {
        ovn = cnt[n];
        for (int j = esub; j < ovn; j += 16) {
            int2 t = ovbuf[j];
            if (t.x == wid) {
                float v = es[(size_t)t.y * 4 + h] + edh;
                v = v > 0.f ? v : 0.2f * v;
                den += __expf(v);
            }
        }
    }
#pragma unroll
    for (int o = 4; o < 64; o <<= 1) den += __shfl_xor(den, o);
    float inv = 1.f / (den + 1e-16f);

    // ---- phase 2: gather 128B rows, accumulate all 4 heads ----
    const int e2 = lane >> 5, f16 = lane & 31;
    const char* hp = (const char*)xc + f16 * 4;
    v2f a0 = {0.f, 0.f}, a1 = {0.f, 0.f}, a2 = {0.f, 0.f}, a3 = {0.f, 0.f};
    for (int eb = 0; eb < padt; eb += 8) {
        u32 of[4]; u32 g[4];
        float w0[4], w1[4], w2[4], w3[4];
#pragma unroll
        for (int k = 0; k < 4; k++) of[k] = sbuf[wave][eb + 2 * k + e2];
#pragma unroll
        for (int k = 0; k < 4; k++) g[k] = *(const u32*)(hp + of[k]);
#pragma unroll
        for (int k = 0; k < 4; k++) {
            int e = eb + 2 * k + e2;
            w0[k] = wbuf[wave][0][e]; w1[k] = wbuf[wave][1][e];
            w2[k] = wbuf[wave][2][e]; w3[k] = wbuf[wave][3][e];
        }
#pragma unroll
        for (int k = 0; k < 4; k++) {
            v2f hx;
            hx.x = __uint_as_float(g[k] << 16);
            hx.y = __uint_as_float(g[k] & 0xffff0000u);
            a0 += v2f{w0[k], w0[k]} * hx;
            a1 += v2f{w1[k], w1[k]} * hx;
            a2 += v2f{w2[k], w2[k]} * hx;
            a3 += v2f{w3[k], w3[k]} * hx;
        }
    }
    if (degt > ELLW) {
        for (int j = 0; j < ovn; j++) {
            int2 t = ovbuf[j];
            if (t.x != wid) continue;
            float wh[4];
#pragma unroll
            for (int hh = 0; hh < 4; hh++) {
                float v = es[(size_t)t.y * 4 + hh] + __shfl(edh, hh);
                v = v > 0.f ? v : 0.2f * v;
                wh[hh] = __expf(v);
            }
            if (lane < 32) {
                u32 g = *(const u32*)(hp + ((u32)t.y << 7));
                v2f hx;
                hx.x = __uint_as_float(g << 16);
                hx.y = __uint_as_float(g & 0xffff0000u);
                a0 += v2f{wh[0], wh[0]} * hx;
                a1 += v2f{wh[1], wh[1]} * hx;
                a2 += v2f{wh[2], wh[2]} * hx;
                a3 += v2f{wh[3], wh[3]} * hx;
            }
        }
    }
    a0.x += __shfl_xor(a0.x, 32); a0.y += __shfl_xor(a0.y, 32);
    a1.x += __shfl_xor(a1.x, 32); a1.y += __shfl_xor(a1.y, 32);
    a2.x += __shfl_xor(a2.x, 32); a2.y += __shfl_xor(a2.y, 32);
    a3.x += __shfl_xor(a3.x, 32); a3.y += __shfl_xor(a3.y, 32);
    float iv[4];
#pragma unroll
    for (int hh = 0; hh < 4; hh++) iv[hh] = __shfl(inv, hh);
    if (lane < 32) {
        u32* op = (u32*)agg + (size_t)wid * 128 + f16;
        op[0]  = ((u32)f2bf(a0.y * iv[0]) << 16) | f2bf(a0.x * iv[0]);
        op[32] = ((u32)f2bf(a1.y * iv[1]) << 16) | f2bf(a1.x * iv[1]);
        op[64] = ((u32)f2bf(a2.y * iv[2]) << 16) | f2bf(a2.x * iv[2]);
        op[96] = ((u32)f2bf(a3.y * iv[3]) << 16) | f2bf(a3.x * iv[3]);
    }
}

// ---------------- layer-1 post-GEMM (block-diagonal per head) + bias + LN + ReLU -> xb bf16 ----------------
__global__ void w1ln_kernel(const u16* __restrict__ agg, const u16* __restrict__ B,
                            const float* __restrict__ bias,
                            const float* __restrict__ lng, const float* __restrict__ lnb,
                            u16* __restrict__ xb, int M) {
    using bfrag = __attribute__((ext_vector_type(8))) short;
    using ffrag = __attribute__((ext_vector_type(4))) float;
    int wave = threadIdx.x >> 6, lane = threadIdx.x & 63;
    int lm = lane & 15, kg = (lane >> 4) * 8;
    int rowblk = blockIdx.x * 64 + wave * 16;
    ffrag acc[16] = {};
#pragma unroll
    for (int hh = 0; hh < 4; hh++) {
#pragma unroll
        for (int k0 = 0; k0 < 64; k0 += 32) {
            bfrag af = *(const bfrag*)(agg + (size_t)(rowblk + lm) * 256 + hh * 64 + kg + k0);
#pragma unroll
            for (int tt = 0; tt < 4; tt++) {
                int t = hh * 4 + tt;
                bfrag bf = *(const bfrag*)(B + (size_t)(hh * 64 + tt * 16 + lm) * 64 + kg + k0);
                acc[t] = __builtin_amdgcn_mfma_f32_16x16x32_bf16(af, bf, acc[t], 0, 0, 0);
            }
        }
    }
    int orow = rowblk + (lane >> 4) * 4;
    float bi[16], gg[16], bb[16];
#pragma unroll
    for (int t = 0; t < 16; t++) {
        int col = t * 16 + lm;
        bi[t] = bias[col]; gg[t] = lng[col]; bb[t] = lnb[col];
    }
#pragma unroll
    for (int r = 0; r < 4; r++) {
        float pv[16];
        float s1 = 0.f, s2 = 0.f;
#pragma unroll
        for (int t = 0; t < 16; t++) {
            float v = acc[t][r] + bi[t];
            pv[t] = v; s1 += v; s2 += v * v;
        }
#pragma unroll
        for (int o = 1; o < 16; o <<= 1) { s1 += __shfl_xor(s1, o); s2 += __shfl_xor(s2, o); }
        float mu = s1 / 256.f;
        float var = s2 / 256.f - mu * mu;
        float rstd = rsqrtf(var + 1e-5f);
#pragma unroll
        for (int t = 0; t < 16; t++) {
            float v = (pv[t] - mu) * rstd * gg[t] + bb[t];
            v = v > 0.f ? v : 0.f;
            xb[(size_t)(orow + r) * 256 + t * 16 + lm] = f2bf(v);
        }
    }
}

// ---------------- GEMM (128-wide N tile) + fused attention scores (layers 2,3) ----------------
template <int H, int C, bool AF32>
__global__ void gemm_scores_kernel(const void* __restrict__ Aptr, const u16* __restrict__ B,
                                   u16* __restrict__ Cout,
                                   const float* __restrict__ as, const float* __restrict__ ad,
                                   float* __restrict__ es, float* __restrict__ ed,
                                   int M, int Nn, int K) {
    constexpr int HT = 128 / C;
    using bfrag = __attribute__((ext_vector_type(8))) short;
    using ffrag = __attribute__((ext_vector_type(4))) float;
    int wave = threadIdx.x >> 6, lane = threadIdx.x & 63;
    int lm = lane & 15, kg = (lane >> 4) * 8;
    int rowblk = blockIdx.x * 64 + wave * 16;
    int n0 = blockIdx.y * 128;
    const u16* Bp = B + (size_t)(n0 + lm) * K + kg;
    ffrag acc[8] = {};
    for (int k0 = 0; k0 < K; k0 += 32) {
        bfrag af;
        if constexpr (AF32) {
            const float* ap = (const float*)Aptr + (size_t)(rowblk + lm) * K + kg + k0;
            float4 a0 = *(const float4*)ap;
            float4 a1 = *(const float4*)(ap + 4);
            af[0] = (short)f2bf(a0.x); af[1] = (short)f2bf(a0.y);
            af[2] = (short)f2bf(a0.z); af[3] = (short)f2bf(a0.w);
            af[4] = (short)f2bf(a1.x); af[5] = (short)f2bf(a1.y);
            af[6] = (short)f2bf(a1.z); af[7] = (short)f2bf(a1.w);
        } else {
            af = *(const bfrag*)((const u16*)Aptr + (size_t)(rowblk + lm) * K + kg + k0);
        }
#pragma unroll
        for (int t = 0; t < 8; t++) {
            bfrag bf = *(const bfrag*)(Bp + (size_t)t * 16 * K + k0);
            acc[t] = __builtin_amdgcn_mfma_f32_16x16x32_bf16(af, bf, acc[t], 0, 0, 0);
        }
    }
    int orow = rowblk + (lane >> 4) * 4;   // C/D: col = lane&15, row = (lane>>4)*4 + reg
    float asv[8], adv[8];
#pragma unroll
    for (int t = 0; t < 8; t++) {
        int fcol = n0 + t * 16 + lm;
        asv[t] = as[fcol]; adv[t] = ad[fcol];
    }
    float ps[4][HT] = {}, pd[4][HT] = {};
#pragma unroll
    for (int t = 0; t < 8; t++) {
        const int hh = t / (C / 16);
#pragma unroll
        for (int r = 0; r < 4; r++) {
            float v = acc[t][r];
            ps[r][hh] += v * asv[t];
            pd[r][hh] += v * adv[t];
            Cout[(size_t)(orow + r) * Nn + n0 + t * 16 + lm] = f2bf(v);
        }
    }
    int hb = blockIdx.y * HT;
#pragma unroll
    for (int r = 0; r < 4; r++)
#pragma unroll
        for (int hh = 0; hh < HT; hh++) {
            float s = ps[r][hh], d = pd[r][hh];
#pragma unroll
            for (int o = 1; o < 16; o <<= 1) { s += __shfl_xor(s, o); d += __shfl_xor(d, o); }
            if (lm == 0) {
                es[(size_t)(orow + r) * H + hb + hh] = s;
                ed[(size_t)(orow + r) * H + hb + hh] = d;
            }
        }
}

// ---------------- fused GAT softmax + aggregation (R1 chassis), layers 2,3 ----------------
// x16out (nullable): bf16 copy of the f32 output (used by layer 3 to feed pw3cat).
template <int H, int C, bool LNRELU>
__global__ void gat_fused_kernel(const u16* __restrict__ hmat,
                                 const float* __restrict__ es, const float* __restrict__ ed,
                                 const int* __restrict__ cnt, const u16* __restrict__ srcs16,
                                 const int2* __restrict__ ovbuf,
                                 const float* __restrict__ bias,
                                 const float* __restrict__ lng, const float* __restrict__ lnb,
                                 void* __restrict__ out, u16* __restrict__ x16out, int n) {
    constexpr int HC = H * C;
    constexpr int VPT = HC / 64;
    constexpr int SH = (HC == 256) ? 9 : 8;      // byte-offset shift for h rows
    constexpr int EPW = 64 / H;                  // edges per phase-1 pass
    constexpr int HSH = (H == 4) ? 2 : ((H == 2) ? 1 : 0);
    __shared__ float wbuf[4][H][100];
    __shared__ int   sbuf[4][ELLW];
    int wave = threadIdx.x >> 6;
    int wid = (blockIdx.x * blockDim.x + threadIdx.x) >> 6;
    int lane = threadIdx.x & 63;
    if (wid >= n) return;

    int degt = cnt[wid];
    int mainc = degt < ELLW ? degt : ELLW;
    int pad = (mainc + 7) & ~7;
    const u16* sp = srcs16 + (size_t)wid * ELLW;

    const int h = lane & (H - 1);
    const int esub = lane >> HSH;
    float edh = ed[(size_t)wid * H + h];

    // ---- phase 1 ----
    float den = 0.f;
    for (int i0 = 0; i0 < pad; i0 += EPW) {
        int e = i0 + esub;
        if (e < pad) {
            float w = 0.f;
            int soff = 0;
            if (e < mainc) {
                int s = sp[e];
                soff = s << SH;
                float v = es[(size_t)s * H + h] + edh;
                v = v > 0.f ? v : 0.2f * v;
                w = __expf(v);
            }
            wbuf[wave][h][e] = w;
            if (h == 0) sbuf[wave][e] = soff;
            den += w;
        }
    }
    int ovn = 0;
    if (degt > ELLW) {
        ovn = cnt[n];
        for (int j = esub; j < ovn; j += EPW) {
            int2 t = ovbuf[j];
            if (t.x == wid) {
                float v = es[(size_t)t.y * H + h] + edh;
                v = v > 0.f ? v : 0.2f * v;
                den += __expf(v);
            }
        }
    }
#pragma unroll
    for (int o = H; o < 64; o <<= 1) den += __shfl_xor(den, o);
    float inv = 1.f / (den + 1e-16f);

    // ---- phase 2: 8-deep batches ----
    const int myhead = (lane * VPT) / C;
    const float invh = __shfl(inv, myhead);
    const int loff = lane * (VPT * 2);
    v2f a01 = {0.f, 0.f}, a23 = {0.f, 0.f};

    for (int e = 0; e < pad; e += 8) {
        int4   o0 = *(const int4*)&sbuf[wave][e];
        int4   o1 = *(const int4*)&sbuf[wave][e + 4];
        float4 w0 = *(const float4*)&wbuf[wave][myhead][e];
        float4 w1 = *(const float4*)&wbuf[wave][myhead][e + 4];
        int   oo[8] = {o0.x, o0.y, o0.z, o0.w, o1.x, o1.y, o1.z, o1.w};
        float ww[8] = {w0.x, w0.y, w0.z, w0.w, w1.x, w1.y, w1.z, w1.w};
        if constexpr (VPT == 4) {
            uint2 gg[8];
#pragma unroll
            for (int u = 0; u < 8; u++)
                gg[u] = *(const uint2*)((const char*)hmat + (size_t)(u32)oo[u] + loff);
#pragma unroll
            for (int u = 0; u < 8; u++) {
                v2f wv = {ww[u], ww[u]};
                v2f h01, h23;
                h01.x = __uint_as_float(gg[u].x << 16);
                h01.y = __uint_as_float(gg[u].x & 0xffff0000u);
                h23.x = __uint_as_float(gg[u].y << 16);
                h23.y = __uint_as_float(gg[u].y & 0xffff0000u);
                a01 += wv * h01;
                a23 += wv * h23;
            }
        } else {
            u32 gg[8];
#pragma unroll
            for (int u = 0; u < 8; u++)
                gg[u] = *(const u32*)((const char*)hmat + (size_t)(u32)oo[u] + loff);
#pragma unroll
            for (int u = 0; u < 8; u++) {
                v2f wv = {ww[u], ww[u]};
                v2f h01;
                h01.x = __uint_as_float(gg[u] << 16);
                h01.y = __uint_as_float(gg[u] & 0xffff0000u);
                a01 += wv * h01;
            }
        }
    }
    if (degt > ELLW) {
        const float edm = __shfl(edh, myhead);
        for (int j = 0; j < ovn; j++) {
            int2 t = ovbuf[j];
            if (t.x != wid) continue;
            float v = es[(size_t)t.y * H + myhead] + edm;
            v = v > 0.f ? v : 0.2f * v;
            float w = __expf(v);
            v2f wv = {w, w};
            if constexpr (VPT == 4) {
                uint2 g = *(const uint2*)((const char*)hmat + ((size_t)t.y << SH) + loff);
                v2f h01, h23;
                h01.x = __uint_as_float(g.x << 16);
                h01.y = __uint_as_float(g.x & 0xffff0000u);
                h23.x = __uint_as_float(g.y << 16);
                h23.y = __uint_as_float(g.y & 0xffff0000u);
                a01 += wv * h01;
                a23 += wv * h23;
            } else {
                u32 g = *(const u32*)((const char*)hmat + ((size_t)t.y << SH) + loff);
                v2f h01;
                h01.x = __uint_as_float(g << 16);
                h01.y = __uint_as_float(g & 0xffff0000u);
                a01 += wv * h01;
            }
        }
    }
    {
        v2f iv = {invh, invh};
        a01 *= iv;
        a23 *= iv;
    }

    int fbase = lane * VPT;
    float y[VPT];
    y[0] = a01.x + bias[fbase + 0];
    y[1] = a01.y + bias[fbase + 1];
    if constexpr (VPT == 4) {
        y[2] = a23.x + bias[fbase + 2];
        y[3] = a23.y + bias[fbase + 3];
    }

    if constexpr (LNRELU) {
        float s1 = 0.f, s2 = 0.f;
#pragma unroll
        for (int j = 0; j < VPT; j++) { s1 += y[j]; s2 += y[j] * y[j]; }
        s1 = wave_sum(s1);
        s2 = wave_sum(s2);
        float mu = s1 / (float)HC;
        float var = s2 / (float)HC - mu * mu;
        float rstd = rsqrtf(var + 1e-5f);
#pragma unroll
        for (int j = 0; j < VPT; j++) {
            float v = (y[j] - mu) * rstd * lng[fbase + j] + lnb[fbase + j];
            y[j] = v > 0.f ? v : 0.f;
        }
        u16* op = (u16*)out + (size_t)wid * HC + fbase;
        if constexpr (VPT == 4) {
            ushort4 o; o.x = f2bf(y[0]); o.y = f2bf(y[1]); o.z = f2bf(y[2]); o.w = f2bf(y[3]);
            *(ushort4*)op = o;
        } else {
            ushort2 o; o.x = f2bf(y[0]); o.y = f2bf(y[1]);
            *(ushort2*)op = o;
        }
    } else {
        float* op = (float*)out + (size_t)wid * HC + fbase;
        if constexpr (VPT == 4) *(float4*)op = make_float4(y[0], y[1], y[2], y[3]);
        else                    *(float2*)op = make_float2(y[0], y[1]);
        if (x16out) {                             // bf16 shadow copy for the final GEMM
            if constexpr (VPT == 4) {
                ushort4 o; o.x = f2bf(y[0]); o.y = f2bf(y[1]); o.z = f2bf(y[2]); o.w = f2bf(y[3]);
                *(ushort4*)&x16out[(size_t)wid * HC + fbase] = o;
            } else {
                ushort2 o; o.x = f2bf(y[0]); o.y = f2bf(y[1]);
                *(ushort2*)&x16out[(size_t)wid * HC + fbase] = o;
            }
        }
    }
}

// ---------------- fused: pf = p2@pw3^T + pb3; out = [x3b|pf]@fw^T + fb ----------------
// 256 thr (R8 chassis). A-fragment loads HOISTED: stage-2 global x3b loads issued at kernel
// top (latency hides under stage-1 MFMAs); stage-1 p2 loads batched. bf16 x3b input halves
// stage-2 A bytes and kills the 8-deep f2bf chain. LDS-staged coalesced epilogues.
__global__ void gemm_pw3cat_kernel(const u16* __restrict__ p2, const u16* __restrict__ Bpw3,
                                   const float* __restrict__ pb3, float* __restrict__ pf,
                                   const u16* __restrict__ x3b, const u16* __restrict__ Bfw,
                                   const float* __restrict__ fb, float* __restrict__ outp,
                                   int M) {
    using bfrag = __attribute__((ext_vector_type(8))) short;
    using ffrag = __attribute__((ext_vector_type(4))) float;
    __shared__ float pft[64][132];   // stride 132: bank offset 4/row, 16B-aligned rows
    int wave = threadIdx.x >> 6, lane = threadIdx.x & 63;
    int lm = lane & 15, kg = (lane >> 4) * 8;
    int rowblk = blockIdx.x * 64 + wave * 16;
    int rowbase = blockIdx.x * 64;
    int row = rowblk + lm;

    // ---- issue stage-2 global A-loads early (independent of stage 1) ----
    bfrag afg[4];
#pragma unroll
    for (int i = 0; i < 4; i++)
        afg[i] = *(const bfrag*)(x3b + (size_t)row * 128 + kg + i * 32);

    // ---- stage 1: pf = p2@pw3^T + pb3 (K=128), A-loads batched ----
    {
        bfrag afs[4];
#pragma unroll
        for (int i = 0; i < 4; i++)
            afs[i] = *(const bfrag*)(p2 + (size_t)row * 128 + kg + i * 32);
        const u16* Bp = Bpw3 + (size_t)lm * 128 + kg;
        ffrag acc[8] = {};
#pragma unroll
        for (int k = 0; k < 4; k++)
#pragma unroll
            for (int t = 0; t < 8; t++) {
                bfrag bf = *(const bfrag*)(Bp + (size_t)t * 16 * 128 + k * 32);
                acc[t] = __builtin_amdgcn_mfma_f32_16x16x32_bf16(afs[k], bf, acc[t], 0, 0, 0);
            }
        int lrow = wave * 16 + (lane >> 4) * 4;
#pragma unroll
        for (int t = 0; t < 8; t++) {
            int col = t * 16 + lm;
            float bi = pb3[col];
#pragma unroll
            for (int r = 0; r < 4; r++)
                pft[lrow + r][col] = acc[t][r] + bi;
        }
    }
    __syncthreads();

    // ---- coalesced pf write from pft (reads only; no hazard vs stage-2 pft reads) ----
    for (int i = threadIdx.x; i < 2048; i += 256) {
        int rw = i >> 5, c4 = (i & 31) << 2;
        float4 v = *(const float4*)&pft[rw][c4];
        *(float4*)&pf[(size_t)(rowbase + rw) * 128 + c4] = v;
    }

    // ---- stage 2: out = [x3b|pf]@fw^T + fb (K=256), A-frags all in registers ----
    {
        int lrow = wave * 16 + lm;
        bfrag afl[4];
#pragma unroll
        for (int i = 0; i < 4; i++) {
            const float* ap = &pft[lrow][kg + i * 32];
            float4 a0 = *(const float4*)ap;
            float4 a1 = *(const float4*)(ap + 4);
            bfrag af;
            af[0] = (short)f2bf(a0.x); af[1] = (short)f2bf(a0.y);
            af[2] = (short)f2bf(a0.z); af[3] = (short)f2bf(a0.w);
            af[4] = (short)f2bf(a1.x); af[5] = (short)f2bf(a1.y);
            af[6] = (short)f2bf(a1.z); af[7] = (short)f2bf(a1.w);
            afl[i] = af;
        }
        const u16* Bp = Bfw + (size_t)lm * 256 + kg;
        ffrag acc[8] = {};
#pragma unroll
        for (int k = 0; k < 8; k++) {
            bfrag af = (k < 4) ? afg[k] : afl[k - 4];
#pragma unroll
            for (int t = 0; t < 8; t++) {
                bfrag bf = *(const bfrag*)(Bp + (size_t)t * 16 * 256 + k * 32);
                acc[t] = __builtin_amdgcn_mfma_f32_16x16x32_bf16(af, bf, acc[t], 0, 0, 0);
            }
        }
        __syncthreads();   // all pft reads (afl + pf copy) done before reuse
        int lrow2 = wave * 16 + (lane >> 4) * 4;
#pragma unroll
        for (int t = 0; t < 8; t++) {
            int col = t * 16 + lm;
            float bi = fb[col];
#pragma unroll
            for (int r = 0; r < 4; r++)
                pft[lrow2 + r][col] = acc[t][r] + bi;
        }
        __syncthreads();
        // ---- coalesced out write from pft ----
        for (int i = threadIdx.x; i < 2048; i += 256) {
            int rw2 = i >> 5, c4 = (i & 31) << 2;
            float4 v = *(const float4*)&pft[rw2][c4];
            *(float4*)&outp[(size_t)(rowbase + rw2) * 128 + c4] = v;
        }
    }
}

extern "C" void kernel_launch(void* const* d_in, const int* in_sizes, int n_in,
                              void* d_out, int out_size, void* d_ws, size_t ws_size,
                              hipStream_t stream) {
    const float* x    = (const float*)d_in[0];
    const int*   ei   = (const int*)d_in[1];
    const float* pos  = (const float*)d_in[2];
    const float* W1   = (const float*)d_in[3];
    const float* as1  = (const float*)d_in[4];
    const float* ad1  = (const float*)d_in[5];
    const float* bg1  = (const float*)d_in[6];
    const float* ln1g = (const float*)d_in[7];
    const float* ln1b = (const float*)d_in[8];
    const float* W2   = (const float*)d_in[9];
    const float* as2  = (const float*)d_in[10];
    const float* ad2  = (const float*)d_in[11];
    const float* bg2  = (const float*)d_in[12];
    const float* ln2g = (const float*)d_in[13];
    const float* ln2b = (const float*)d_in[14];
    const float* W3   = (const float*)d_in[15];
    const float* as3  = (const float*)d_in[16];
    const float* ad3  = (const float*)d_in[17];
    const float* bg3  = (const float*)d_in[18];
    const float* pw1  = (const float*)d_in[19];
    const float* pb1  = (const float*)d_in[20];
    const float* bn1g = (const float*)d_in[21];
    const float* bn1b = (const float*)d_in[22];
    const float* pw2  = (const float*)d_in[23];
    const float* pb2  = (const float*)d_in[24];
    const float* bn2g = (const float*)d_in[25];
    const float* bn2b = (const float*)d_in[26];
    const float* pw3  = (const float*)d_in[27];
    const float* pb3  = (const float*)d_in[28];
    const float* fw   = (const float*)d_in[29];
    const float* fb   = (const float*)d_in[30];

    const int N = NNODES;
    float* out = (float*)d_out;                    // [N,128]
    float* x3  = out + (size_t)N * 128;            // [N,128]
    float* pf  = out + (size_t)2 * N * 128;        // [N,128]

    char* ws = (char*)d_ws;
    size_t off = 0;
    auto alloc = [&](size_t bytes) -> void* {
        void* p = ws + off;
        off += (bytes + 255) / 256 * 256;
        return p;
    };
    int*   cnt    = (int*)alloc((size_t)(N + 1 + NBUCK) * 4);  // degrees + spill count + bucket cursors
    u32*   bcnt   = (u32*)(cnt + N + 1);
    u32*   seg    = (u32*)alloc((size_t)NBUCK * SEGCAP * 4);   // bucketed packed (dst<<16|src)
    u16*   srcs16 = (u16*)alloc((size_t)N * ELLW * 2);
    int2*  ovbuf  = (int2*)alloc((size_t)NETOT * 8);
    float* esb    = (float*)alloc((size_t)N * 4 * 4);
    float* edb    = (float*)alloc((size_t)N * 4 * 4);
    u16*   w1c    = (u16*)alloc(16384 * 2);
    u16*   w2c    = (u16*)alloc(32768 * 2);
    u16*   w3c    = (u16*)alloc(16384 * 2);
    u16*   pw2c   = (u16*)alloc(8192 * 2);
    u16*   pw3c   = (u16*)alloc(16384 * 2);
    u16*   fwc    = (u16*)alloc(32768 * 2);
    u16*   hbufb  = (u16*)alloc((size_t)N * 128 * 2);   // layers 2,3 h tables
    u16*   xb     = (u16*)alloc((size_t)N * 256 * 2);
    u16*   p2b    = (u16*)alloc((size_t)N * 128 * 2);
    u16*   xc     = (u16*)alloc((size_t)N * 64 * 2);    // layer-1 bf16 x table
    float* vbuf   = (float*)alloc(512 * 4);             // v_s/v_d [8][64]
    u16*   aggb   = (u16*)alloc((size_t)N * 256 * 2);   // layer-1 aggregate (bf16)
    u16*   x3b    = (u16*)alloc((size_t)N * 128 * 2);   // bf16 shadow of x3

    // ---- graph build phase A + weight cast + prep_v ----
    hipMemsetAsync(cnt, 0, (size_t)(N + 1 + NBUCK) * 4, stream);
    build_a_kernel<<<ABLOCKS + CBLOCKS + 1, 1024, 0, stream>>>(
        ei, bcnt, seg, W1, as1, ad1, vbuf,
        W1, w1c, 4096, W2, w2c, 8192, W3, w3c, 4096,
        pw2, pw2c, 2048, pw3, pw3c, 4096, fw, fwc, 8192);

    // ---- mid: build_b + esed1 + pn12 (independent, one launch) ----
    mid_kernel<<<NBUCK + 2 * GBLK, 256, 0, stream>>>(
        seg, bcnt, cnt, srcs16, ovbuf,
        x, vbuf, esb, edb, xc,
        pos, pw1, pb1, bn1g, bn1b, pw2c, p2b, pb2, bn2g, bn2b);

    const int NW = N / 4;   // one-wave-per-node kernels
    const int GB = GBLK;    // 625 GEMM row-blocks

    // ---- GAT layer 1 (aggregate-then-transform) ----
    gat_agg_kernel<<<NW, 256, 0, stream>>>(xc, esb, edb, cnt, srcs16, ovbuf, aggb, N);
    w1ln_kernel<<<GB, 256, 0, stream>>>(aggb, w1c, bg1, ln1g, ln1b, xb, N);

    // ---- GAT layer 2 ----
    gemm_scores_kernel<2, 64, false><<<dim3(GB, 1), 256, 0, stream>>>(
        xb, w2c, hbufb, as2, ad2, esb, edb, N, 128, 256);
    gat_fused_kernel<2, 64, true><<<NW, 256, 0, stream>>>(
        hbufb, esb, edb, cnt, srcs16, ovbuf, bg2, ln2g, ln2b, xb, nullptr, N);

    // ---- GAT layer 3 (out f32 -> x3, bf16 shadow -> x3b) ----
    gemm_scores_kernel<1, 128, false><<<dim3(GB, 1), 256, 0, stream>>>(
        xb, w3c, hbufb, as3, ad3, esb, edb, N, 128, 128);
    gat_fused_kernel<1, 128, false><<<NW, 256, 0, stream>>>(
        hbufb, esb, edb, cnt, srcs16, ovbuf, bg3, nullptr, nullptr, x3, x3b, N);

    // ---- pw3 GEMM + fusion GEMM (hoisted A-loads, bf16 x3, coalesced epilogues) ----
    gemm_pw3cat_kernel<<<GB, 256, 0, stream>>>(p2b, pw3c, pb3, pf, x3b, fwc, fb, out, N);
}

// Round 11
// 347.658 us; speedup vs baseline: 1.0626x; 1.0130x over previous
//
#include <hip/hip_runtime.h>
#include <cstddef>

#define NNODES 40000
#define NEDGES 640000
#define NETOT  (NNODES + NEDGES)
#define ELLW   96          // fixed edge slots per node; overflow -> spill list
#define NCAST  30720       // float4 groups across the 6 weight tensors
#define NBUCK  313         // dst>>7 buckets (128 nodes each)
#define SEGCAP 8192        // pairs per bucket segment (expected ~2300, +129 sigma)
#define ABLOCKS 84         // ceil(NETOT / 8192) edge-bucketing blocks
#define CBLOCKS 30         // NCAST / 1024 weight-cast blocks
#define GBLK   625         // NNODES / 64 row-blocks

typedef unsigned short u16;
typedef unsigned int   u32;
using v2f = __attribute__((ext_vector_type(2))) float;

// ---------------- helpers ----------------
__device__ inline float wave_sum(float v) {
#pragma unroll
    for (int o = 32; o > 0; o >>= 1) v += __shfl_xor(v, o);
    return v;
}
__device__ inline u16 f2bf(float f) {   // round-to-nearest-even f32 -> bf16
    u32 u = __float_as_uint(f);
    return (u16)((u + 0x7fffu + ((u >> 16) & 1u)) >> 16);
}

// ---------------- build phase A: bucket edges by dst range + weight cast + prep_v ----
__global__ void build_a_kernel(const int* __restrict__ ei, u32* __restrict__ bcnt,
                               u32* __restrict__ seg,
                               const float* __restrict__ W1, const float* __restrict__ as1,
                               const float* __restrict__ ad1, float* __restrict__ vbuf,
                               const float* s0, u16* d0, int n0, const float* s1, u16* d1, int n1,
                               const float* s2, u16* d2, int n2, const float* s3, u16* d3, int n3,
                               const float* s4, u16* d4, int n4, const float* s5, u16* d5, int n5) {
    int tid = threadIdx.x;
    int blk = blockIdx.x;
    if (blk >= ABLOCKS) {
        if (blk < ABLOCKS + CBLOCKS) {            // ---- weight cast ----
            int i = (blk - ABLOCKS) * 1024 + tid;
            const float* s; u16* d;
            if      (i < n0) { s = s0; d = d0; }
            else if ((i -= n0) < n1) { s = s1; d = d1; }
            else if ((i -= n1) < n2) { s = s2; d = d2; }
            else if ((i -= n2) < n3) { s = s3; d = d3; }
            else if ((i -= n3) < n4) { s = s4; d = d4; }
            else if ((i -= n4) < n5) { s = s5; d = d5; }
            else return;
            float4 v = ((const float4*)s)[i];
            ushort4 o; o.x = f2bf(v.x); o.y = f2bf(v.y); o.z = f2bf(v.z); o.w = f2bf(v.w);
            ((ushort4*)d)[i] = o;
        } else if (tid < 256) {                   // ---- prep_v: v_s[h]=W_h^T a_s[h], v_d ----
            int h = tid >> 6, k = tid & 63;
            float ss = 0.f, dd = 0.f;
            for (int c = 0; c < 64; c++) {
                float w = W1[(h * 64 + c) * 64 + k];
                ss += as1[h * 64 + c] * w;
                dd += ad1[h * 64 + c] * w;
            }
            vbuf[tid] = ss;
            vbuf[256 + tid] = dd;
        }
        return;
    }
    __shared__ u32 hist[NBUCK], hbase[NBUCK];
    for (int i = tid; i < NBUCK; i += 1024) hist[i] = 0;
    __syncthreads();
    u32 pk[8], loc[8]; int bj[8];
    int g0 = blk * 8192;
#pragma unroll
    for (int j = 0; j < 8; j++) {
        int g = g0 + j * 1024 + tid;
        bj[j] = -1;
        if (g < NETOT) {
            int src, dst;
            if (g < NEDGES) { src = ei[g]; dst = ei[NEDGES + g]; }
            else            { src = g - NEDGES; dst = src; }
            int b = dst >> 7;
            pk[j] = ((u32)dst << 16) | (u32)src;
            bj[j] = b;
            loc[j] = atomicAdd(&hist[b], 1u);
        }
    }
    __syncthreads();
    for (int i = tid; i < NBUCK; i += 1024) {
        u32 c = hist[i];
        hbase[i] = c ? atomicAdd(&bcnt[i], c) : 0u;
    }
    __syncthreads();
#pragma unroll
    for (int j = 0; j < 8; j++) {
        if (bj[j] >= 0) {
            u32 pos = hbase[bj[j]] + loc[j];
            if (pos < SEGCAP) seg[(size_t)bj[j] * SEGCAP + pos] = pk[j];
        }
    }
}

// ---------------- mid kernel: build_b (ELL fill) + esed1 (layer-1 scores/cast) + pn12 ----------------
__global__ void mid_kernel(const u32* __restrict__ seg, const u32* __restrict__ bcnt,
                           int* __restrict__ cnt, u16* __restrict__ srcs16,
                           int2* __restrict__ ovbuf,
                           const float* __restrict__ x, const float* __restrict__ vbuf,
                           float* __restrict__ es, float* __restrict__ ed, u16* __restrict__ xc,
                           const float* __restrict__ pos,
                           const float* __restrict__ pw1, const float* __restrict__ pb1,
                           const float* __restrict__ bn1g, const float* __restrict__ bn1b,
                           const u16* __restrict__ Bpn, u16* __restrict__ p2out,
                           const float* __restrict__ pb2,
                           const float* __restrict__ bn2g, const float* __restrict__ bn2b) {
    __shared__ u32 lcnt[128];
    __shared__ float vl[512];
    int tid = threadIdx.x;
    int blk = blockIdx.x;

    if (blk < NBUCK) {                            // ---- build_b: per-bucket ELL fill ----
        int base = blk << 7;
        if (tid < 128) lcnt[tid] = 0;
        __syncthreads();
        u32 m = bcnt[blk]; if (m > SEGCAP) m = SEGCAP;
        const u32* sp = seg + (size_t)blk * SEGCAP;
        for (u32 e = tid; e < m; e += 256) {
            u32 pkv = sp[e];
            u32 dst = pkv >> 16, src = pkv & 0xffffu;
            u32 p = atomicAdd(&lcnt[dst - (u32)base], 1u);
            if (p < ELLW) srcs16[dst * ELLW + p] = (u16)src;
            else {
                int q = atomicAdd(&cnt[NNODES], 1);   // rare spill
                ovbuf[q] = make_int2((int)dst, (int)src);
            }
        }
        __syncthreads();
        if (tid < 128 && base + tid < NNODES) cnt[base + tid] = (int)lcnt[tid];
        return;
    }
    blk -= NBUCK;
    if (blk < GBLK) {                             // ---- esed1: es/ed = x.v + cast x->bf16 ----
        vl[tid] = vbuf[tid];
        vl[tid + 256] = vbuf[tid + 256];
        __syncthreads();
        int lane = tid & 63, wave = tid >> 6;
        int i = lane >> 2, q = lane & 3;
        int node = blk * 64 + wave * 16 + i;
        const float* xp = x + (size_t)node * 64 + q * 16;
        float xr[16];
        *(float4*)&xr[0]  = ((const float4*)xp)[0];
        *(float4*)&xr[4]  = ((const float4*)xp)[1];
        *(float4*)&xr[8]  = ((const float4*)xp)[2];
        *(float4*)&xr[12] = ((const float4*)xp)[3];
        float p[8];
#pragma unroll
        for (int h = 0; h < 8; h++) {
            float s = 0.f;
#pragma unroll
            for (int j = 0; j < 16; j++) s += xr[j] * vl[h * 64 + q * 16 + j];
            p[h] = s;
        }
#pragma unroll
        for (int h = 0; h < 8; h++) {
            p[h] += __shfl_xor(p[h], 1);
            p[h] += __shfl_xor(p[h], 2);
        }
        es[node * 4 + q] = p[q];
        ed[node * 4 + q] = p[4 + q];
        u16* cp = xc + (size_t)node * 64 + q * 16;
#pragma unroll
        for (int j = 0; j < 16; j += 4) {
            ushort4 o; o.x = f2bf(xr[j]); o.y = f2bf(xr[j + 1]);
            o.z = f2bf(xr[j + 2]); o.w = f2bf(xr[j + 3]);
            *(ushort4*)(cp + j) = o;
        }
        return;
    }
    blk -= GBLK;                                  // ---- pn12 ----
    {
        const int Nn = 128, K = 64;
        using bfrag = __attribute__((ext_vector_type(8))) short;
        using ffrag = __attribute__((ext_vector_type(4))) float;
        int wave = tid >> 6, lane = tid & 63;
        int lm = lane & 15, kg = (lane >> 4) * 8;
        int rowblk = blk * 64 + wave * 16;
        int row = rowblk + lm;
        float p0 = pos[row * 3 + 0], p1 = pos[row * 3 + 1], p2 = pos[row * 3 + 2];
        const u16* Bp = Bpn + (size_t)lm * K + kg;
        const float bnscale = rsqrtf(1.0f + 1e-5f);
        ffrag acc[8] = {};
#pragma unroll
        for (int k0 = 0; k0 < K; k0 += 32) {
            bfrag af;
#pragma unroll
            for (int j = 0; j < 8; j++) {
                int k = kg + k0 + j;
                float v = p0 * pw1[k * 3 + 0] + p1 * pw1[k * 3 + 1] + p2 * pw1[k * 3 + 2] + pb1[k];
                v = v * (bn1g[k] * bnscale) + bn1b[k];
                v = v > 0.f ? v : 0.f;
                af[j] = (short)f2bf(v);
            }
#pragma unroll
            for (int t = 0; t < 8; t++) {
                bfrag bf = *(const bfrag*)(Bp + (size_t)t * 16 * K + k0);
                acc[t] = __builtin_amdgcn_mfma_f32_16x16x32_bf16(af, bf, acc[t], 0, 0, 0);
            }
        }
        int orow = rowblk + (lane >> 4) * 4;
#pragma unroll
        for (int t = 0; t < 8; t++) {
            int col = t * 16 + lm;
            float bi = pb2[col], g = bn2g[col] * bnscale, bb = bn2b[col];
#pragma unroll
            for (int r = 0; r < 4; r++) {
                float v = (acc[t][r] + bi) * g + bb;
                v = v > 0.f ? v : 0.f;
                p2out[(size_t)(orow + r) * Nn + col] = f2bf(v);
            }
        }
    }
}

// ---------------- layer-1 aggregation over x (64-dim rows, 128B) ----------------
__global__ void gat_agg_kernel(const u16* __restrict__ xc,
                               const float* __restrict__ es, const float* __restrict__ ed,
                               const int* __restrict__ cnt, const u16* __restrict__ srcs16,
                               const int2* __restrict__ ovbuf,
                               u16* __restrict__ agg, int n) {
    __shared__ float wbuf[4][4][100];
    __shared__ u32   sbuf[4][ELLW];
    int wave = threadIdx.x >> 6;
    int wid = (blockIdx.x * blockDim.x + threadIdx.x) >> 6;
    int lane = threadIdx.x & 63;
    if (wid >= n) return;

    int degt = cnt[wid];
    int mainc = degt < ELLW ? degt : ELLW;
    int padt = (mainc + 7) & ~7;
    const u16* sp = srcs16 + (size_t)wid * ELLW;

    const int h = lane & 3;
    const int esub = lane >> 2;
    float edh = ed[(size_t)wid * 4 + h];

    // ---- phase 1 ----
    float den = 0.f;
    for (int i0 = 0; i0 < padt; i0 += 16) {
        int e = i0 + esub;
        if (e < padt) {
            float w = 0.f; u32 off = 0;
            if (e < mainc) {
                int s = sp[e];
                off = (u32)s << 7;
                float v = es[(size_t)s * 4 + h] + edh;
                v = v > 0.f ? v : 0.2f * v;
                w = __expf(v);
            }
            wbuf[wave][h][e] = w;
            if (h == 0) sbuf[wave][e] = off;
            den += w;
        }
    }
    int ovn = 0;
    if (degt > ELLW) {
        ovn = cnt[n];
        for (int j = esub; j < ovn; j += 16) {
            int2 t = ovbuf[j];
            if (t.x == wid) {
                float v = es[(size_t)t.y * 4 + h] + edh;
                v = v > 0.f ? v : 0.2f * v;
                den += __expf(v);
            }
        }
    }
#pragma unroll
    for (int o = 4; o < 64; o <<= 1) den += __shfl_xor(den, o);
    float inv = 1.f / (den + 1e-16f);

    // ---- phase 2: gather 128B rows, accumulate all 4 heads ----
    const int e2 = lane >> 5, f16 = lane & 31;
    const char* hp = (const char*)xc + f16 * 4;
    v2f a0 = {0.f, 0.f}, a1 = {0.f, 0.f}, a2 = {0.f, 0.f}, a3 = {0.f, 0.f};
    for (int eb = 0; eb < padt; eb += 8) {
        u32 of[4]; u32 g[4];
        float w0[4], w1[4], w2[4], w3[4];
#pragma unroll
        for (int k = 0; k < 4; k++) of[k] = sbuf[wave][eb + 2 * k + e2];
#pragma unroll
        for (int k = 0; k < 4; k++) g[k] = *(const u32*)(hp + of[k]);
#pragma unroll
        for (int k = 0; k < 4; k++) {
            int e = eb + 2 * k + e2;
            w0[k] = wbuf[wave][0][e]; w1[k] = wbuf[wave][1][e];
            w2[k] = wbuf[wave][2][e]; w3[k] = wbuf[wave][3][e];
        }
#pragma unroll
        for (int k = 0; k < 4; k++) {
            v2f hx;
            hx.x = __uint_as_float(g[k] << 16);
            hx.y = __uint_as_float(g[k] & 0xffff0000u);
            a0 += v2f{w0[k], w0[k]} * hx;
            a1 += v2f{w1[k], w1[k]} * hx;
            a2 += v2f{w2[k], w2[k]} * hx;
            a3 += v2f{w3[k], w3[k]} * hx;
        }
    }
    if (degt > ELLW) {
        for (int j = 0; j < ovn; j++) {
            int2 t = ovbuf[j];
            if (t.x != wid) continue;
            float wh[4];
#pragma unroll
            for (int hh = 0; hh < 4; hh++) {
                float v = es[(size_t)t.y * 4 + hh] + __shfl(edh, hh);
                v = v > 0.f ? v : 0.2f * v;
                wh[hh] = __expf(v);
            }
            if (lane < 32) {
                u32 g = *(const u32*)(hp + ((u32)t.y << 7));
                v2f hx;
                hx.x = __uint_as_float(g << 16);
                hx.y = __uint_as_float(g & 0xffff0000u);
                a0 += v2f{wh[0], wh[0]} * hx;
                a1 += v2f{wh[1], wh[1]} * hx;
                a2 += v2f{wh[2], wh[2]} * hx;
                a3 += v2f{wh[3], wh[3]} * hx;
            }
        }
    }
    a0.x += __shfl_xor(a0.x, 32); a0.y += __shfl_xor(a0.y, 32);
    a1.x += __shfl_xor(a1.x, 32); a1.y += __shfl_xor(a1.y, 32);
    a2.x += __shfl_xor(a2.x, 32); a2.y += __shfl_xor(a2.y, 32);
    a3.x += __shfl_xor(a3.x, 32); a3.y += __shfl_xor(a3.y, 32);
    float iv[4];
#pragma unroll
    for (int hh = 0; hh < 4; hh++) iv[hh] = __shfl(inv, hh);
    if (lane < 32) {
        u32* op = (u32*)agg + (size_t)wid * 128 + f16;
        op[0]  = ((u32)f2bf(a0.y * iv[0]) << 16) | f2bf(a0.x * iv[0]);
        op[32] = ((u32)f2bf(a1.y * iv[1]) << 16) | f2bf(a1.x * iv[1]);
        op[64] = ((u32)f2bf(a2.y * iv[2]) << 16) | f2bf(a2.x * iv[2]);
        op[96] = ((u32)f2bf(a3.y * iv[3]) << 16) | f2bf(a3.x * iv[3]);
    }
}

// ---------------- layer-1 post-GEMM (block-diagonal per head) + bias + LN + ReLU -> xb bf16 ----------------
// launch_bounds(256,2): grid is only 2.44 waves/SIMD, so let the compiler use VGPRs for ILP.
__global__ __launch_bounds__(256, 2) void w1ln_kernel(
                            const u16* __restrict__ agg, const u16* __restrict__ B,
                            const float* __restrict__ bias,
                            const float* __restrict__ lng, const float* __restrict__ lnb,
                            u16* __restrict__ xb, int M) {
    using bfrag = __attribute__((ext_vector_type(8))) short;
    using ffrag = __attribute__((ext_vector_type(4))) float;
    int wave = threadIdx.x >> 6, lane = threadIdx.x & 63;
    int lm = lane & 15, kg = (lane >> 4) * 8;
    int rowblk = blockIdx.x * 64 + wave * 16;
    ffrag acc[16] = {};
#pragma unroll
    for (int hh = 0; hh < 4; hh++) {
#pragma unroll
        for (int k0 = 0; k0 < 64; k0 += 32) {
            bfrag af = *(const bfrag*)(agg + (size_t)(rowblk + lm) * 256 + hh * 64 + kg + k0);
            bfrag bfs[4];
#pragma unroll
            for (int tt = 0; tt < 4; tt++)
                bfs[tt] = *(const bfrag*)(B + (size_t)(hh * 64 + tt * 16 + lm) * 64 + kg + k0);
#pragma unroll
            for (int tt = 0; tt < 4; tt++) {
                int t = hh * 4 + tt;
                acc[t] = __builtin_amdgcn_mfma_f32_16x16x32_bf16(af, bfs[tt], acc[t], 0, 0, 0);
            }
        }
    }
    int orow = rowblk + (lane >> 4) * 4;
    float bi[16], gg[16], bb[16];
#pragma unroll
    for (int t = 0; t < 16; t++) {
        int col = t * 16 + lm;
        bi[t] = bias[col]; gg[t] = lng[col]; bb[t] = lnb[col];
    }
#pragma unroll
    for (int r = 0; r < 4; r++) {
        float pv[16];
        float s1 = 0.f, s2 = 0.f;
#pragma unroll
        for (int t = 0; t < 16; t++) {
            float v = acc[t][r] + bi[t];
            pv[t] = v; s1 += v; s2 += v * v;
        }
#pragma unroll
        for (int o = 1; o < 16; o <<= 1) { s1 += __shfl_xor(s1, o); s2 += __shfl_xor(s2, o); }
        float mu = s1 / 256.f;
        float var = s2 / 256.f - mu * mu;
        float rstd = rsqrtf(var + 1e-5f);
#pragma unroll
        for (int t = 0; t < 16; t++) {
            float v = (pv[t] - mu) * rstd * gg[t] + bb[t];
            v = v > 0.f ? v : 0.f;
            xb[(size_t)(orow + r) * 256 + t * 16 + lm] = f2bf(v);
        }
    }
}

// ---------------- GEMM (128-wide N tile) + fused attention scores (layers 2,3) ----------------
// launch_bounds(256,2) + per-k0 batched B-loads: 8 loads in flight, one wait, 8 MFMAs.
template <int H, int C, bool AF32>
__global__ __launch_bounds__(256, 2) void gemm_scores_kernel(
                                   const void* __restrict__ Aptr, const u16* __restrict__ B,
                                   u16* __restrict__ Cout,
                                   const float* __restrict__ as, const float* __restrict__ ad,
                                   float* __restrict__ es, float* __restrict__ ed,
                                   int M, int Nn, int K) {
    constexpr int HT = 128 / C;
    using bfrag = __attribute__((ext_vector_type(8))) short;
    using ffrag = __attribute__((ext_vector_type(4))) float;
    int wave = threadIdx.x >> 6, lane = threadIdx.x & 63;
    int lm = lane & 15, kg = (lane >> 4) * 8;
    int rowblk = blockIdx.x * 64 + wave * 16;
    int n0 = blockIdx.y * 128;
    const u16* Bp = B + (size_t)(n0 + lm) * K + kg;
    ffrag acc[8] = {};
    for (int k0 = 0; k0 < K; k0 += 32) {
        bfrag af;
        if constexpr (AF32) {
            const float* ap = (const float*)Aptr + (size_t)(rowblk + lm) * K + kg + k0;
            float4 a0 = *(const float4*)ap;
            float4 a1 = *(const float4*)(ap + 4);
            af[0] = (short)f2bf(a0.x); af[1] = (short)f2bf(a0.y);
            af[2] = (short)f2bf(a0.z); af[3] = (short)f2bf(a0.w);
            af[4] = (short)f2bf(a1.x); af[5] = (short)f2bf(a1.y);
            af[6] = (short)f2bf(a1.z); af[7] = (short)f2bf(a1.w);
        } else {
            af = *(const bfrag*)((const u16*)Aptr + (size_t)(rowblk + lm) * K + kg + k0);
        }
        bfrag bfs[8];
#pragma unroll
        for (int t = 0; t < 8; t++)
            bfs[t] = *(const bfrag*)(Bp + (size_t)t * 16 * K + k0);
#pragma unroll
        for (int t = 0; t < 8; t++)
            acc[t] = __builtin_amdgcn_mfma_f32_16x16x32_bf16(af, bfs[t], acc[t], 0, 0, 0);
    }
    int orow = rowblk + (lane >> 4) * 4;   // C/D: col = lane&15, row = (lane>>4)*4 + reg
    float asv[8], adv[8];
#pragma unroll
    for (int t = 0; t < 8; t++) {
        int fcol = n0 + t * 16 + lm;
        asv[t] = as[fcol]; adv[t] = ad[fcol];
    }
    float ps[4][HT] = {}, pd[4][HT] = {};
#pragma unroll
    for (int t = 0; t < 8; t++) {
        const int hh = t / (C / 16);
#pragma unroll
        for (int r = 0; r < 4; r++) {
            float v = acc[t][r];
            ps[r][hh] += v * asv[t];
            pd[r][hh] += v * adv[t];
            Cout[(size_t)(orow + r) * Nn + n0 + t * 16 + lm] = f2bf(v);
        }
    }
    int hb = blockIdx.y * HT;
#pragma unroll
    for (int r = 0; r < 4; r++)
#pragma unroll
        for (int hh = 0; hh < HT; hh++) {
            float s = ps[r][hh], d = pd[r][hh];
#pragma unroll
            for (int o = 1; o < 16; o <<= 1) { s += __shfl_xor(s, o); d += __shfl_xor(d, o); }
            if (lm == 0) {
                es[(size_t)(orow + r) * H + hb + hh] = s;
                ed[(size_t)(orow + r) * H + hb + hh] = d;
            }
        }
}

// ---------------- fused GAT softmax + aggregation (R1 chassis), layers 2,3 ----------------
template <int H, int C, bool LNRELU>
__global__ void gat_fused_kernel(const u16* __restrict__ hmat,
                                 const float* __restrict__ es, const float* __restrict__ ed,
                                 const int* __restrict__ cnt, const u16* __restrict__ srcs16,
                                 const int2* __restrict__ ovbuf,
                                 const float* __restrict__ bias,
                                 const float* __restrict__ lng, const float* __restrict__ lnb,
                                 void* __restrict__ out, u16* __restrict__ x16out, int n) {
    constexpr int HC = H * C;
    constexpr int VPT = HC / 64;
    constexpr int SH = (HC == 256) ? 9 : 8;      // byte-offset shift for h rows
    constexpr int EPW = 64 / H;                  // edges per phase-1 pass
    constexpr int HSH = (H == 4) ? 2 : ((H == 2) ? 1 : 0);
    __shared__ float wbuf[4][H][100];
    __shared__ int   sbuf[4][ELLW];
    int wave = threadIdx.x >> 6;
    int wid = (blockIdx.x * blockDim.x + threadIdx.x) >> 6;
    int lane = threadIdx.x & 63;
    if (wid >= n) return;

    int degt = cnt[wid];
    int mainc = degt < ELLW ? degt : ELLW;
    int pad = (mainc + 7) & ~7;
    const u16* sp = srcs16 + (size_t)wid * ELLW;

    const int h = lane & (H - 1);
    const int esub = lane >> HSH;
    float edh = ed[(size_t)wid * H + h];

    // ---- phase 1 ----
    float den = 0.f;
    for (int i0 = 0; i0 < pad; i0 += EPW) {
        int e = i0 + esub;
        if (e < pad) {
            float w = 0.f;
            int soff = 0;
            if (e < mainc) {
                int s = sp[e];
                soff = s << SH;
                float v = es[(size_t)s * H + h] + edh;
                v = v > 0.f ? v : 0.2f * v;
                w = __expf(v);
            }
            wbuf[wave][h][e] = w;
            if (h == 0) sbuf[wave][e] = soff;
            den += w;
        }
    }
    int ovn = 0;
    if (degt > ELLW) {
        ovn = cnt[n];
        for (int j = esub; j < ovn; j += EPW) {
            int2 t = ovbuf[j];
            if (t.x == wid) {
                float v = es[(size_t)t.y * H + h] + edh;
                v = v > 0.f ? v : 0.2f * v;
                den += __expf(v);
            }
        }
    }
#pragma unroll
    for (int o = H; o < 64; o <<= 1) den += __shfl_xor(den, o);
    float inv = 1.f / (den + 1e-16f);

    // ---- phase 2: 8-deep batches ----
    const int myhead = (lane * VPT) / C;
    const float invh = __shfl(inv, myhead);
    const int loff = lane * (VPT * 2);
    v2f a01 = {0.f, 0.f}, a23 = {0.f, 0.f};

    for (int e = 0; e < pad; e += 8) {
        int4   o0 = *(const int4*)&sbuf[wave][e];
        int4   o1 = *(const int4*)&sbuf[wave][e + 4];
        float4 w0 = *(const float4*)&wbuf[wave][myhead][e];
        float4 w1 = *(const float4*)&wbuf[wave][myhead][e + 4];
        int   oo[8] = {o0.x, o0.y, o0.z, o0.w, o1.x, o1.y, o1.z, o1.w};
        float ww[8] = {w0.x, w0.y, w0.z, w0.w, w1.x, w1.y, w1.z, w1.w};
        if constexpr (VPT == 4) {
            uint2 gg[8];
#pragma unroll
            for (int u = 0; u < 8; u++)
                gg[u] = *(const uint2*)((const char*)hmat + (size_t)(u32)oo[u] + loff);
#pragma unroll
            for (int u = 0; u < 8; u++) {
                v2f wv = {ww[u], ww[u]};
                v2f h01, h23;
                h01.x = __uint_as_float(gg[u].x << 16);
                h01.y = __uint_as_float(gg[u].x & 0xffff0000u);
                h23.x = __uint_as_float(gg[u].y << 16);
                h23.y = __uint_as_float(gg[u].y & 0xffff0000u);
                a01 += wv * h01;
                a23 += wv * h23;
            }
        } else {
            u32 gg[8];
#pragma unroll
            for (int u = 0; u < 8; u++)
                gg[u] = *(const u32*)((const char*)hmat + (size_t)(u32)oo[u] + loff);
#pragma unroll
            for (int u = 0; u < 8; u++) {
                v2f wv = {ww[u], ww[u]};
                v2f h01;
                h01.x = __uint_as_float(gg[u] << 16);
                h01.y = __uint_as_float(gg[u] & 0xffff0000u);
                a01 += wv * h01;
            }
        }
    }
    if (degt > ELLW) {
        const float edm = __shfl(edh, myhead);
        for (int j = 0; j < ovn; j++) {
            int2 t = ovbuf[j];
            if (t.x != wid) continue;
            float v = es[(size_t)t.y * H + myhead] + edm;
            v = v > 0.f ? v : 0.2f * v;
            float w = __expf(v);
            v2f wv = {w, w};
            if constexpr (VPT == 4) {
                uint2 g = *(const uint2*)((const char*)hmat + ((size_t)t.y << SH) + loff);
                v2f h01, h23;
                h01.x = __uint_as_float(g.x << 16);
                h01.y = __uint_as_float(g.x & 0xffff0000u);
                h23.x = __uint_as_float(g.y << 16);
                h23.y = __uint_as_float(g.y & 0xffff0000u);
                a01 += wv * h01;
                a23 += wv * h23;
            } else {
                u32 g = *(const u32*)((const char*)hmat + ((size_t)t.y << SH) + loff);
                v2f h01;
                h01.x = __uint_as_float(g << 16);
                h01.y = __uint_as_float(g & 0xffff0000u);
                a01 += wv * h01;
            }
        }
    }
    {
        v2f iv = {invh, invh};
        a01 *= iv;
        a23 *= iv;
    }

    int fbase = lane * VPT;
    float y[VPT];
    y[0] = a01.x + bias[fbase + 0];
    y[1] = a01.y + bias[fbase + 1];
    if constexpr (VPT == 4) {
        y[2] = a23.x + bias[fbase + 2];
        y[3] = a23.y + bias[fbase + 3];
    }

    if constexpr (LNRELU) {
        float s1 = 0.f, s2 = 0.f;
#pragma unroll
        for (int j = 0; j < VPT; j++) { s1 += y[j]; s2 += y[j] * y[j]; }
        s1 = wave_sum(s1);
        s2 = wave_sum(s2);
        float mu = s1 / (float)HC;
        float var = s2 / (float)HC - mu * mu;
        float rstd = rsqrtf(var + 1e-5f);
#pragma unroll
        for (int j = 0; j < VPT; j++) {
            float v = (y[j] - mu) * rstd * lng[fbase + j] + lnb[fbase + j];
            y[j] = v > 0.f ? v : 0.f;
        }
        u16* op = (u16*)out + (size_t)wid * HC + fbase;
        if constexpr (VPT == 4) {
            ushort4 o; o.x = f2bf(y[0]); o.y = f2bf(y[1]); o.z = f2bf(y[2]); o.w = f2bf(y[3]);
            *(ushort4*)op = o;
        } else {
            ushort2 o; o.x = f2bf(y[0]); o.y = f2bf(y[1]);
            *(ushort2*)op = o;
        }
    } else {
        float* op = (float*)out + (size_t)wid * HC + fbase;
        if constexpr (VPT == 4) *(float4*)op = make_float4(y[0], y[1], y[2], y[3]);
        else                    *(float2*)op = make_float2(y[0], y[1]);
        if (x16out) {                             // bf16 shadow copy for the final GEMM
            if constexpr (VPT == 4) {
                ushort4 o; o.x = f2bf(y[0]); o.y = f2bf(y[1]); o.z = f2bf(y[2]); o.w = f2bf(y[3]);
                *(ushort4*)&x16out[(size_t)wid * HC + fbase] = o;
            } else {
                ushort2 o; o.x = f2bf(y[0]); o.y = f2bf(y[1]);
                *(ushort2*)&x16out[(size_t)wid * HC + fbase] = o;
            }
        }
    }
}

// ---------------- fused: pf = p2@pw3^T + pb3; out = [x3b|pf]@fw^T + fb ----------------
// launch_bounds(256,2): VGPR cap 64 -> 256 so B-loads can be held in flight. B-loads are
// explicitly batched 16-deep (one wait per 16). Grid supplies only ~2.44 waves/SIMD, so
// per-wave ILP is the only latency cover available; this buys it with registers.
__global__ __launch_bounds__(256, 2) void gemm_pw3cat_kernel(
                                   const u16* __restrict__ p2, const u16* __restrict__ Bpw3,
                                   const float* __restrict__ pb3, float* __restrict__ pf,
                                   const u16* __restrict__ x3b, const u16* __restrict__ Bfw,
                                   const float* __restrict__ fb, float* __restrict__ outp,
                                   int M) {
    using bfrag = __attribute__((ext_vector_type(8))) short;
    using ffrag = __attribute__((ext_vector_type(4))) float;
    __shared__ float pft[64][132];   // stride 132: bank offset 4/row, 16B-aligned rows
    int wave = threadIdx.x >> 6, lane = threadIdx.x & 63;
    int lm = lane & 15, kg = (lane >> 4) * 8;
    int rowblk = blockIdx.x * 64 + wave * 16;
    int rowbase = blockIdx.x * 64;
    int row = rowblk + lm;

    // ---- issue stage-2 global A-loads early (independent of stage 1) ----
    bfrag afg[4];
#pragma unroll
    for (int i = 0; i < 4; i++)
        afg[i] = *(const bfrag*)(x3b + (size_t)row * 128 + kg + i * 32);

    // ---- stage 1: pf = p2@pw3^T + pb3 (K=128); B batched 16-deep ----
    {
        bfrag afs[4];
#pragma unroll
        for (int i = 0; i < 4; i++)
            afs[i] = *(const bfrag*)(p2 + (size_t)row * 128 + kg + i * 32);
        const u16* Bp = Bpw3 + (size_t)lm * 128 + kg;
        ffrag acc[8] = {};
#pragma unroll
        for (int kp = 0; kp < 2; kp++) {          // k-pairs: (0,1), (2,3)
            bfrag bfs[2][8];
#pragma unroll
            for (int kk = 0; kk < 2; kk++)
#pragma unroll
                for (int t = 0; t < 8; t++)
                    bfs[kk][t] = *(const bfrag*)(Bp + (size_t)t * 16 * 128 + (kp * 2 + kk) * 32);
#pragma unroll
            for (int kk = 0; kk < 2; kk++)
#pragma unroll
                for (int t = 0; t < 8; t++)
                    acc[t] = __builtin_amdgcn_mfma_f32_16x16x32_bf16(afs[kp * 2 + kk], bfs[kk][t], acc[t], 0, 0, 0);
        }
        int lrow = wave * 16 + (lane >> 4) * 4;
#pragma unroll
        for (int t = 0; t < 8; t++) {
            int col = t * 16 + lm;
            float bi = pb3[col];
#pragma unroll
            for (int r = 0; r < 4; r++)
                pft[lrow + r][col] = acc[t][r] + bi;
        }
    }
    __syncthreads();

    // ---- coalesced pf write from pft (reads only; no hazard vs stage-2 pft reads) ----
    for (int i = threadIdx.x; i < 2048; i += 256) {
        int rw = i >> 5, c4 = (i & 31) << 2;
        float4 v = *(const float4*)&pft[rw][c4];
        *(float4*)&pf[(size_t)(rowbase + rw) * 128 + c4] = v;
    }

    // ---- stage 2: out = [x3b|pf]@fw^T + fb (K=256); B batched 16-deep ----
    {
        int lrow = wave * 16 + lm;
        bfrag afl[4];
#pragma unroll
        for (int i = 0; i < 4; i++) {
            const float* ap = &pft[lrow][kg + i * 32];
            float4 a0 = *(const float4*)ap;
            float4 a1 = *(const float4*)(ap + 4);
            bfrag af;
            af[0] = (short)f2bf(a0.x); af[1] = (short)f2bf(a0.y);
            af[2] = (short)f2bf(a0.z); af[3] = (short)f2bf(a0.w);
            af[4] = (short)f2bf(a1.x); af[5] = (short)f2bf(a1.y);
            af[6] = (short)f2bf(a1.z); af[7] = (short)f2bf(a1.w);
            afl[i] = af;
        }
        const u16* Bp = Bfw + (size_t)lm * 256 + kg;
        ffrag acc[8] = {};
#pragma unroll
        for (int kp = 0; kp < 4; kp++) {          // k-pairs: (0,1)..(6,7)
            bfrag bfs[2][8];
#pragma unroll
            for (int kk = 0; kk < 2; kk++)
#pragma unroll
                for (int t = 0; t < 8; t++)
                    bfs[kk][t] = *(const bfrag*)(Bp + (size_t)t * 16 * 256 + (kp * 2 + kk) * 32);
#pragma unroll
            for (int kk = 0; kk < 2; kk++) {
                int k = kp * 2 + kk;
                bfrag af = (k < 4) ? afg[k] : afl[k - 4];
#pragma unroll
                for (int t = 0; t < 8; t++)
                    acc[t] = __builtin_amdgcn_mfma_f32_16x16x32_bf16(af, bfs[kk][t], acc[t], 0, 0, 0);
            }
        }
        __syncthreads();   // all pft reads (afl + pf copy) done before reuse
        int lrow2 = wave * 16 + (lane >> 4) * 4;
#pragma unroll
        for (int t = 0; t < 8; t++) {
            int col = t * 16 + lm;
            float bi = fb[col];
#pragma unroll
            for (int r = 0; r < 4; r++)
                pft[lrow2 + r][col] = acc[t][r] + bi;
        }
        __syncthreads();
        // ---- coalesced out write from pft ----
        for (int i = threadIdx.x; i < 2048; i += 256) {
            int rw2 = i >> 5, c4 = (i & 31) << 2;
            float4 v = *(const float4*)&pft[rw2][c4];
            *(float4*)&outp[(size_t)(rowbase + rw2) * 128 + c4] = v;
        }
    }
}

extern "C" void kernel_launch(void* const* d_in, const int* in_sizes, int n_in,
                              void* d_out, int out_size, void* d_ws, size_t ws_size,
                              hipStream_t stream) {
    const float* x    = (const float*)d_in[0];
    const int*   ei   = (const int*)d_in[1];
    const float* pos  = (const float*)d_in[2];
    const float* W1   = (const float*)d_in[3];
    const float* as1  = (const float*)d_in[4];
    const float* ad1  = (const float*)d_in[5];
    const float* bg1  = (const float*)d_in[6];
    const float* ln1g = (const float*)d_in[7];
    const float* ln1b = (const float*)d_in[8];
    const float* W2   = (const float*)d_in[9];
    const float* as2  = (const float*)d_in[10];
    const float* ad2  = (const float*)d_in[11];
    const float* bg2  = (const float*)d_in[12];
    const float* ln2g = (const float*)d_in[13];
    const float* ln2b = (const float*)d_in[14];
    const float* W3   = (const float*)d_in[15];
    const float* as3  = (const float*)d_in[16];
    const float* ad3  = (const float*)d_in[17];
    const float* bg3  = (const float*)d_in[18];
    const float* pw1  = (const float*)d_in[19];
    const float* pb1  = (const float*)d_in[20];
    const float* bn1g = (const float*)d_in[21];
    const float* bn1b = (const float*)d_in[22];
    const float* pw2  = (const float*)d_in[23];
    const float* pb2  = (const float*)d_in[24];
    const float* bn2g = (const float*)d_in[25];
    const float* bn2b = (const float*)d_in[26];
    const float* pw3  = (const float*)d_in[27];
    const float* pb3  = (const float*)d_in[28];
    const float* fw   = (const float*)d_in[29];
    const float* fb   = (const float*)d_in[30];

    const int N = NNODES;
    float* out = (float*)d_out;                    // [N,128]
    float* x3  = out + (size_t)N * 128;            // [N,128]
    float* pf  = out + (size_t)2 * N * 128;        // [N,128]

    char* ws = (char*)d_ws;
    size_t off = 0;
    auto alloc = [&](size_t bytes) -> void* {
        void* p = ws + off;
        off += (bytes + 255) / 256 * 256;
        return p;
    };
    int*   cnt    = (int*)alloc((size_t)(N + 1 + NBUCK) * 4);  // degrees + spill count + bucket cursors
    u32*   bcnt   = (u32*)(cnt + N + 1);
    u32*   seg    = (u32*)alloc((size_t)NBUCK * SEGCAP * 4);   // bucketed packed (dst<<16|src)
    u16*   srcs16 = (u16*)alloc((size_t)N * ELLW * 2);
    int2*  ovbuf  = (int2*)alloc((size_t)NETOT * 8);
    float* esb    = (float*)alloc((size_t)N * 4 * 4);
    float* edb    = (float*)alloc((size_t)N * 4 * 4);
    u16*   w1c    = (u16*)alloc(16384 * 2);
    u16*   w2c    = (u16*)alloc(32768 * 2);
    u16*   w3c    = (u16*)alloc(16384 * 2);
    u16*   pw2c   = (u16*)alloc(8192 * 2);
    u16*   pw3c   = (u16*)alloc(16384 * 2);
    u16*   fwc    = (u16*)alloc(32768 * 2);
    u16*   hbufb  = (u16*)alloc((size_t)N * 128 * 2);   // layers 2,3 h tables
    u16*   xb     = (u16*)alloc((size_t)N * 256 * 2);
    u16*   p2b    = (u16*)alloc((size_t)N * 128 * 2);
    u16*   xc     = (u16*)alloc((size_t)N * 64 * 2);    // layer-1 bf16 x table
    float* vbuf   = (float*)alloc(512 * 4);             // v_s/v_d [8][64]
    u16*   aggb   = (u16*)alloc((size_t)N * 256 * 2);   // layer-1 aggregate (bf16)
    u16*   x3b    = (u16*)alloc((size_t)N * 128 * 2);   // bf16 shadow of x3

    // ---- graph build phase A + weight cast + prep_v ----
    hipMemsetAsync(cnt, 0, (size_t)(N + 1 + NBUCK) * 4, stream);
    build_a_kernel<<<ABLOCKS + CBLOCKS + 1, 1024, 0, stream>>>(
        ei, bcnt, seg, W1, as1, ad1, vbuf,
        W1, w1c, 4096, W2, w2c, 8192, W3, w3c, 4096,
        pw2, pw2c, 2048, pw3, pw3c, 4096, fw, fwc, 8192);

    // ---- mid: build_b + esed1 + pn12 (independent, one launch) ----
    mid_kernel<<<NBUCK + 2 * GBLK, 256, 0, stream>>>(
        seg, bcnt, cnt, srcs16, ovbuf,
        x, vbuf, esb, edb, xc,
        pos, pw1, pb1, bn1g, bn1b, pw2c, p2b, pb2, bn2g, bn2b);

    const int NW = N / 4;   // one-wave-per-node kernels
    const int GB = GBLK;    // 625 GEMM row-blocks

    // ---- GAT layer 1 (aggregate-then-transform) ----
    gat_agg_kernel<<<NW, 256, 0, stream>>>(xc, esb, edb, cnt, srcs16, ovbuf, aggb, N);
    w1ln_kernel<<<GB, 256, 0, stream>>>(aggb, w1c, bg1, ln1g, ln1b, xb, N);

    // ---- GAT layer 2 ----
    gemm_scores_kernel<2, 64, false><<<dim3(GB, 1), 256, 0, stream>>>(
        xb, w2c, hbufb, as2, ad2, esb, edb, N, 128, 256);
    gat_fused_kernel<2, 64, true><<<NW, 256, 0, stream>>>(
        hbufb, esb, edb, cnt, srcs16, ovbuf, bg2, ln2g, ln2b, xb, nullptr, N);

    // ---- GAT layer 3 (out f32 -> x3, bf16 shadow -> x3b) ----
    gemm_scores_kernel<1, 128, false><<<dim3(GB, 1), 256, 0, stream>>>(
        xb, w3c, hbufb, as3, ad3, esb, edb, N, 128, 128);
    gat_fused_kernel<1, 128, false><<<NW, 256, 0, stream>>>(
        hbufb, esb, edb, cnt, srcs16, ovbuf, bg3, nullptr, nullptr, x3, x3b, N);

    // ---- pw3 GEMM + fusion GEMM (ILP-deep B batches, launch_bounds ILP) ----
    gemm_pw3cat_kernel<<<GB, 256, 0, stream>>>(p2b, pw3c, pb3, pf, x3b, fwc, fb, out, N);
}

// Round 12
// 334.775 us; speedup vs baseline: 1.1035x; 1.0385x over previous
//
#include <hip/hip_runtime.h>
#include <cstddef>

#define NNODES 40000
#define NEDGES 640000
#define NETOT  (NNODES + NEDGES)
#define ELLW   96          // fixed edge slots per node; overflow -> spill list
#define NCAST  30720       // float4 groups across the 6 weight tensors
#define NBUCK  313         // dst>>7 buckets (128 nodes each)
#define SEGCAP 8192        // pairs per bucket segment (expected ~2300, +129 sigma)
#define ABLOCKS 84         // ceil(NETOT / 8192) edge-bucketing blocks
#define CBLOCKS 30         // NCAST / 1024 weight-cast blocks
#define GBLK   625         // NNODES / 64 row-blocks

typedef unsigned short u16;
typedef unsigned int   u32;
using v2f = __attribute__((ext_vector_type(2))) float;

// ---------------- helpers ----------------
__device__ inline float wave_sum(float v) {
#pragma unroll
    for (int o = 32; o > 0; o >>= 1) v += __shfl_xor(v, o);
    return v;
}
__device__ inline u16 f2bf(float f) {   // round-to-nearest-even f32 -> bf16
    u32 u = __float_as_uint(f);
    return (u16)((u + 0x7fffu + ((u >> 16) & 1u)) >> 16);
}

// ---------------- build phase A: bucket edges by dst range + weight cast + prep_v ----
__global__ void build_a_kernel(const int* __restrict__ ei, u32* __restrict__ bcnt,
                               u32* __restrict__ seg,
                               const float* __restrict__ W1, const float* __restrict__ as1,
                               const float* __restrict__ ad1, float* __restrict__ vbuf,
                               const float* s0, u16* d0, int n0, const float* s1, u16* d1, int n1,
                               const float* s2, u16* d2, int n2, const float* s3, u16* d3, int n3,
                               const float* s4, u16* d4, int n4, const float* s5, u16* d5, int n5) {
    int tid = threadIdx.x;
    int blk = blockIdx.x;
    if (blk >= ABLOCKS) {
        if (blk < ABLOCKS + CBLOCKS) {            // ---- weight cast ----
            int i = (blk - ABLOCKS) * 1024 + tid;
            const float* s; u16* d;
            if      (i < n0) { s = s0; d = d0; }
            else if ((i -= n0) < n1) { s = s1; d = d1; }
            else if ((i -= n1) < n2) { s = s2; d = d2; }
            else if ((i -= n2) < n3) { s = s3; d = d3; }
            else if ((i -= n3) < n4) { s = s4; d = d4; }
            else if ((i -= n4) < n5) { s = s5; d = d5; }
            else return;
            float4 v = ((const float4*)s)[i];
            ushort4 o; o.x = f2bf(v.x); o.y = f2bf(v.y); o.z = f2bf(v.z); o.w = f2bf(v.w);
            ((ushort4*)d)[i] = o;
        } else if (tid < 256) {                   // ---- prep_v: v_s[h]=W_h^T a_s[h], v_d ----
            int h = tid >> 6, k = tid & 63;
            float ss = 0.f, dd = 0.f;
            for (int c = 0; c < 64; c++) {
                float w = W1[(h * 64 + c) * 64 + k];
                ss += as1[h * 64 + c] * w;
                dd += ad1[h * 64 + c] * w;
            }
            vbuf[tid] = ss;
            vbuf[256 + tid] = dd;
        }
        return;
    }
    __shared__ u32 hist[NBUCK], hbase[NBUCK];
    for (int i = tid; i < NBUCK; i += 1024) hist[i] = 0;
    __syncthreads();
    u32 pk[8], loc[8]; int bj[8];
    int g0 = blk * 8192;
#pragma unroll
    for (int j = 0; j < 8; j++) {
        int g = g0 + j * 1024 + tid;
        bj[j] = -1;
        if (g < NETOT) {
            int src, dst;
            if (g < NEDGES) { src = ei[g]; dst = ei[NEDGES + g]; }
            else            { src = g - NEDGES; dst = src; }
            int b = dst >> 7;
            pk[j] = ((u32)dst << 16) | (u32)src;
            bj[j] = b;
            loc[j] = atomicAdd(&hist[b], 1u);
        }
    }
    __syncthreads();
    for (int i = tid; i < NBUCK; i += 1024) {
        u32 c = hist[i];
        hbase[i] = c ? atomicAdd(&bcnt[i], c) : 0u;
    }
    __syncthreads();
#pragma unroll
    for (int j = 0; j < 8; j++) {
        if (bj[j] >= 0) {
            u32 pos = hbase[bj[j]] + loc[j];
            if (pos < SEGCAP) seg[(size_t)bj[j] * SEGCAP + pos] = pk[j];
        }
    }
}

// ---------------- mid kernel: build_b (ELL fill) + esed1 (layer-1 scores/cast) + pn12 ----------------
__global__ void mid_kernel(const u32* __restrict__ seg, const u32* __restrict__ bcnt,
                           int* __restrict__ cnt, u16* __restrict__ srcs16,
                           int2* __restrict__ ovbuf,
                           const float* __restrict__ x, const float* __restrict__ vbuf,
                           float* __restrict__ es, float* __restrict__ ed, u16* __restrict__ xc,
                           const float* __restrict__ pos,
                           const float* __restrict__ pw1, const float* __restrict__ pb1,
                           const float* __restrict__ bn1g, const float* __restrict__ bn1b,
                           const u16* __restrict__ Bpn, u16* __restrict__ p2out,
                           const float* __restrict__ pb2,
                           const float* __restrict__ bn2g, const float* __restrict__ bn2b) {
    __shared__ u32 lcnt[128];
    __shared__ float vl[512];
    int tid = threadIdx.x;
    int blk = blockIdx.x;

    if (blk < NBUCK) {                            // ---- build_b: per-bucket ELL fill ----
        int base = blk << 7;
        if (tid < 128) lcnt[tid] = 0;
        __syncthreads();
        u32 m = bcnt[blk]; if (m > SEGCAP) m = SEGCAP;
        const u32* sp = seg + (size_t)blk * SEGCAP;
        for (u32 e = tid; e < m; e += 256) {
            u32 pkv = sp[e];
            u32 dst = pkv >> 16, src = pkv & 0xffffu;
            u32 p = atomicAdd(&lcnt[dst - (u32)base], 1u);
            if (p < ELLW) srcs16[dst * ELLW + p] = (u16)src;
            else {
                int q = atomicAdd(&cnt[NNODES], 1);   // rare spill
                ovbuf[q] = make_int2((int)dst, (int)src);
            }
        }
        __syncthreads();
        if (tid < 128 && base + tid < NNODES) cnt[base + tid] = (int)lcnt[tid];
        return;
    }
    blk -= NBUCK;
    if (blk < GBLK) {                             // ---- esed1: es/ed = x.v + cast x->bf16 ----
        vl[tid] = vbuf[tid];
        vl[tid + 256] = vbuf[tid + 256];
        __syncthreads();
        int lane = tid & 63, wave = tid >> 6;
        int i = lane >> 2, q = lane & 3;
        int node = blk * 64 + wave * 16 + i;
        const float* xp = x + (size_t)node * 64 + q * 16;
        float xr[16];
        *(float4*)&xr[0]  = ((const float4*)xp)[0];
        *(float4*)&xr[4]  = ((const float4*)xp)[1];
        *(float4*)&xr[8]  = ((const float4*)xp)[2];
        *(float4*)&xr[12] = ((const float4*)xp)[3];
        float p[8];
#pragma unroll
        for (int h = 0; h < 8; h++) {
            float s = 0.f;
#pragma unroll
            for (int j = 0; j < 16; j++) s += xr[j] * vl[h * 64 + q * 16 + j];
            p[h] = s;
        }
#pragma unroll
        for (int h = 0; h < 8; h++) {
            p[h] += __shfl_xor(p[h], 1);
            p[h] += __shfl_xor(p[h], 2);
        }
        es[node * 4 + q] = p[q];
        ed[node * 4 + q] = p[4 + q];
        u16* cp = xc + (size_t)node * 64 + q * 16;
#pragma unroll
        for (int j = 0; j < 16; j += 4) {
            ushort4 o; o.x = f2bf(xr[j]); o.y = f2bf(xr[j + 1]);
            o.z = f2bf(xr[j + 2]); o.w = f2bf(xr[j + 3]);
            *(ushort4*)(cp + j) = o;
        }
        return;
    }
    blk -= GBLK;                                  // ---- pn12 ----
    {
        const int Nn = 128, K = 64;
        using bfrag = __attribute__((ext_vector_type(8))) short;
        using ffrag = __attribute__((ext_vector_type(4))) float;
        int wave = tid >> 6, lane = tid & 63;
        int lm = lane & 15, kg = (lane >> 4) * 8;
        int rowblk = blk * 64 + wave * 16;
        int row = rowblk + lm;
        float p0 = pos[row * 3 + 0], p1 = pos[row * 3 + 1], p2 = pos[row * 3 + 2];
        const u16* Bp = Bpn + (size_t)lm * K + kg;
        const float bnscale = rsqrtf(1.0f + 1e-5f);
        ffrag acc[8] = {};
#pragma unroll
        for (int k0 = 0; k0 < K; k0 += 32) {
            bfrag af;
#pragma unroll
            for (int j = 0; j < 8; j++) {
                int k = kg + k0 + j;
                float v = p0 * pw1[k * 3 + 0] + p1 * pw1[k * 3 + 1] + p2 * pw1[k * 3 + 2] + pb1[k];
                v = v * (bn1g[k] * bnscale) + bn1b[k];
                v = v > 0.f ? v : 0.f;
                af[j] = (short)f2bf(v);
            }
#pragma unroll
            for (int t = 0; t < 8; t++) {
                bfrag bf = *(const bfrag*)(Bp + (size_t)t * 16 * K + k0);
                acc[t] = __builtin_amdgcn_mfma_f32_16x16x32_bf16(af, bf, acc[t], 0, 0, 0);
            }
        }
        int orow = rowblk + (lane >> 4) * 4;
#pragma unroll
        for (int t = 0; t < 8; t++) {
            int col = t * 16 + lm;
            float bi = pb2[col], g = bn2g[col] * bnscale, bb = bn2b[col];
#pragma unroll
            for (int r = 0; r < 4; r++) {
                float v = (acc[t][r] + bi) * g + bb;
                v = v > 0.f ? v : 0.f;
                p2out[(size_t)(orow + r) * Nn + col] = f2bf(v);
            }
        }
    }
}

// ---------------- layer-1 aggregation over x (64-dim rows, 128B) ----------------
__global__ void gat_agg_kernel(const u16* __restrict__ xc,
                               const float* __restrict__ es, const float* __restrict__ ed,
                               const int* __restrict__ cnt, const u16* __restrict__ srcs16,
                               const int2* __restrict__ ovbuf,
                               u16* __restrict__ agg, int n) {
    __shared__ float wbuf[4][4][100];
    __shared__ u32   sbuf[4][ELLW];
    int wave = threadIdx.x >> 6;
    int wid = (blockIdx.x * blockDim.x + threadIdx.x) >> 6;
    int lane = threadIdx.x & 63;
    if (wid >= n) return;

    int degt = cnt[wid];
    int mainc = degt < ELLW ? degt : ELLW;
    int padt = (mainc + 7) & ~7;
    const u16* sp = srcs16 + (size_t)wid * ELLW;

    const int h = lane & 3;
    const int esub = lane >> 2;
    float edh = ed[(size_t)wid * 4 + h];

    // ---- phase 1 ----
    float den = 0.f;
    for (int i0 = 0; i0 < padt; i0 += 16) {
        int e = i0 + esub;
        if (e < padt) {
            float w = 0.f; u32 off = 0;
            if (e < mainc) {
                int s = sp[e];
                off = (u32)s << 7;
                float v = es[(size_t)s * 4 + h] + edh;
                v = v > 0.f ? v : 0.2f * v;
                w = __expf(v);
            }
            wbuf[wave][h][e] = w;
            if (h == 0) sbuf[wave][e] = off;
            den += w;
        }
    }
    int ovn = 0;
    if (degt > ELLW) {
        ovn = cnt[n];
        for (int j = esub; j < ovn; j += 16) {
            int2 t = ovbuf[j];
            if (t.x == wid) {
                float v = es[(size_t)t.y * 4 + h] + edh;
                v = v > 0.f ? v : 0.2f * v;
                den += __expf(v);
            }
        }
    }
#pragma unroll
    for (int o = 4; o < 64; o <<= 1) den += __shfl_xor(den, o);
    float inv = 1.f / (den + 1e-16f);

    // ---- phase 2: gather 128B rows, accumulate all 4 heads ----
    const int e2 = lane >> 5, f16 = lane & 31;
    const char* hp = (const char*)xc + f16 * 4;
    v2f a0 = {0.f, 0.f}, a1 = {0.f, 0.f}, a2 = {0.f, 0.f}, a3 = {0.f, 0.f};
    for (int eb = 0; eb < padt; eb += 8) {
        u32 of[4]; u32 g[4];
        float w0[4], w1[4], w2[4], w3[4];
#pragma unroll
        for (int k = 0; k < 4; k++) of[k] = sbuf[wave][eb + 2 * k + e2];
#pragma unroll
        for (int k = 0; k < 4; k++) g[k] = *(const u32*)(hp + of[k]);
#pragma unroll
        for (int k = 0; k < 4; k++) {
            int e = eb + 2 * k + e2;
            w0[k] = wbuf[wave][0][e]; w1[k] = wbuf[wave][1][e];
            w2[k] = wbuf[wave][2][e]; w3[k] = wbuf[wave][3][e];
        }
#pragma unroll
        for (int k = 0; k < 4; k++) {
            v2f hx;
            hx.x = __uint_as_float(g[k] << 16);
            hx.y = __uint_as_float(g[k] & 0xffff0000u);
            a0 += v2f{w0[k], w0[k]} * hx;
            a1 += v2f{w1[k], w1[k]} * hx;
            a2 += v2f{w2[k], w2[k]} * hx;
            a3 += v2f{w3[k], w3[k]} * hx;
        }
    }
    if (degt > ELLW) {
        for (int j = 0; j < ovn; j++) {
            int2 t = ovbuf[j];
            if (t.x != wid) continue;
            float wh[4];
#pragma unroll
            for (int hh = 0; hh < 4; hh++) {
                float v = es[(size_t)t.y * 4 + hh] + __shfl(edh, hh);
                v = v > 0.f ? v : 0.2f * v;
                wh[hh] = __expf(v);
            }
            if (lane < 32) {
                u32 g = *(const u32*)(hp + ((u32)t.y << 7));
                v2f hx;
                hx.x = __uint_as_float(g << 16);
                hx.y = __uint_as_float(g & 0xffff0000u);
                a0 += v2f{wh[0], wh[0]} * hx;
                a1 += v2f{wh[1], wh[1]} * hx;
                a2 += v2f{wh[2], wh[2]} * hx;
                a3 += v2f{wh[3], wh[3]} * hx;
            }
        }
    }
    a0.x += __shfl_xor(a0.x, 32); a0.y += __shfl_xor(a0.y, 32);
    a1.x += __shfl_xor(a1.x, 32); a1.y += __shfl_xor(a1.y, 32);
    a2.x += __shfl_xor(a2.x, 32); a2.y += __shfl_xor(a2.y, 32);
    a3.x += __shfl_xor(a3.x, 32); a3.y += __shfl_xor(a3.y, 32);
    float iv[4];
#pragma unroll
    for (int hh = 0; hh < 4; hh++) iv[hh] = __shfl(inv, hh);
    if (lane < 32) {
        u32* op = (u32*)agg + (size_t)wid * 128 + f16;
        op[0]  = ((u32)f2bf(a0.y * iv[0]) << 16) | f2bf(a0.x * iv[0]);
        op[32] = ((u32)f2bf(a1.y * iv[1]) << 16) | f2bf(a1.x * iv[1]);
        op[64] = ((u32)f2bf(a2.y * iv[2]) << 16) | f2bf(a2.x * iv[2]);
        op[96] = ((u32)f2bf(a3.y * iv[3]) << 16) | f2bf(a3.x * iv[3]);
    }
}

// ---------------- layer-1 post-GEMM (block-diagonal per head) + bias + LN + ReLU -> xb bf16 ----------------
__global__ __launch_bounds__(256, 2) void w1ln_kernel(
                            const u16* __restrict__ agg, const u16* __restrict__ B,
                            const float* __restrict__ bias,
                            const float* __restrict__ lng, const float* __restrict__ lnb,
                            u16* __restrict__ xb, int M) {
    using bfrag = __attribute__((ext_vector_type(8))) short;
    using ffrag = __attribute__((ext_vector_type(4))) float;
    int wave = threadIdx.x >> 6, lane = threadIdx.x & 63;
    int lm = lane & 15, kg = (lane >> 4) * 8;
    int rowblk = blockIdx.x * 64 + wave * 16;
    ffrag acc[16] = {};
#pragma unroll
    for (int hh = 0; hh < 4; hh++) {
#pragma unroll
        for (int k0 = 0; k0 < 64; k0 += 32) {
            bfrag af = *(const bfrag*)(agg + (size_t)(rowblk + lm) * 256 + hh * 64 + kg + k0);
            bfrag bfs[4];
#pragma unroll
            for (int tt = 0; tt < 4; tt++)
                bfs[tt] = *(const bfrag*)(B + (size_t)(hh * 64 + tt * 16 + lm) * 64 + kg + k0);
#pragma unroll
            for (int tt = 0; tt < 4; tt++) {
                int t = hh * 4 + tt;
                acc[t] = __builtin_amdgcn_mfma_f32_16x16x32_bf16(af, bfs[tt], acc[t], 0, 0, 0);
            }
        }
    }
    int orow = rowblk + (lane >> 4) * 4;
    float bi[16], gg[16], bb[16];
#pragma unroll
    for (int t = 0; t < 16; t++) {
        int col = t * 16 + lm;
        bi[t] = bias[col]; gg[t] = lng[col]; bb[t] = lnb[col];
    }
#pragma unroll
    for (int r = 0; r < 4; r++) {
        float pv[16];
        float s1 = 0.f, s2 = 0.f;
#pragma unroll
        for (int t = 0; t < 16; t++) {
            float v = acc[t][r] + bi[t];
            pv[t] = v; s1 += v; s2 += v * v;
        }
#pragma unroll
        for (int o = 1; o < 16; o <<= 1) { s1 += __shfl_xor(s1, o); s2 += __shfl_xor(s2, o); }
        float mu = s1 / 256.f;
        float var = s2 / 256.f - mu * mu;
        float rstd = rsqrtf(var + 1e-5f);
#pragma unroll
        for (int t = 0; t < 16; t++) {
            float v = (pv[t] - mu) * rstd * gg[t] + bb[t];
            v = v > 0.f ? v : 0.f;
            xb[(size_t)(orow + r) * 256 + t * 16 + lm] = f2bf(v);
        }
    }
}

// ---------------- GEMM (128-wide N tile) + fused attention scores (layers 2,3) ----------------
template <int H, int C, bool AF32>
__global__ __launch_bounds__(256, 2) void gemm_scores_kernel(
                                   const void* __restrict__ Aptr, const u16* __restrict__ B,
                                   u16* __restrict__ Cout,
                                   const float* __restrict__ as, const float* __restrict__ ad,
                                   float* __restrict__ es, float* __restrict__ ed,
                                   int M, int Nn, int K) {
    constexpr int HT = 128 / C;
    using bfrag = __attribute__((ext_vector_type(8))) short;
    using ffrag = __attribute__((ext_vector_type(4))) float;
    int wave = threadIdx.x >> 6, lane = threadIdx.x & 63;
    int lm = lane & 15, kg = (lane >> 4) * 8;
    int rowblk = blockIdx.x * 64 + wave * 16;
    int n0 = blockIdx.y * 128;
    const u16* Bp = B + (size_t)(n0 + lm) * K + kg;
    ffrag acc[8] = {};
    for (int k0 = 0; k0 < K; k0 += 32) {
        bfrag af;
        if constexpr (AF32) {
            const float* ap = (const float*)Aptr + (size_t)(rowblk + lm) * K + kg + k0;
            float4 a0 = *(const float4*)ap;
            float4 a1 = *(const float4*)(ap + 4);
            af[0] = (short)f2bf(a0.x); af[1] = (short)f2bf(a0.y);
            af[2] = (short)f2bf(a0.z); af[3] = (short)f2bf(a0.w);
            af[4] = (short)f2bf(a1.x); af[5] = (short)f2bf(a1.y);
            af[6] = (short)f2bf(a1.z); af[7] = (short)f2bf(a1.w);
        } else {
            af = *(const bfrag*)((const u16*)Aptr + (size_t)(rowblk + lm) * K + kg + k0);
        }
        bfrag bfs[8];
#pragma unroll
        for (int t = 0; t < 8; t++)
            bfs[t] = *(const bfrag*)(Bp + (size_t)t * 16 * K + k0);
#pragma unroll
        for (int t = 0; t < 8; t++)
            acc[t] = __builtin_amdgcn_mfma_f32_16x16x32_bf16(af, bfs[t], acc[t], 0, 0, 0);
    }
    int orow = rowblk + (lane >> 4) * 4;   // C/D: col = lane&15, row = (lane>>4)*4 + reg
    float asv[8], adv[8];
#pragma unroll
    for (int t = 0; t < 8; t++) {
        int fcol = n0 + t * 16 + lm;
        asv[t] = as[fcol]; adv[t] = ad[fcol];
    }
    float ps[4][HT] = {}, pd[4][HT] = {};
#pragma unroll
    for (int t = 0; t < 8; t++) {
        const int hh = t / (C / 16);
#pragma unroll
        for (int r = 0; r < 4; r++) {
            float v = acc[t][r];
            ps[r][hh] += v * asv[t];
            pd[r][hh] += v * adv[t];
            Cout[(size_t)(orow + r) * Nn + n0 + t * 16 + lm] = f2bf(v);
        }
    }
    int hb = blockIdx.y * HT;
#pragma unroll
    for (int r = 0; r < 4; r++)
#pragma unroll
        for (int hh = 0; hh < HT; hh++) {
            float s = ps[r][hh], d = pd[r][hh];
#pragma unroll
            for (int o = 1; o < 16; o <<= 1) { s += __shfl_xor(s, o); d += __shfl_xor(d, o); }
            if (lm == 0) {
                es[(size_t)(orow + r) * H + hb + hh] = s;
                ed[(size_t)(orow + r) * H + hb + hh] = d;
            }
        }
}

// ---------------- fused GAT softmax + aggregation (R1 chassis), layers 2,3 ----------------
template <int H, int C, bool LNRELU>
__global__ void gat_fused_kernel(const u16* __restrict__ hmat,
                                 const float* __restrict__ es, const float* __restrict__ ed,
                                 const int* __restrict__ cnt, const u16* __restrict__ srcs16,
                                 const int2* __restrict__ ovbuf,
                                 const float* __restrict__ bias,
                                 const float* __restrict__ lng, const float* __restrict__ lnb,
                                 void* __restrict__ out, u16* __restrict__ x16out, int n) {
    constexpr int HC = H * C;
    constexpr int VPT = HC / 64;
    constexpr int SH = (HC == 256) ? 9 : 8;      // byte-offset shift for h rows
    constexpr int EPW = 64 / H;                  // edges per phase-1 pass
    constexpr int HSH = (H == 4) ? 2 : ((H == 2) ? 1 : 0);
    __shared__ float wbuf[4][H][100];
    __shared__ int   sbuf[4][ELLW];
    int wave = threadIdx.x >> 6;
    int wid = (blockIdx.x * blockDim.x + threadIdx.x) >> 6;
    int lane = threadIdx.x & 63;
    if (wid >= n) return;

    int degt = cnt[wid];
    int mainc = degt < ELLW ? degt : ELLW;
    int pad = (mainc + 7) & ~7;
    const u16* sp = srcs16 + (size_t)wid * ELLW;

    const int h = lane & (H - 1);
    const int esub = lane >> HSH;
    float edh = ed[(size_t)wid * H + h];

    // ---- phase 1 ----
    float den = 0.f;
    for (int i0 = 0; i0 < pad; i0 += EPW) {
        int e = i0 + esub;
        if (e < pad) {
            float w = 0.f;
            int soff = 0;
            if (e < mainc) {
                int s = sp[e];
                soff = s << SH;
                float v = es[(size_t)s * H + h] + edh;
                v = v > 0.f ? v : 0.2f * v;
                w = __expf(v);
            }
            wbuf[wave][h][e] = w;
            if (h == 0) sbuf[wave][e] = soff;
            den += w;
        }
    }
    int ovn = 0;
    if (degt > ELLW) {
        ovn = cnt[n];
        for (int j = esub; j < ovn; j += EPW) {
            int2 t = ovbuf[j];
            if (t.x == wid) {
                float v = es[(size_t)t.y * H + h] + edh;
                v = v > 0.f ? v : 0.2f * v;
                den += __expf(v);
            }
        }
    }
#pragma unroll
    for (int o = H; o < 64; o <<= 1) den += __shfl_xor(den, o);
    float inv = 1.f / (den + 1e-16f);

    // ---- phase 2: 8-deep batches ----
    const int myhead = (lane * VPT) / C;
    const float invh = __shfl(inv, myhead);
    const int loff = lane * (VPT * 2);
    v2f a01 = {0.f, 0.f}, a23 = {0.f, 0.f};

    for (int e = 0; e < pad; e += 8) {
        int4   o0 = *(const int4*)&sbuf[wave][e];
        int4   o1 = *(const int4*)&sbuf[wave][e + 4];
        float4 w0 = *(const float4*)&wbuf[wave][myhead][e];
        float4 w1 = *(const float4*)&wbuf[wave][myhead][e + 4];
        int   oo[8] = {o0.x, o0.y, o0.z, o0.w, o1.x, o1.y, o1.z, o1.w};
        float ww[8] = {w0.x, w0.y, w0.z, w0.w, w1.x, w1.y, w1.z, w1.w};
        if constexpr (VPT == 4) {
            uint2 gg[8];
#pragma unroll
            for (int u = 0; u < 8; u++)
                gg[u] = *(const uint2*)((const char*)hmat + (size_t)(u32)oo[u] + loff);
#pragma unroll
            for (int u = 0; u < 8; u++) {
                v2f wv = {ww[u], ww[u]};
                v2f h01, h23;
                h01.x = __uint_as_float(gg[u].x << 16);
                h01.y = __uint_as_float(gg[u].x & 0xffff0000u);
                h23.x = __uint_as_float(gg[u].y << 16);
                h23.y = __uint_as_float(gg[u].y & 0xffff0000u);
                a01 += wv * h01;
                a23 += wv * h23;
            }
        } else {
            u32 gg[8];
#pragma unroll
            for (int u = 0; u < 8; u++)
                gg[u] = *(const u32*)((const char*)hmat + (size_t)(u32)oo[u] + loff);
#pragma unroll
            for (int u = 0; u < 8; u++) {
                v2f wv = {ww[u], ww[u]};
                v2f h01;
                h01.x = __uint_as_float(gg[u] << 16);
                h01.y = __uint_as_float(gg[u] & 0xffff0000u);
                a01 += wv * h01;
            }
        }
    }
    if (degt > ELLW) {
        const float edm = __shfl(edh, myhead);
        for (int j = 0; j < ovn; j++) {
            int2 t = ovbuf[j];
            if (t.x != wid) continue;
            float v = es[(size_t)t.y * H + myhead] + edm;
            v = v > 0.f ? v : 0.2f * v;
            float w = __expf(v);
            v2f wv = {w, w};
            if constexpr (VPT == 4) {
                uint2 g = *(const uint2*)((const char*)hmat + ((size_t)t.y << SH) + loff);
                v2f h01, h23;
                h01.x = __uint_as_float(g.x << 16);
                h01.y = __uint_as_float(g.x & 0xffff0000u);
                h23.x = __uint_as_float(g.y << 16);
                h23.y = __uint_as_float(g.y & 0xffff0000u);
                a01 += wv * h01;
                a23 += wv * h23;
            } else {
                u32 g = *(const u32*)((const char*)hmat + ((size_t)t.y << SH) + loff);
                v2f h01;
                h01.x = __uint_as_float(g << 16);
                h01.y = __uint_as_float(g & 0xffff0000u);
                a01 += wv * h01;
            }
        }
    }
    {
        v2f iv = {invh, invh};
        a01 *= iv;
        a23 *= iv;
    }

    int fbase = lane * VPT;
    float y[VPT];
    y[0] = a01.x + bias[fbase + 0];
    y[1] = a01.y + bias[fbase + 1];
    if constexpr (VPT == 4) {
        y[2] = a23.x + bias[fbase + 2];
        y[3] = a23.y + bias[fbase + 3];
    }

    if constexpr (LNRELU) {
        float s1 = 0.f, s2 = 0.f;
#pragma unroll
        for (int j = 0; j < VPT; j++) { s1 += y[j]; s2 += y[j] * y[j]; }
        s1 = wave_sum(s1);
        s2 = wave_sum(s2);
        float mu = s1 / (float)HC;
        float var = s2 / (float)HC - mu * mu;
        float rstd = rsqrtf(var + 1e-5f);
#pragma unroll
        for (int j = 0; j < VPT; j++) {
            float v = (y[j] - mu) * rstd * lng[fbase + j] + lnb[fbase + j];
            y[j] = v > 0.f ? v : 0.f;
        }
        u16* op = (u16*)out + (size_t)wid * HC + fbase;
        if constexpr (VPT == 4) {
            ushort4 o; o.x = f2bf(y[0]); o.y = f2bf(y[1]); o.z = f2bf(y[2]); o.w = f2bf(y[3]);
            *(ushort4*)op = o;
        } else {
            ushort2 o; o.x = f2bf(y[0]); o.y = f2bf(y[1]);
            *(ushort2*)op = o;
        }
    } else {
        float* op = (float*)out + (size_t)wid * HC + fbase;
        if constexpr (VPT == 4) *(float4*)op = make_float4(y[0], y[1], y[2], y[3]);
        else                    *(float2*)op = make_float2(y[0], y[1]);
        if (x16out) {                             // bf16 shadow copy for the final GEMM
            if constexpr (VPT == 4) {
                ushort4 o; o.x = f2bf(y[0]); o.y = f2bf(y[1]); o.z = f2bf(y[2]); o.w = f2bf(y[3]);
                *(ushort4*)&x16out[(size_t)wid * HC + fbase] = o;
            } else {
                ushort2 o; o.x = f2bf(y[0]); o.y = f2bf(y[1]);
                *(ushort2*)&x16out[(size_t)wid * HC + fbase] = o;
            }
        }
    }
}

// ---------------- pf = p2@pw3^T + pb3 (K=128), B staged in LDS; writes pf (f32) + pfb (bf16) ----
// LDS B layout: [128][128+8] u16; row stride 272B -> bank step 4 -> 2-way conflict (free).
__global__ void pf_kernel(const u16* __restrict__ p2, const u16* __restrict__ Bpw3,
                          const float* __restrict__ pb3, float* __restrict__ pf,
                          u16* __restrict__ pfb, int M) {
    using bfrag = __attribute__((ext_vector_type(8))) short;
    using ffrag = __attribute__((ext_vector_type(4))) float;
    __shared__ u16 bl[128][136];
    int tid = threadIdx.x;
    // coop-load B (32KB): 2048 16B chunks, 8 per thread, coalesced
    for (int i = tid; i < 2048; i += 256) {
        int r = i >> 4, c = (i & 15) * 8;
        *(uint4*)&bl[r][c] = *(const uint4*)(Bpw3 + (size_t)r * 128 + c);
    }
    __syncthreads();
    int wave = tid >> 6, lane = tid & 63;
    int lm = lane & 15, kg = (lane >> 4) * 8;
    int row = blockIdx.x * 64 + wave * 16 + lm;
    bfrag afs[4];
#pragma unroll
    for (int i = 0; i < 4; i++)
        afs[i] = *(const bfrag*)(p2 + (size_t)row * 128 + kg + i * 32);
    ffrag acc[8] = {};
#pragma unroll
    for (int k = 0; k < 4; k++)
#pragma unroll
        for (int t = 0; t < 8; t++) {
            bfrag bf = *(const bfrag*)&bl[t * 16 + lm][kg + k * 32];
            acc[t] = __builtin_amdgcn_mfma_f32_16x16x32_bf16(afs[k], bf, acc[t], 0, 0, 0);
        }
    int orow = blockIdx.x * 64 + wave * 16 + (lane >> 4) * 4;
#pragma unroll
    for (int t = 0; t < 8; t++) {
        int col = t * 16 + lm;
        float bi = pb3[col];
#pragma unroll
        for (int r = 0; r < 4; r++) {
            float v = acc[t][r] + bi;
            pf[(size_t)(orow + r) * 128 + col] = v;
            pfb[(size_t)(orow + r) * 128 + col] = f2bf(v);
        }
    }
}

// ---------------- out = [x3b|pfb]@fw^T + fb (K=256), B (fwc, 64KB) staged in LDS ----
// LDS B layout: [128][256+8] u16; row stride 528B -> bank step 4 -> 2-way conflict (free).
__global__ void out_kernel(const u16* __restrict__ x3b, const u16* __restrict__ pfb,
                           const u16* __restrict__ Bfw, const float* __restrict__ fb,
                           float* __restrict__ outp, int M) {
    using bfrag = __attribute__((ext_vector_type(8))) short;
    using ffrag = __attribute__((ext_vector_type(4))) float;
    __shared__ u16 bl[128][264];
    int tid = threadIdx.x;
    // coop-load B (64KB): 4096 16B chunks, 16 per thread, coalesced
    for (int i = tid; i < 4096; i += 256) {
        int r = i >> 5, c = (i & 31) * 8;
        *(uint4*)&bl[r][c] = *(const uint4*)(Bfw + (size_t)r * 256 + c);
    }
    __syncthreads();
    int wave = tid >> 6, lane = tid & 63;
    int lm = lane & 15, kg = (lane >> 4) * 8;
    int row = blockIdx.x * 64 + wave * 16 + lm;
    bfrag afs[8];
#pragma unroll
    for (int i = 0; i < 4; i++)
        afs[i] = *(const bfrag*)(x3b + (size_t)row * 128 + kg + i * 32);
#pragma unroll
    for (int i = 0; i < 4; i++)
        afs[4 + i] = *(const bfrag*)(pfb + (size_t)row * 128 + kg + i * 32);
    ffrag acc[8] = {};
#pragma unroll
    for (int k = 0; k < 8; k++)
#pragma unroll
        for (int t = 0; t < 8; t++) {
            bfrag bf = *(const bfrag*)&bl[t * 16 + lm][kg + k * 32];
            acc[t] = __builtin_amdgcn_mfma_f32_16x16x32_bf16(afs[k], bf, acc[t], 0, 0, 0);
        }
    int orow = blockIdx.x * 64 + wave * 16 + (lane >> 4) * 4;
#pragma unroll
    for (int t = 0; t < 8; t++) {
        int col = t * 16 + lm;
        float bi = fb[col];
#pragma unroll
        for (int r = 0; r < 4; r++)
            outp[(size_t)(orow + r) * 128 + col] = acc[t][r] + bi;
    }
}

extern "C" void kernel_launch(void* const* d_in, const int* in_sizes, int n_in,
                              void* d_out, int out_size, void* d_ws, size_t ws_size,
                              hipStream_t stream) {
    const float* x    = (const float*)d_in[0];
    const int*   ei   = (const int*)d_in[1];
    const float* pos  = (const float*)d_in[2];
    const float* W1   = (const float*)d_in[3];
    const float* as1  = (const float*)d_in[4];
    const float* ad1  = (const float*)d_in[5];
    const float* bg1  = (const float*)d_in[6];
    const float* ln1g = (const float*)d_in[7];
    const float* ln1b = (const float*)d_in[8];
    const float* W2   = (const float*)d_in[9];
    const float* as2  = (const float*)d_in[10];
    const float* ad2  = (const float*)d_in[11];
    const float* bg2  = (const float*)d_in[12];
    const float* ln2g = (const float*)d_in[13];
    const float* ln2b = (const float*)d_in[14];
    const float* W3   = (const float*)d_in[15];
    const float* as3  = (const float*)d_in[16];
    const float* ad3  = (const float*)d_in[17];
    const float* bg3  = (const float*)d_in[18];
    const float* pw1  = (const float*)d_in[19];
    const float* pb1  = (const float*)d_in[20];
    const float* bn1g = (const float*)d_in[21];
    const float* bn1b = (const float*)d_in[22];
    const float* pw2  = (const float*)d_in[23];
    const float* pb2  = (const float*)d_in[24];
    const float* bn2g = (const float*)d_in[25];
    const float* bn2b = (const float*)d_in[26];
    const float* pw3  = (const float*)d_in[27];
    const float* pb3  = (const float*)d_in[28];
    const float* fw   = (const float*)d_in[29];
    const float* fb   = (const float*)d_in[30];

    const int N = NNODES;
    float* out = (float*)d_out;                    // [N,128]
    float* x3  = out + (size_t)N * 128;            // [N,128]
    float* pf  = out + (size_t)2 * N * 128;        // [N,128]

    char* ws = (char*)d_ws;
    size_t off = 0;
    auto alloc = [&](size_t bytes) -> void* {
        void* p = ws + off;
        off += (bytes + 255) / 256 * 256;
        return p;
    };
    int*   cnt    = (int*)alloc((size_t)(N + 1 + NBUCK) * 4);  // degrees + spill count + bucket cursors
    u32*   bcnt   = (u32*)(cnt + N + 1);
    u32*   seg    = (u32*)alloc((size_t)NBUCK * SEGCAP * 4);   // bucketed packed (dst<<16|src)
    u16*   srcs16 = (u16*)alloc((size_t)N * ELLW * 2);
    int2*  ovbuf  = (int2*)alloc((size_t)NETOT * 8);
    float* esb    = (float*)alloc((size_t)N * 4 * 4);
    float* edb    = (float*)alloc((size_t)N * 4 * 4);
    u16*   w1c    = (u16*)alloc(16384 * 2);
    u16*   w2c    = (u16*)alloc(32768 * 2);
    u16*   w3c    = (u16*)alloc(16384 * 2);
    u16*   pw2c   = (u16*)alloc(8192 * 2);
    u16*   pw3c   = (u16*)alloc(16384 * 2);
    u16*   fwc    = (u16*)alloc(32768 * 2);
    u16*   hbufb  = (u16*)alloc((size_t)N * 128 * 2);   // layers 2,3 h tables
    u16*   xb     = (u16*)alloc((size_t)N * 256 * 2);
    u16*   p2b    = (u16*)alloc((size_t)N * 128 * 2);
    u16*   xc     = (u16*)alloc((size_t)N * 64 * 2);    // layer-1 bf16 x table
    float* vbuf   = (float*)alloc(512 * 4);             // v_s/v_d [8][64]
    u16*   aggb   = (u16*)alloc((size_t)N * 256 * 2);   // layer-1 aggregate (bf16)
    u16*   x3b    = (u16*)alloc((size_t)N * 128 * 2);   // bf16 shadow of x3
    u16*   pfb    = (u16*)alloc((size_t)N * 128 * 2);   // bf16 shadow of pf

    // ---- graph build phase A + weight cast + prep_v ----
    hipMemsetAsync(cnt, 0, (size_t)(N + 1 + NBUCK) * 4, stream);
    build_a_kernel<<<ABLOCKS + CBLOCKS + 1, 1024, 0, stream>>>(
        ei, bcnt, seg, W1, as1, ad1, vbuf,
        W1, w1c, 4096, W2, w2c, 8192, W3, w3c, 4096,
        pw2, pw2c, 2048, pw3, pw3c, 4096, fw, fwc, 8192);

    // ---- mid: build_b + esed1 + pn12 (independent, one launch) ----
    mid_kernel<<<NBUCK + 2 * GBLK, 256, 0, stream>>>(
        seg, bcnt, cnt, srcs16, ovbuf,
        x, vbuf, esb, edb, xc,
        pos, pw1, pb1, bn1g, bn1b, pw2c, p2b, pb2, bn2g, bn2b);

    const int NW = N / 4;   // one-wave-per-node kernels
    const int GB = GBLK;    // 625 GEMM row-blocks

    // ---- GAT layer 1 (aggregate-then-transform) ----
    gat_agg_kernel<<<NW, 256, 0, stream>>>(xc, esb, edb, cnt, srcs16, ovbuf, aggb, N);
    w1ln_kernel<<<GB, 256, 0, stream>>>(aggb, w1c, bg1, ln1g, ln1b, xb, N);

    // ---- GAT layer 2 ----
    gemm_scores_kernel<2, 64, false><<<dim3(GB, 1), 256, 0, stream>>>(
        xb, w2c, hbufb, as2, ad2, esb, edb, N, 128, 256);
    gat_fused_kernel<2, 64, true><<<NW, 256, 0, stream>>>(
        hbufb, esb, edb, cnt, srcs16, ovbuf, bg2, ln2g, ln2b, xb, nullptr, N);

    // ---- GAT layer 3 (out f32 -> x3, bf16 shadow -> x3b) ----
    gemm_scores_kernel<1, 128, false><<<dim3(GB, 1), 256, 0, stream>>>(
        xb, w3c, hbufb, as3, ad3, esb, edb, N, 128, 128);
    gat_fused_kernel<1, 128, false><<<NW, 256, 0, stream>>>(
        hbufb, esb, edb, cnt, srcs16, ovbuf, bg3, nullptr, nullptr, x3, x3b, N);

    // ---- final GEMMs, split + LDS-staged B ----
    pf_kernel<<<GB, 256, 0, stream>>>(p2b, pw3c, pb3, pf, pfb, N);
    out_kernel<<<GB, 256, 0, stream>>>(x3b, pfb, fwc, fb, out, N);
}

// Round 13
// 309.879 us; speedup vs baseline: 1.1921x; 1.0803x over previous
//
#include <hip/hip_runtime.h>
#include <cstddef>

#define NNODES 40000
#define NEDGES 640000
#define NETOT  (NNODES + NEDGES)
#define ELLW   96          // fixed edge slots per node; overflow -> spill list
#define NBUCK  313         // dst>>7 buckets (128 nodes each)
#define SEGCAP 8192        // pairs per bucket segment (expected ~2300, +129 sigma)
#define ABLOCKS 84         // ceil(NETOT / 8192) edge-bucketing blocks
#define CBLOCKS 30         // weight-cast blocks (30720 float4 groups / 1024)
#define ACB (ABLOCKS + CBLOCKS)
#define GBLK   625         // NNODES / 64 row-blocks

typedef unsigned short u16;
typedef unsigned int   u32;
using v2f = __attribute__((ext_vector_type(2))) float;

// ---------------- helpers ----------------
__device__ inline float wave_sum(float v) {
#pragma unroll
    for (int o = 32; o > 0; o >>= 1) v += __shfl_xor(v, o);
    return v;
}
__device__ inline u16 f2bf(float f) {   // round-to-nearest-even f32 -> bf16
    u32 u = __float_as_uint(f);
    return (u16)((u + 0x7fffu + ((u >> 16) & 1u)) >> 16);
}

// ---------------- build phase A: edge bucketing + weight cast + prep_v + prep_v3 + bcomb/cvec ----
// blocks: [0,ABLOCKS) bucket | [ABLOCKS,ACB) cast | ACB prep_v | ACB+1 prep_v3 |
//         [ACB+2, ACB+34) bcomb=[fw1@W3 | fw2] bf16 | ACB+34 cvec = fw1@bg3+fb
__global__ void build_a_kernel(const int* __restrict__ ei, u32* __restrict__ bcnt,
                               u32* __restrict__ seg,
                               const float* __restrict__ W1, const float* __restrict__ as1,
                               const float* __restrict__ ad1, float* __restrict__ vbuf,
                               const float* __restrict__ W3, const float* __restrict__ as3,
                               const float* __restrict__ ad3, float* __restrict__ v3buf,
                               const float* __restrict__ fwf, const float* __restrict__ bg3,
                               const float* __restrict__ fbf,
                               u16* __restrict__ bcomb, float* __restrict__ cvec,
                               const float* s0, u16* d0, int n0, const float* s1, u16* d1, int n1,
                               const float* s2, u16* d2, int n2, const float* s3, u16* d3, int n3,
                               const float* s4, u16* d4, int n4, const float* s5, u16* d5, int n5) {
    int tid = threadIdx.x;
    int blk = blockIdx.x;
    if (blk >= ABLOCKS) {
        if (blk < ACB) {                          // ---- weight cast (float4 groups) ----
            int i = (blk - ABLOCKS) * 1024 + tid;
            const float* s; u16* d;
            if      (i < n0) { s = s0; d = d0; }
            else if ((i -= n0) < n1) { s = s1; d = d1; }
            else if ((i -= n1) < n2) { s = s2; d = d2; }
            else if ((i -= n2) < n3) { s = s3; d = d3; }
            else if ((i -= n3) < n4) { s = s4; d = d4; }
            else if ((i -= n4) < n5) { s = s5; d = d5; }
            else return;
            float4 v = ((const float4*)s)[i];
            ushort4 o; o.x = f2bf(v.x); o.y = f2bf(v.y); o.z = f2bf(v.z); o.w = f2bf(v.w);
            ((ushort4*)d)[i] = o;
        } else if (blk == ACB) {                  // ---- prep_v: v_s[h]=W1_h^T a_s1[h] ----
            if (tid < 256) {
                int h = tid >> 6, k = tid & 63;
                float ss = 0.f, dd = 0.f;
                for (int c = 0; c < 64; c++) {
                    float w = W1[(h * 64 + c) * 64 + k];
                    ss += as1[h * 64 + c] * w;
                    dd += ad1[h * 64 + c] * w;
                }
                vbuf[tid] = ss;
                vbuf[256 + tid] = dd;
            }
        } else if (blk == ACB + 1) {              // ---- prep_v3: v3 = W3^T a_s3 ----
            if (tid < 128) {
                float ss = 0.f, dd = 0.f;
                for (int c = 0; c < 128; c++) {
                    float w = W3[c * 128 + tid];
                    ss += as3[c] * w;
                    dd += ad3[c] * w;
                }
                v3buf[tid] = ss;
                v3buf[128 + tid] = dd;
            }
        } else if (blk < ACB + 2 + 32) {          // ---- bcomb: [fw1@W3 | fw2] bf16 ----
            int e = (blk - (ACB + 2)) * 1024 + tid;   // 0..32767
            int o = e >> 8, d = e & 255;
            if (d < 128) {
                float s = 0.f;
                for (int k = 0; k < 128; k++) s += fwf[o * 256 + k] * W3[k * 128 + d];
                bcomb[o * 256 + d] = f2bf(s);
            } else {
                bcomb[o * 256 + d] = f2bf(fwf[o * 256 + d]);
            }
        } else {                                  // ---- cvec = fw1@bg3 + fb ----
            if (tid < 128) {
                float s = fbf[tid];
                for (int k = 0; k < 128; k++) s += fwf[tid * 256 + k] * bg3[k];
                cvec[tid] = s;
            }
        }
        return;
    }
    __shared__ u32 hist[NBUCK], hbase[NBUCK];
    for (int i = tid; i < NBUCK; i += 1024) hist[i] = 0;
    __syncthreads();
    u32 pk[8], loc[8]; int bj[8];
    int g0 = blk * 8192;
#pragma unroll
    for (int j = 0; j < 8; j++) {
        int g = g0 + j * 1024 + tid;
        bj[j] = -1;
        if (g < NETOT) {
            int src, dst;
            if (g < NEDGES) { src = ei[g]; dst = ei[NEDGES + g]; }
            else            { src = g - NEDGES; dst = src; }
            int b = dst >> 7;
            pk[j] = ((u32)dst << 16) | (u32)src;
            bj[j] = b;
            loc[j] = atomicAdd(&hist[b], 1u);
        }
    }
    __syncthreads();
    for (int i = tid; i < NBUCK; i += 1024) {
        u32 c = hist[i];
        hbase[i] = c ? atomicAdd(&bcnt[i], c) : 0u;
    }
    __syncthreads();
#pragma unroll
    for (int j = 0; j < 8; j++) {
        if (bj[j] >= 0) {
            u32 pos = hbase[bj[j]] + loc[j];
            if (pos < SEGCAP) seg[(size_t)bj[j] * SEGCAP + pos] = pk[j];
        }
    }
}

// ---------------- mid kernel: build_b (ELL fill) + esed1 (layer-1 scores/cast) + pn12 ----------------
__global__ void mid_kernel(const u32* __restrict__ seg, const u32* __restrict__ bcnt,
                           int* __restrict__ cnt, u16* __restrict__ srcs16,
                           int2* __restrict__ ovbuf,
                           const float* __restrict__ x, const float* __restrict__ vbuf,
                           float* __restrict__ es, float* __restrict__ ed, u16* __restrict__ xc,
                           const float* __restrict__ pos,
                           const float* __restrict__ pw1, const float* __restrict__ pb1,
                           const float* __restrict__ bn1g, const float* __restrict__ bn1b,
                           const u16* __restrict__ Bpn, u16* __restrict__ p2out,
                           const float* __restrict__ pb2,
                           const float* __restrict__ bn2g, const float* __restrict__ bn2b) {
    __shared__ u32 lcnt[128];
    __shared__ float vl[512];
    int tid = threadIdx.x;
    int blk = blockIdx.x;

    if (blk < NBUCK) {                            // ---- build_b: per-bucket ELL fill ----
        int base = blk << 7;
        if (tid < 128) lcnt[tid] = 0;
        __syncthreads();
        u32 m = bcnt[blk]; if (m > SEGCAP) m = SEGCAP;
        const u32* sp = seg + (size_t)blk * SEGCAP;
        for (u32 e = tid; e < m; e += 256) {
            u32 pkv = sp[e];
            u32 dst = pkv >> 16, src = pkv & 0xffffu;
            u32 p = atomicAdd(&lcnt[dst - (u32)base], 1u);
            if (p < ELLW) srcs16[dst * ELLW + p] = (u16)src;
            else {
                int q = atomicAdd(&cnt[NNODES], 1);   // rare spill
                ovbuf[q] = make_int2((int)dst, (int)src);
            }
        }
        __syncthreads();
        if (tid < 128 && base + tid < NNODES) cnt[base + tid] = (int)lcnt[tid];
        return;
    }
    blk -= NBUCK;
    if (blk < GBLK) {                             // ---- esed1: es/ed = x.v + cast x->bf16 ----
        vl[tid] = vbuf[tid];
        vl[tid + 256] = vbuf[tid + 256];
        __syncthreads();
        int lane = tid & 63, wave = tid >> 6;
        int i = lane >> 2, q = lane & 3;
        int node = blk * 64 + wave * 16 + i;
        const float* xp = x + (size_t)node * 64 + q * 16;
        float xr[16];
        *(float4*)&xr[0]  = ((const float4*)xp)[0];
        *(float4*)&xr[4]  = ((const float4*)xp)[1];
        *(float4*)&xr[8]  = ((const float4*)xp)[2];
        *(float4*)&xr[12] = ((const float4*)xp)[3];
        float p[8];
#pragma unroll
        for (int h = 0; h < 8; h++) {
            float s = 0.f;
#pragma unroll
            for (int j = 0; j < 16; j++) s += xr[j] * vl[h * 64 + q * 16 + j];
            p[h] = s;
        }
#pragma unroll
        for (int h = 0; h < 8; h++) {
            p[h] += __shfl_xor(p[h], 1);
            p[h] += __shfl_xor(p[h], 2);
        }
        es[node * 4 + q] = p[q];
        ed[node * 4 + q] = p[4 + q];
        u16* cp = xc + (size_t)node * 64 + q * 16;
#pragma unroll
        for (int j = 0; j < 16; j += 4) {
            ushort4 o; o.x = f2bf(xr[j]); o.y = f2bf(xr[j + 1]);
            o.z = f2bf(xr[j + 2]); o.w = f2bf(xr[j + 3]);
            *(ushort4*)(cp + j) = o;
        }
        return;
    }
    blk -= GBLK;                                  // ---- pn12 ----
    {
        const int Nn = 128, K = 64;
        using bfrag = __attribute__((ext_vector_type(8))) short;
        using ffrag = __attribute__((ext_vector_type(4))) float;
        int wave = tid >> 6, lane = tid & 63;
        int lm = lane & 15, kg = (lane >> 4) * 8;
        int rowblk = blk * 64 + wave * 16;
        int row = rowblk + lm;
        float p0 = pos[row * 3 + 0], p1 = pos[row * 3 + 1], p2 = pos[row * 3 + 2];
        const u16* Bp = Bpn + (size_t)lm * K + kg;
        const float bnscale = rsqrtf(1.0f + 1e-5f);
        ffrag acc[8] = {};
#pragma unroll
        for (int k0 = 0; k0 < K; k0 += 32) {
            bfrag af;
#pragma unroll
            for (int j = 0; j < 8; j++) {
                int k = kg + k0 + j;
                float v = p0 * pw1[k * 3 + 0] + p1 * pw1[k * 3 + 1] + p2 * pw1[k * 3 + 2] + pb1[k];
                v = v * (bn1g[k] * bnscale) + bn1b[k];
                v = v > 0.f ? v : 0.f;
                af[j] = (short)f2bf(v);
            }
#pragma unroll
            for (int t = 0; t < 8; t++) {
                bfrag bf = *(const bfrag*)(Bp + (size_t)t * 16 * K + k0);
                acc[t] = __builtin_amdgcn_mfma_f32_16x16x32_bf16(af, bf, acc[t], 0, 0, 0);
            }
        }
        int orow = rowblk + (lane >> 4) * 4;
#pragma unroll
        for (int t = 0; t < 8; t++) {
            int col = t * 16 + lm;
            float bi = pb2[col], g = bn2g[col] * bnscale, bb = bn2b[col];
#pragma unroll
            for (int r = 0; r < 4; r++) {
                float v = (acc[t][r] + bi) * g + bb;
                v = v > 0.f ? v : 0.f;
                p2out[(size_t)(orow + r) * Nn + col] = f2bf(v);
            }
        }
    }
}

// ---------------- layer-1 aggregation over x (64-dim rows, 128B) ----------------
__global__ void gat_agg_kernel(const u16* __restrict__ xc,
                               const float* __restrict__ es, const float* __restrict__ ed,
                               const int* __restrict__ cnt, const u16* __restrict__ srcs16,
                               const int2* __restrict__ ovbuf,
                               u16* __restrict__ agg, int n) {
    __shared__ float wbuf[4][4][100];
    __shared__ u32   sbuf[4][ELLW];
    int wave = threadIdx.x >> 6;
    int wid = (blockIdx.x * blockDim.x + threadIdx.x) >> 6;
    int lane = threadIdx.x & 63;
    if (wid >= n) return;

    int degt = cnt[wid];
    int mainc = degt < ELLW ? degt : ELLW;
    int padt = (mainc + 7) & ~7;
    const u16* sp = srcs16 + (size_t)wid * ELLW;

    const int h = lane & 3;
    const int esub = lane >> 2;
    float edh = ed[(size_t)wid * 4 + h];

    // ---- phase 1 ----
    float den = 0.f;
    for (int i0 = 0; i0 < padt; i0 += 16) {
        int e = i0 + esub;
        if (e < padt) {
            float w = 0.f; u32 off = 0;
            if (e < mainc) {
                int s = sp[e];
                off = (u32)s << 7;
                float v = es[(size_t)s * 4 + h] + edh;
                v = v > 0.f ? v : 0.2f * v;
                w = __expf(v);
            }
            wbuf[wave][h][e] = w;
            if (h == 0) sbuf[wave][e] = off;
            den += w;
        }
    }
    int ovn = 0;
    if (degt > ELLW) {
        ovn = cnt[n];
        for (int j = esub; j < ovn; j += 16) {
            int2 t = ovbuf[j];
            if (t.x == wid) {
                float v = es[(size_t)t.y * 4 + h] + edh;
                v = v > 0.f ? v : 0.2f * v;
                den += __expf(v);
            }
        }
    }
#pragma unroll
    for (int o = 4; o < 64; o <<= 1) den += __shfl_xor(den, o);
    float inv = 1.f / (den + 1e-16f);

    // ---- phase 2: gather 128B rows, accumulate all 4 heads ----
    const int e2 = lane >> 5, f16 = lane & 31;
    const char* hp = (const char*)xc + f16 * 4;
    v2f a0 = {0.f, 0.f}, a1 = {0.f, 0.f}, a2 = {0.f, 0.f}, a3 = {0.f, 0.f};
    for (int eb = 0; eb < padt; eb += 8) {
        u32 of[4]; u32 g[4];
        float w0[4], w1[4], w2[4], w3[4];
#pragma unroll
        for (int k = 0; k < 4; k++) of[k] = sbuf[wave][eb + 2 * k + e2];
#pragma unroll
        for (int k = 0; k < 4; k++) g[k] = *(const u32*)(hp + of[k]);
#pragma unroll
        for (int k = 0; k < 4; k++) {
            int e = eb + 2 * k + e2;
            w0[k] = wbuf[wave][0][e]; w1[k] = wbuf[wave][1][e];
            w2[k] = wbuf[wave][2][e]; w3[k] = wbuf[wave][3][e];
        }
#pragma unroll
        for (int k = 0; k < 4; k++) {
            v2f hx;
            hx.x = __uint_as_float(g[k] << 16);
            hx.y = __uint_as_float(g[k] & 0xffff0000u);
            a0 += v2f{w0[k], w0[k]} * hx;
            a1 += v2f{w1[k], w1[k]} * hx;
            a2 += v2f{w2[k], w2[k]} * hx;
            a3 += v2f{w3[k], w3[k]} * hx;
        }
    }
    if (degt > ELLW) {
        for (int j = 0; j < ovn; j++) {
            int2 t = ovbuf[j];
            if (t.x != wid) continue;
            float wh[4];
#pragma unroll
            for (int hh = 0; hh < 4; hh++) {
                float v = es[(size_t)t.y * 4 + hh] + __shfl(edh, hh);
                v = v > 0.f ? v : 0.2f * v;
                wh[hh] = __expf(v);
            }
            if (lane < 32) {
                u32 g = *(const u32*)(hp + ((u32)t.y << 7));
                v2f hx;
                hx.x = __uint_as_float(g << 16);
                hx.y = __uint_as_float(g & 0xffff0000u);
                a0 += v2f{wh[0], wh[0]} * hx;
                a1 += v2f{wh[1], wh[1]} * hx;
                a2 += v2f{wh[2], wh[2]} * hx;
                a3 += v2f{wh[3], wh[3]} * hx;
            }
        }
    }
    a0.x += __shfl_xor(a0.x, 32); a0.y += __shfl_xor(a0.y, 32);
    a1.x += __shfl_xor(a1.x, 32); a1.y += __shfl_xor(a1.y, 32);
    a2.x += __shfl_xor(a2.x, 32); a2.y += __shfl_xor(a2.y, 32);
    a3.x += __shfl_xor(a3.x, 32); a3.y += __shfl_xor(a3.y, 32);
    float iv[4];
#pragma unroll
    for (int hh = 0; hh < 4; hh++) iv[hh] = __shfl(inv, hh);
    if (lane < 32) {
        u32* op = (u32*)agg + (size_t)wid * 128 + f16;
        op[0]  = ((u32)f2bf(a0.y * iv[0]) << 16) | f2bf(a0.x * iv[0]);
        op[32] = ((u32)f2bf(a1.y * iv[1]) << 16) | f2bf(a1.x * iv[1]);
        op[64] = ((u32)f2bf(a2.y * iv[2]) << 16) | f2bf(a2.x * iv[2]);
        op[96] = ((u32)f2bf(a3.y * iv[3]) << 16) | f2bf(a3.x * iv[3]);
    }
}

// ---------------- layer-1 post-GEMM (block-diagonal per head) + bias + LN + ReLU -> xb bf16 ----------------
__global__ __launch_bounds__(256, 2) void w1ln_kernel(
                            const u16* __restrict__ agg, const u16* __restrict__ B,
                            const float* __restrict__ bias,
                            const float* __restrict__ lng, const float* __restrict__ lnb,
                            u16* __restrict__ xb, int M) {
    using bfrag = __attribute__((ext_vector_type(8))) short;
    using ffrag = __attribute__((ext_vector_type(4))) float;
    int wave = threadIdx.x >> 6, lane = threadIdx.x & 63;
    int lm = lane & 15, kg = (lane >> 4) * 8;
    int rowblk = blockIdx.x * 64 + wave * 16;
    ffrag acc[16] = {};
#pragma unroll
    for (int hh = 0; hh < 4; hh++) {
#pragma unroll
        for (int k0 = 0; k0 < 64; k0 += 32) {
            bfrag af = *(const bfrag*)(agg + (size_t)(rowblk + lm) * 256 + hh * 64 + kg + k0);
            bfrag bfs[4];
#pragma unroll
            for (int tt = 0; tt < 4; tt++)
                bfs[tt] = *(const bfrag*)(B + (size_t)(hh * 64 + tt * 16 + lm) * 64 + kg + k0);
#pragma unroll
            for (int tt = 0; tt < 4; tt++) {
                int t = hh * 4 + tt;
                acc[t] = __builtin_amdgcn_mfma_f32_16x16x32_bf16(af, bfs[tt], acc[t], 0, 0, 0);
            }
        }
    }
    int orow = rowblk + (lane >> 4) * 4;
    float bi[16], gg[16], bb[16];
#pragma unroll
    for (int t = 0; t < 16; t++) {
        int col = t * 16 + lm;
        bi[t] = bias[col]; gg[t] = lng[col]; bb[t] = lnb[col];
    }
#pragma unroll
    for (int r = 0; r < 4; r++) {
        float pv[16];
        float s1 = 0.f, s2 = 0.f;
#pragma unroll
        for (int t = 0; t < 16; t++) {
            float v = acc[t][r] + bi[t];
            pv[t] = v; s1 += v; s2 += v * v;
        }
#pragma unroll
        for (int o = 1; o < 16; o <<= 1) { s1 += __shfl_xor(s1, o); s2 += __shfl_xor(s2, o); }
        float mu = s1 / 256.f;
        float var = s2 / 256.f - mu * mu;
        float rstd = rsqrtf(var + 1e-5f);
#pragma unroll
        for (int t = 0; t < 16; t++) {
            float v = (pv[t] - mu) * rstd * gg[t] + bb[t];
            v = v > 0.f ? v : 0.f;
            xb[(size_t)(orow + r) * 256 + t * 16 + lm] = f2bf(v);
        }
    }
}

// ---------------- merged: gs2 (layer-2 GEMM + scores, K=256) || pf = p2@pw3^T + pb3 ----------------
// blocks [0,GBLK): gs2; [GBLK,2*GBLK): pf (LDS-staged B). Independent work overlapped.
__global__ __launch_bounds__(256, 2) void gs2pf_kernel(
        const u16* __restrict__ xb, const u16* __restrict__ B2, u16* __restrict__ Cout,
        const float* __restrict__ as2, const float* __restrict__ ad2,
        float* __restrict__ es, float* __restrict__ ed,
        const u16* __restrict__ p2, const u16* __restrict__ Bpw3,
        const float* __restrict__ pb3, float* __restrict__ pf, u16* __restrict__ pfb, int M) {
    using bfrag = __attribute__((ext_vector_type(8))) short;
    using ffrag = __attribute__((ext_vector_type(4))) float;
    __shared__ u16 bl[128][136];
    int tid = threadIdx.x;
    int blk = blockIdx.x;
    int wave = tid >> 6, lane = tid & 63;
    int lm = lane & 15, kg = (lane >> 4) * 8;
    if (blk < GBLK) {
        // ---- gs2: h2 = xb@W2^T, H=2, C=64, K=256, plus attention scores ----
        int rowblk = blk * 64 + wave * 16;
        const u16* Bp = B2 + (size_t)lm * 256 + kg;
        ffrag acc[8] = {};
        for (int k0 = 0; k0 < 256; k0 += 32) {
            bfrag af = *(const bfrag*)(xb + (size_t)(rowblk + lm) * 256 + kg + k0);
            bfrag bfs[8];
#pragma unroll
            for (int t = 0; t < 8; t++)
                bfs[t] = *(const bfrag*)(Bp + (size_t)t * 16 * 256 + k0);
#pragma unroll
            for (int t = 0; t < 8; t++)
                acc[t] = __builtin_amdgcn_mfma_f32_16x16x32_bf16(af, bfs[t], acc[t], 0, 0, 0);
        }
        int orow = rowblk + (lane >> 4) * 4;
        float asv[8], adv[8];
#pragma unroll
        for (int t = 0; t < 8; t++) {
            int fcol = t * 16 + lm;
            asv[t] = as2[fcol]; adv[t] = ad2[fcol];
        }
        float ps[4][2] = {}, pd[4][2] = {};
#pragma unroll
        for (int t = 0; t < 8; t++) {
            const int hh = t >> 2;
#pragma unroll
            for (int r = 0; r < 4; r++) {
                float v = acc[t][r];
                ps[r][hh] += v * asv[t];
                pd[r][hh] += v * adv[t];
                Cout[(size_t)(orow + r) * 128 + t * 16 + lm] = f2bf(v);
            }
        }
#pragma unroll
        for (int r = 0; r < 4; r++)
#pragma unroll
            for (int hh = 0; hh < 2; hh++) {
                float s = ps[r][hh], d = pd[r][hh];
#pragma unroll
                for (int o = 1; o < 16; o <<= 1) { s += __shfl_xor(s, o); d += __shfl_xor(d, o); }
                if (lm == 0) {
                    es[(size_t)(orow + r) * 2 + hh] = s;
                    ed[(size_t)(orow + r) * 2 + hh] = d;
                }
            }
    } else {
        blk -= GBLK;
        // ---- pf = p2@pw3^T + pb3 (K=128), LDS-staged B; writes pf (f32) + pfb (bf16) ----
        for (int i = tid; i < 2048; i += 256) {
            int r = i >> 4, c = (i & 15) * 8;
            *(uint4*)&bl[r][c] = *(const uint4*)(Bpw3 + (size_t)r * 128 + c);
        }
        __syncthreads();
        int row = blk * 64 + wave * 16 + lm;
        bfrag afs[4];
#pragma unroll
        for (int i = 0; i < 4; i++)
            afs[i] = *(const bfrag*)(p2 + (size_t)row * 128 + kg + i * 32);
        ffrag acc[8] = {};
#pragma unroll
        for (int k = 0; k < 4; k++)
#pragma unroll
            for (int t = 0; t < 8; t++) {
                bfrag bf = *(const bfrag*)&bl[t * 16 + lm][kg + k * 32];
                acc[t] = __builtin_amdgcn_mfma_f32_16x16x32_bf16(afs[k], bf, acc[t], 0, 0, 0);
            }
        int orow = blk * 64 + wave * 16 + (lane >> 4) * 4;
#pragma unroll
        for (int t = 0; t < 8; t++) {
            int col = t * 16 + lm;
            float bi = pb3[col];
#pragma unroll
            for (int r = 0; r < 4; r++) {
                float v = acc[t][r] + bi;
                pf[(size_t)(orow + r) * 128 + col] = v;
                pfb[(size_t)(orow + r) * 128 + col] = f2bf(v);
            }
        }
    }
}

// ---------------- fused GAT softmax + aggregation (layers 2,3) ----------------
// v3/v3d non-null (layer 2): also emits layer-3 scores es3o/ed3o = xbrow . v3 from registers.
// out null (layer-3 agg role): skip f32 store, bias treated as zero; x16out gets bf16 sums.
template <int H, int C, bool LNRELU>
__global__ void gat_fused_kernel(const u16* __restrict__ hmat,
                                 const float* __restrict__ es, const float* __restrict__ ed,
                                 const int* __restrict__ cnt, const u16* __restrict__ srcs16,
                                 const int2* __restrict__ ovbuf,
                                 const float* __restrict__ bias,
                                 const float* __restrict__ lng, const float* __restrict__ lnb,
                                 void* __restrict__ out, u16* __restrict__ x16out,
                                 const float* __restrict__ v3, const float* __restrict__ v3d,
                                 float* __restrict__ es3o, float* __restrict__ ed3o, int n) {
    constexpr int HC = H * C;
    constexpr int VPT = HC / 64;
    constexpr int SH = (HC == 256) ? 9 : 8;      // byte-offset shift for rows
    constexpr int EPW = 64 / H;                  // edges per phase-1 pass
    constexpr int HSH = (H == 4) ? 2 : ((H == 2) ? 1 : 0);
    __shared__ float wbuf[4][H][100];
    __shared__ int   sbuf[4][ELLW];
    int wave = threadIdx.x >> 6;
    int wid = (blockIdx.x * blockDim.x + threadIdx.x) >> 6;
    int lane = threadIdx.x & 63;
    if (wid >= n) return;

    int degt = cnt[wid];
    int mainc = degt < ELLW ? degt : ELLW;
    int pad = (mainc + 7) & ~7;
    const u16* sp = srcs16 + (size_t)wid * ELLW;

    const int h = lane & (H - 1);
    const int esub = lane >> HSH;
    float edh = ed[(size_t)wid * H + h];

    // ---- phase 1 ----
    float den = 0.f;
    for (int i0 = 0; i0 < pad; i0 += EPW) {
        int e = i0 + esub;
        if (e < pad) {
            float w = 0.f;
            int soff = 0;
            if (e < mainc) {
                int s = sp[e];
                soff = s << SH;
                float v = es[(size_t)s * H + h] + edh;
                v = v > 0.f ? v : 0.2f * v;
                w = __expf(v);
            }
            wbuf[wave][h][e] = w;
            if (h == 0) sbuf[wave][e] = soff;
            den += w;
        }
    }
    int ovn = 0;
    if (degt > ELLW) {
        ovn = cnt[n];
        for (int j = esub; j < ovn; j += EPW) {
            int2 t = ovbuf[j];
            if (t.x == wid) {
                float v = es[(size_t)t.y * H + h] + edh;
                v = v > 0.f ? v : 0.2f * v;
                den += __expf(v);
            }
        }
    }
#pragma unroll
    for (int o = H; o < 64; o <<= 1) den += __shfl_xor(den, o);
    float inv = 1.f / (den + 1e-16f);

    // ---- phase 2: 8-deep batches ----
    const int myhead = (lane * VPT) / C;
    const float invh = __shfl(inv, myhead);
    const int loff = lane * (VPT * 2);
    v2f a01 = {0.f, 0.f}, a23 = {0.f, 0.f};

    for (int e = 0; e < pad; e += 8) {
        int4   o0 = *(const int4*)&sbuf[wave][e];
        int4   o1 = *(const int4*)&sbuf[wave][e + 4];
        float4 w0 = *(const float4*)&wbuf[wave][myhead][e];
        float4 w1 = *(const float4*)&wbuf[wave][myhead][e + 4];
        int   oo[8] = {o0.x, o0.y, o0.z, o0.w, o1.x, o1.y, o1.z, o1.w};
        float ww[8] = {w0.x, w0.y, w0.z, w0.w, w1.x, w1.y, w1.z, w1.w};
        if constexpr (VPT == 4) {
            uint2 gg[8];
#pragma unroll
            for (int u = 0; u < 8; u++)
                gg[u] = *(const uint2*)((const char*)hmat + (size_t)(u32)oo[u] + loff);
#pragma unroll
            for (int u = 0; u < 8; u++) {
                v2f wv = {ww[u], ww[u]};
                v2f h01, h23;
                h01.x = __uint_as_float(gg[u].x << 16);
                h01.y = __uint_as_float(gg[u].x & 0xffff0000u);
                h23.x = __uint_as_float(gg[u].y << 16);
                h23.y = __uint_as_float(gg[u].y & 0xffff0000u);
                a01 += wv * h01;
                a23 += wv * h23;
            }
        } else {
            u32 gg[8];
#pragma unroll
            for (int u = 0; u < 8; u++)
                gg[u] = *(const u32*)((const char*)hmat + (size_t)(u32)oo[u] + loff);
#pragma unroll
            for (int u = 0; u < 8; u++) {
                v2f wv = {ww[u], ww[u]};
                v2f h01;
                h01.x = __uint_as_float(gg[u] << 16);
                h01.y = __uint_as_float(gg[u] & 0xffff0000u);
                a01 += wv * h01;
            }
        }
    }
    if (degt > ELLW) {
        const float edm = __shfl(edh, myhead);
        for (int j = 0; j < ovn; j++) {
            int2 t = ovbuf[j];
            if (t.x != wid) continue;
            float v = es[(size_t)t.y * H + myhead] + edm;
            v = v > 0.f ? v : 0.2f * v;
            float w = __expf(v);
            v2f wv = {w, w};
            if constexpr (VPT == 4) {
                uint2 g = *(const uint2*)((const char*)hmat + ((size_t)t.y << SH) + loff);
                v2f h01, h23;
                h01.x = __uint_as_float(g.x << 16);
                h01.y = __uint_as_float(g.x & 0xffff0000u);
                h23.x = __uint_as_float(g.y << 16);
                h23.y = __uint_as_float(g.y & 0xffff0000u);
                a01 += wv * h01;
                a23 += wv * h23;
            } else {
                u32 g = *(const u32*)((const char*)hmat + ((size_t)t.y << SH) + loff);
                v2f h01;
                h01.x = __uint_as_float(g << 16);
                h01.y = __uint_as_float(g & 0xffff0000u);
                a01 += wv * h01;
            }
        }
    }
    {
        v2f iv = {invh, invh};
        a01 *= iv;
        a23 *= iv;
    }

    int fbase = lane * VPT;
    float y[VPT];
    y[0] = a01.x;
    y[1] = a01.y;
    if constexpr (VPT == 4) { y[2] = a23.x; y[3] = a23.y; }
    if (bias) {
#pragma unroll
        for (int j = 0; j < VPT; j++) y[j] += bias[fbase + j];
    }

    if constexpr (LNRELU) {
        float s1 = 0.f, s2 = 0.f;
#pragma unroll
        for (int j = 0; j < VPT; j++) { s1 += y[j]; s2 += y[j] * y[j]; }
        s1 = wave_sum(s1);
        s2 = wave_sum(s2);
        float mu = s1 / (float)HC;
        float var = s2 / (float)HC - mu * mu;
        float rstd = rsqrtf(var + 1e-5f);
#pragma unroll
        for (int j = 0; j < VPT; j++) {
            float v = (y[j] - mu) * rstd * lng[fbase + j] + lnb[fbase + j];
            y[j] = v > 0.f ? v : 0.f;
        }
        if (v3) {   // layer-3 scores from this node's xb row (prep_v trick)
            float s3 = 0.f, d3 = 0.f;
#pragma unroll
            for (int j = 0; j < VPT; j++) {
                s3 += y[j] * v3[fbase + j];
                d3 += y[j] * v3d[fbase + j];
            }
            s3 = wave_sum(s3);
            d3 = wave_sum(d3);
            if (lane == 0) { es3o[wid] = s3; ed3o[wid] = d3; }
        }
        u16* op = (u16*)out + (size_t)wid * HC + fbase;
        if constexpr (VPT == 4) {
            ushort4 o; o.x = f2bf(y[0]); o.y = f2bf(y[1]); o.z = f2bf(y[2]); o.w = f2bf(y[3]);
            *(ushort4*)op = o;
        } else {
            ushort2 o; o.x = f2bf(y[0]); o.y = f2bf(y[1]);
            *(ushort2*)op = o;
        }
    } else {
        if (out) {
            float* op = (float*)out + (size_t)wid * HC + fbase;
            if constexpr (VPT == 4) *(float4*)op = make_float4(y[0], y[1], y[2], y[3]);
            else                    *(float2*)op = make_float2(y[0], y[1]);
        }
        if (x16out) {
            if constexpr (VPT == 4) {
                ushort4 o; o.x = f2bf(y[0]); o.y = f2bf(y[1]); o.z = f2bf(y[2]); o.w = f2bf(y[3]);
                *(ushort4*)&x16out[(size_t)wid * HC + fbase] = o;
            } else {
                ushort2 o; o.x = f2bf(y[0]); o.y = f2bf(y[1]);
                *(ushort2*)&x16out[(size_t)wid * HC + fbase] = o;
            }
        }
    }
}

// ---------------- merged final: x3 = agg3@W3^T + bg3  ||  out = [agg3|pfb]@bcomb^T + cvec ----
// blocks [0,GBLK): x3 role (K=128); [GBLK,2*GBLK): out role (K=256). Both LDS-stage B.
__global__ void w3out_kernel(const u16* __restrict__ agg3b, const u16* __restrict__ w3c,
                             const float* __restrict__ bg3, float* __restrict__ x3,
                             const u16* __restrict__ pfb, const u16* __restrict__ bcomb,
                             const float* __restrict__ cvec, float* __restrict__ outp, int M) {
    using bfrag = __attribute__((ext_vector_type(8))) short;
    using ffrag = __attribute__((ext_vector_type(4))) float;
    __shared__ u16 bl[128][264];
    int tid = threadIdx.x;
    int blk = blockIdx.x;
    int wave = tid >> 6, lane = tid & 63;
    int lm = lane & 15, kg = (lane >> 4) * 8;
    if (blk < GBLK) {
        // ---- x3 = agg3@W3^T + bg3 (K=128), f32 output only ----
        for (int i = tid; i < 2048; i += 256) {
            int r = i >> 4, c = (i & 15) * 8;
            *(uint4*)&bl[r][c] = *(const uint4*)(w3c + (size_t)r * 128 + c);
        }
        __syncthreads();
        int row = blk * 64 + wave * 16 + lm;
        bfrag afs[4];
#pragma unroll
        for (int i = 0; i < 4; i++)
            afs[i] = *(const bfrag*)(agg3b + (size_t)row * 128 + kg + i * 32);
        ffrag acc[8] = {};
#pragma unroll
        for (int k = 0; k < 4; k++)
#pragma unroll
            for (int t = 0; t < 8; t++) {
                bfrag bf = *(const bfrag*)&bl[t * 16 + lm][kg + k * 32];
                acc[t] = __builtin_amdgcn_mfma_f32_16x16x32_bf16(afs[k], bf, acc[t], 0, 0, 0);
            }
        int orow = blk * 64 + wave * 16 + (lane >> 4) * 4;
#pragma unroll
        for (int t = 0; t < 8; t++) {
            int col = t * 16 + lm;
            float bi = bg3[col];
#pragma unroll
            for (int r = 0; r < 4; r++)
                x3[(size_t)(orow + r) * 128 + col] = acc[t][r] + bi;
        }
    } else {
        blk -= GBLK;
        // ---- out = [agg3|pfb]@bcomb^T + cvec (K=256) ----
        for (int i = tid; i < 4096; i += 256) {
            int r = i >> 5, c = (i & 31) * 8;
            *(uint4*)&bl[r][c] = *(const uint4*)(bcomb + (size_t)r * 256 + c);
        }
        __syncthreads();
        int row = blk * 64 + wave * 16 + lm;
        bfrag afs[8];
#pragma unroll
        for (int i = 0; i < 4; i++)
            afs[i] = *(const bfrag*)(agg3b + (size_t)row * 128 + kg + i * 32);
#pragma unroll
        for (int i = 0; i < 4; i++)
            afs[4 + i] = *(const bfrag*)(pfb + (size_t)row * 128 + kg + i * 32);
        ffrag acc[8] = {};
#pragma unroll
        for (int k = 0; k < 8; k++)
#pragma unroll
            for (int t = 0; t < 8; t++) {
                bfrag bf = *(const bfrag*)&bl[t * 16 + lm][kg + k * 32];
                acc[t] = __builtin_amdgcn_mfma_f32_16x16x32_bf16(afs[k], bf, acc[t], 0, 0, 0);
            }
        int orow = blk * 64 + wave * 16 + (lane >> 4) * 4;
#pragma unroll
        for (int t = 0; t < 8; t++) {
            int col = t * 16 + lm;
            float bi = cvec[col];
#pragma unroll
            for (int r = 0; r < 4; r++)
                outp[(size_t)(orow + r) * 128 + col] = acc[t][r] + bi;
        }
    }
}

extern "C" void kernel_launch(void* const* d_in, const int* in_sizes, int n_in,
                              void* d_out, int out_size, void* d_ws, size_t ws_size,
                              hipStream_t stream) {
    const float* x    = (const float*)d_in[0];
    const int*   ei   = (const int*)d_in[1];
    const float* pos  = (const float*)d_in[2];
    const float* W1   = (const float*)d_in[3];
    const float* as1  = (const float*)d_in[4];
    const float* ad1  = (const float*)d_in[5];
    const float* bg1  = (const float*)d_in[6];
    const float* ln1g = (const float*)d_in[7];
    const float* ln1b = (const float*)d_in[8];
    const float* W2   = (const float*)d_in[9];
    const float* as2  = (const float*)d_in[10];
    const float* ad2  = (const float*)d_in[11];
    const float* bg2  = (const float*)d_in[12];
    const float* ln2g = (const float*)d_in[13];
    const float* ln2b = (const float*)d_in[14];
    const float* W3   = (const float*)d_in[15];
    const float* as3  = (const float*)d_in[16];
    const float* ad3  = (const float*)d_in[17];
    const float* bg3  = (const float*)d_in[18];
    const float* pw1  = (const float*)d_in[19];
    const float* pb1  = (const float*)d_in[20];
    const float* bn1g = (const float*)d_in[21];
    const float* bn1b = (const float*)d_in[22];
    const float* pw2  = (const float*)d_in[23];
    const float* pb2  = (const float*)d_in[24];
    const float* bn2g = (const float*)d_in[25];
    const float* bn2b = (const float*)d_in[26];
    const float* pw3  = (const float*)d_in[27];
    const float* pb3  = (const float*)d_in[28];
    const float* fw   = (const float*)d_in[29];
    const float* fb   = (const float*)d_in[30];

    const int N = NNODES;
    float* out = (float*)d_out;                    // [N,128]
    float* x3  = out + (size_t)N * 128;            // [N,128]
    float* pf  = out + (size_t)2 * N * 128;        // [N,128]

    char* ws = (char*)d_ws;
    size_t off = 0;
    auto alloc = [&](size_t bytes) -> void* {
        void* p = ws + off;
        off += (bytes + 255) / 256 * 256;
        return p;
    };
    int*   cnt    = (int*)alloc((size_t)(N + 1 + NBUCK) * 4);  // degrees + spill count + bucket cursors
    u32*   bcnt   = (u32*)(cnt + N + 1);
    u32*   seg    = (u32*)alloc((size_t)NBUCK * SEGCAP * 4);   // bucketed packed (dst<<16|src)
    u16*   srcs16 = (u16*)alloc((size_t)N * ELLW * 2);
    int2*  ovbuf  = (int2*)alloc((size_t)NETOT * 8);
    float* esb    = (float*)alloc((size_t)N * 4 * 4);
    float* edb    = (float*)alloc((size_t)N * 4 * 4);
    float* es3b   = (float*)alloc((size_t)N * 4);
    float* ed3b   = (float*)alloc((size_t)N * 4);
    u16*   w1c    = (u16*)alloc(16384 * 2);
    u16*   w2c    = (u16*)alloc(32768 * 2);
    u16*   w3c    = (u16*)alloc(16384 * 2);
    u16*   pw2c   = (u16*)alloc(8192 * 2);
    u16*   pw3c   = (u16*)alloc(16384 * 2);
    u16*   fwc    = (u16*)alloc(32768 * 2);
    u16*   bcomb  = (u16*)alloc(32768 * 2);             // [fw1@W3 | fw2] bf16
    float* cvec   = (float*)alloc(128 * 4);             // fw1@bg3 + fb
    u16*   hbufb  = (u16*)alloc((size_t)N * 128 * 2);   // layer-2 h table
    u16*   xb     = (u16*)alloc((size_t)N * 256 * 2);
    u16*   p2b    = (u16*)alloc((size_t)N * 128 * 2);
    u16*   xc     = (u16*)alloc((size_t)N * 64 * 2);    // layer-1 bf16 x table
    float* vbuf   = (float*)alloc(512 * 4);             // layer-1 v_s/v_d [8][64]
    float* v3buf  = (float*)alloc(256 * 4);             // layer-3 v3/v3d
    u16*   aggb   = (u16*)alloc((size_t)N * 256 * 2);   // layer-1 aggregate (bf16)
    u16*   agg3b  = (u16*)alloc((size_t)N * 128 * 2);   // layer-3 aggregate (bf16)
    u16*   pfb    = (u16*)alloc((size_t)N * 128 * 2);   // bf16 shadow of pf

    // ---- graph build phase A + weight cast + prep_v/prep_v3 + bcomb/cvec ----
    hipMemsetAsync(cnt, 0, (size_t)(N + 1 + NBUCK) * 4, stream);
    build_a_kernel<<<ACB + 35, 1024, 0, stream>>>(
        ei, bcnt, seg, W1, as1, ad1, vbuf, W3, as3, ad3, v3buf,
        fw, bg3, fb, bcomb, cvec,
        W1, w1c, 4096, W2, w2c, 8192, W3, w3c, 4096,
        pw2, pw2c, 2048, pw3, pw3c, 4096, fw, fwc, 8192);

    // ---- mid: build_b + esed1 + pn12 (independent, one launch) ----
    mid_kernel<<<NBUCK + 2 * GBLK, 256, 0, stream>>>(
        seg, bcnt, cnt, srcs16, ovbuf,
        x, vbuf, esb, edb, xc,
        pos, pw1, pb1, bn1g, bn1b, pw2c, p2b, pb2, bn2g, bn2b);

    const int NW = N / 4;   // one-wave-per-node kernels
    const int GB = GBLK;    // 625 GEMM row-blocks

    // ---- GAT layer 1 (aggregate-then-transform) ----
    gat_agg_kernel<<<NW, 256, 0, stream>>>(xc, esb, edb, cnt, srcs16, ovbuf, aggb, N);
    w1ln_kernel<<<GB, 256, 0, stream>>>(aggb, w1c, bg1, ln1g, ln1b, xb, N);

    // ---- layer-2 GEMM+scores || pf GEMM (independent, merged) ----
    gs2pf_kernel<<<2 * GB, 256, 0, stream>>>(
        xb, w2c, hbufb, as2, ad2, esb, edb,
        p2b, pw3c, pb3, pf, pfb, N);

    // ---- GAT layer 2 (+ fused layer-3 scores from xb rows) ----
    gat_fused_kernel<2, 64, true><<<NW, 256, 0, stream>>>(
        hbufb, esb, edb, cnt, srcs16, ovbuf, bg2, ln2g, ln2b, xb, nullptr,
        v3buf, v3buf + 128, es3b, ed3b, N);

    // ---- GAT layer 3 aggregation over xb (bf16 sums only, no bias) ----
    gat_fused_kernel<1, 128, false><<<NW, 256, 0, stream>>>(
        xb, es3b, ed3b, cnt, srcs16, ovbuf, nullptr, nullptr, nullptr,
        nullptr, agg3b, nullptr, nullptr, nullptr, nullptr, N);

    // ---- merged final: x3 = agg3@W3^T + bg3 || out = [agg3|pf]@bcomb^T + cvec ----
    w3out_kernel<<<2 * GB, 256, 0, stream>>>(agg3b, w3c, bg3, x3, pfb, bcomb, cvec, out, N);
}